// Round 11
// baseline (745.596 us; speedup 1.0000x reference)
//
#include <hip/hip_runtime.h>

#define DIM 1024
#define BATCH 4096

typedef __attribute__((ext_vector_type(8))) short short8v;
typedef __attribute__((ext_vector_type(4))) short short4v;
typedef __attribute__((ext_vector_type(4))) float f32x4;

// ---------------------------------------------------------------------------
__device__ __forceinline__ float dpp_reduce_bcast(float x) {
  int v = __builtin_bit_cast(int, x);
#define DPP_STEP(ctrl)                                                        \
  {                                                                           \
    int s = __builtin_amdgcn_update_dpp(0, v, ctrl, 0xf, 0xf, true);          \
    v = __builtin_bit_cast(                                                   \
        int, __builtin_bit_cast(float, v) + __builtin_bit_cast(float, s));    \
  }
  DPP_STEP(0x111) DPP_STEP(0x112) DPP_STEP(0x114) DPP_STEP(0x118)
  DPP_STEP(0x142) DPP_STEP(0x143)
#undef DPP_STEP
  return __builtin_bit_cast(float, __builtin_amdgcn_readlane(v, 63));
}

__device__ __forceinline__ short f2bf(float f) {
  unsigned u = __builtin_bit_cast(unsigned, f);
  u += 0x7FFFu + ((u >> 16) & 1u);
  return (short)(u >> 16);
}
__device__ __forceinline__ float bf2f(short h) {
  unsigned u = ((unsigned)(unsigned short)h) << 16;
  return __builtin_bit_cast(float, u);
}

// ---------------------------------------------------------------------------
// tau[m] = 2/||row m||^2. U side: row m of U. V side: row (1023-m) of V
// (V reflectors are applied in reverse order; Av[m] = V[1023-m]).
__global__ __launch_bounds__(256) void prep_k(const float* __restrict__ U,
                                              const float* __restrict__ V,
                                              float* __restrict__ tinu,
                                              float* __restrict__ tinv) {
  int gw = (blockIdx.x * 256 + threadIdx.x) >> 6;
  int lane = threadIdx.x & 63;
  if (gw >= 2048) return;
  const float* src = (gw < 1024) ? (U + (size_t)gw * DIM)
                                 : (V + (size_t)(1023 - (gw - 1024)) * DIM);
  float s = 0.f;
#pragma unroll
  for (int q = 0; q < 4; ++q) {
    float4 v = *reinterpret_cast<const float4*>(src + q * 256 + lane * 4);
    s += v.x * v.x + v.y * v.y + v.z * v.z + v.w * v.w;
  }
  float tot = dpp_reduce_bcast(s);
  if (lane == 0) {
    float val = 2.0f / tot;
    if (gw < 1024) tinu[gw] = val; else tinv[gw - 1024] = val;
  }
}

__global__ __launch_bounds__(256) void sig_k(const float* __restrict__ p, float* __restrict__ sg) {
  int i = blockIdx.x * 256 + threadIdx.x;
  if (i < DIM) {
    sg[i] = 0.1f + 0.9f / (1.0f + __expf(-p[i]));  // 0.9*sigmoid(p)+0.1
  }
}

// ---------------------------------------------------------------------------
// Natural-layout bf16 hi/lo splits of Au = U and Av = rows-of-V-reversed.
__global__ __launch_bounds__(256) void asplit_k(const float* __restrict__ U,
                                                const float* __restrict__ V,
                                                short* __restrict__ AuH,
                                                short* __restrict__ AuL,
                                                short* __restrict__ AvH,
                                                short* __restrict__ AvL) {
  int e = (blockIdx.x * 256 + threadIdx.x) * 8;
  int side = e >> 20;
  int idx = e & 1048575;
  int r = idx >> 10, c = idx & 1023;
  const float* src = side ? (V + (size_t)(1023 - r) * DIM + c)
                          : (U + (size_t)r * DIM + c);
  float4 a = *reinterpret_cast<const float4*>(src);
  float4 b = *reinterpret_cast<const float4*>(src + 4);
  float fv[8] = {a.x, a.y, a.z, a.w, b.x, b.y, b.z, b.w};
  short8v h, l;
#pragma unroll
  for (int j = 0; j < 8; ++j) {
    short hh = f2bf(fv[j]);
    h[j] = hh;
    l[j] = f2bf(fv[j] - bf2f(hh));
  }
  *reinterpret_cast<short8v*>((side ? AvH : AuH) + idx) = h;
  *reinterpret_cast<short8v*>((side ? AvL : AuL) + idx) = l;
}

// ---------------------------------------------------------------------------
// Gram: G[m][n] = Au_m . Au_n (4-term split-bf16 for accuracy). z = side.
__global__ __launch_bounds__(256) void gram_k(const float* __restrict__ U,
                                              const float* __restrict__ V,
                                              const short* __restrict__ AuH,
                                              const short* __restrict__ AuL,
                                              const short* __restrict__ AvH,
                                              const short* __restrict__ AvL,
                                              float* __restrict__ Gu,
                                              float* __restrict__ Gv) {
  __shared__ short Ah[128][40], Al[128][40], Bh[128][40], Bl[128][40];
  const int side = blockIdx.z;
  const float* A = side ? V : U;
  const short* BH = side ? AvH : AuH;
  const short* BL = side ? AvL : AuL;
  float* G = side ? Gv : Gu;
  const int tid = threadIdx.x;
  const int bn = blockIdx.x, bm = blockIdx.y;
  const int wid = tid >> 6, wr = wid >> 1, wc = wid & 1;
  const int lane = tid & 63, l15 = lane & 15, k8 = (lane >> 4) << 3;
  f32x4 acc[4][4] = {};

  for (int kb = 0; kb < DIM; kb += 32) {
    __syncthreads();
#pragma unroll
    for (int ii = 0; ii < 4; ++ii) {
      int flat = tid + ii * 256;
      int r = flat >> 3, kq = (flat & 7) << 2;
      int rg = bm * 128 + r;
      int rs = side ? (1023 - rg) : rg;
      float4 v = *reinterpret_cast<const float4*>(A + (size_t)rs * DIM + kb + kq);
      short4v h, l;
      float fv[4] = {v.x, v.y, v.z, v.w};
#pragma unroll
      for (int j = 0; j < 4; ++j) {
        short hh = f2bf(fv[j]); h[j] = hh; l[j] = f2bf(fv[j] - bf2f(hh));
      }
      *reinterpret_cast<short4v*>(&Ah[r][kq]) = h;
      *reinterpret_cast<short4v*>(&Al[r][kq]) = l;
    }
#pragma unroll
    for (int ii = 0; ii < 2; ++ii) {
      int flat = tid + ii * 256;
      int n = flat >> 2, kk8 = (flat & 3) << 3;
      size_t off = (size_t)(bn * 128 + n) * DIM + kb + kk8;
      *reinterpret_cast<short8v*>(&Bh[n][kk8]) = *reinterpret_cast<const short8v*>(BH + off);
      *reinterpret_cast<short8v*>(&Bl[n][kk8]) = *reinterpret_cast<const short8v*>(BL + off);
    }
    __syncthreads();
    short8v ah[4], al_[4], bh[4], bl_[4];
#pragma unroll
    for (int m = 0; m < 4; ++m) {
      int r = wr * 64 + m * 16 + l15;
      ah[m] = *reinterpret_cast<const short8v*>(&Ah[r][k8]);
      al_[m] = *reinterpret_cast<const short8v*>(&Al[r][k8]);
    }
#pragma unroll
    for (int n = 0; n < 4; ++n) {
      int r = wc * 64 + n * 16 + l15;
      bh[n] = *reinterpret_cast<const short8v*>(&Bh[r][k8]);
      bl_[n] = *reinterpret_cast<const short8v*>(&Bl[r][k8]);
    }
#pragma unroll
    for (int m = 0; m < 4; ++m)
#pragma unroll
      for (int n = 0; n < 4; ++n) {
        acc[m][n] = __builtin_amdgcn_mfma_f32_16x16x32_bf16(ah[m], bh[n], acc[m][n], 0, 0, 0);
        acc[m][n] = __builtin_amdgcn_mfma_f32_16x16x32_bf16(ah[m], bl_[n], acc[m][n], 0, 0, 0);
        acc[m][n] = __builtin_amdgcn_mfma_f32_16x16x32_bf16(al_[m], bh[n], acc[m][n], 0, 0, 0);
        acc[m][n] = __builtin_amdgcn_mfma_f32_16x16x32_bf16(al_[m], bl_[n], acc[m][n], 0, 0, 0);
      }
  }
#pragma unroll
  for (int n = 0; n < 4; ++n) {
    int gcol = bn * 128 + wc * 64 + n * 16 + l15;
#pragma unroll
    for (int m = 0; m < 4; ++m) {
      int grow0 = bm * 128 + wr * 64 + m * 16 + ((lane >> 4) << 2);
#pragma unroll
      for (int j = 0; j < 4; ++j)
        G[(size_t)(grow0 + j) * DIM + gcol] = acc[m][n][j];
    }
  }
}

// ---------------------------------------------------------------------------
// 64x64 diagonal T blocks: T[k][k]=tau_k; T[i][k] = -tau_k * sum_{m=i}^{k-1}
// T[i][m]*S[m][k], S[m][k]=G[b0+m][b0+k]. One wave per block.
__global__ __launch_bounds__(64) void tdiag_k(const float* __restrict__ Gu,
                                              const float* __restrict__ Gv,
                                              const float* __restrict__ tinu,
                                              const float* __restrict__ tinv,
                                              float* __restrict__ Tu,
                                              float* __restrict__ Tv) {
  __shared__ float S[64][68], Tl[64][68];
  int z = blockIdx.x >> 4;
  int d = blockIdx.x & 15;
  const float* G = z ? Gv : Gu;
  const float* tau = z ? tinv : tinu;
  float* T = z ? Tv : Tu;
  int b0 = d * 64;
  int lane = threadIdx.x;
#pragma unroll
  for (int j = 0; j < 64; j += 4) {
    *reinterpret_cast<float4*>(&S[lane][j]) =
        *reinterpret_cast<const float4*>(G + (size_t)(b0 + lane) * DIM + b0 + j);
    float4 zz = {0.f, 0.f, 0.f, 0.f};
    *reinterpret_cast<float4*>(&Tl[lane][j]) = zz;
  }
  __syncthreads();
  Tl[lane][lane] = tau[b0 + lane];
  __syncthreads();
  for (int k = 1; k < 64; ++k) {
    float tk = tau[b0 + k];
    float acc = 0.f;
    if (lane < k) {
      for (int m = lane; m < k; ++m) acc = fmaf(Tl[lane][m], S[m][k], acc);
    }
    __syncthreads();
    if (lane < k) Tl[lane][k] = -tk * acc;
    __syncthreads();
  }
#pragma unroll
  for (int j = 0; j < 64; j += 4)
    *reinterpret_cast<float4*>(T + (size_t)(b0 + lane) * DIM + b0 + j) =
        *reinterpret_cast<const float4*>(&Tl[lane][j]);
}

// ---------------------------------------------------------------------------
// Level s=64 combine, fully in-LDS: X = -T_A @ S_AB @ T_B for pair blocks
// [a0,a0+64) x [a0+64,a0+128). 16 workgroups (8 pairs x 2 sides).
__global__ __launch_bounds__(256) void tcomb64_k(const float* __restrict__ Gu,
                                                 const float* __restrict__ Gv,
                                                 float* __restrict__ Tu,
                                                 float* __restrict__ Tv) {
  __shared__ float TA[64][68], SS[64][68], TB[64][68], W[64][68];
  int zz = blockIdx.x;
  int side = zz >> 3, p = zz & 7;
  int a0 = p * 128;
  const float* G = side ? Gv : Gu;
  float* T = side ? Tv : Tu;
  int tid = threadIdx.x;
#pragma unroll
  for (int ii = 0; ii < 4; ++ii) {
    int flat = tid + ii * 256;
    int r = flat >> 4, c4 = (flat & 15) << 2;
    *reinterpret_cast<float4*>(&TA[r][c4]) =
        *reinterpret_cast<const float4*>(T + (size_t)(a0 + r) * DIM + a0 + c4);
    *reinterpret_cast<float4*>(&SS[r][c4]) =
        *reinterpret_cast<const float4*>(G + (size_t)(a0 + r) * DIM + a0 + 64 + c4);
    *reinterpret_cast<float4*>(&TB[r][c4]) =
        *reinterpret_cast<const float4*>(T + (size_t)(a0 + 64 + r) * DIM + a0 + 64 + c4);
  }
  __syncthreads();
  int tx = tid & 15, ty = tid >> 4;
  float acc[4][4] = {};
  for (int k = 0; k < 64; ++k) {
    float a[4], b[4];
#pragma unroll
    for (int m = 0; m < 4; ++m) a[m] = SS[ty * 4 + m][k];
#pragma unroll
    for (int n = 0; n < 4; ++n) b[n] = TB[k][tx * 4 + n];
#pragma unroll
    for (int m = 0; m < 4; ++m)
#pragma unroll
      for (int n = 0; n < 4; ++n) acc[m][n] = fmaf(a[m], b[n], acc[m][n]);
  }
#pragma unroll
  for (int m = 0; m < 4; ++m)
#pragma unroll
    for (int n = 0; n < 4; ++n) W[ty * 4 + m][tx * 4 + n] = acc[m][n];
  __syncthreads();
  float acc2[4][4] = {};
  for (int k = 0; k < 64; ++k) {
    float a[4], b[4];
#pragma unroll
    for (int m = 0; m < 4; ++m) a[m] = TA[ty * 4 + m][k];
#pragma unroll
    for (int n = 0; n < 4; ++n) b[n] = W[k][tx * 4 + n];
#pragma unroll
    for (int m = 0; m < 4; ++m)
#pragma unroll
      for (int n = 0; n < 4; ++n) acc2[m][n] = fmaf(a[m], b[n], acc2[m][n]);
  }
#pragma unroll
  for (int m = 0; m < 4; ++m)
#pragma unroll
    for (int n = 0; n < 4; ++n)
      T[(size_t)(a0 + ty * 4 + m) * DIM + a0 + 64 + tx * 4 + n] = -acc2[m][n];
}

// ---------------------------------------------------------------------------
// General MFMA gemm for tree levels s>=128: 128-tile, A f32 natural (on-fly
// split), B f32 transpose-staged in LDS. stage1: Tmp = S_AB @ T_B (alpha=+1);
// stage2: T[a0..][a0+s..] = -T_A @ Tmp.
__global__ __launch_bounds__(256) void tcombgg_k(const float* __restrict__ Gu,
                                                 const float* __restrict__ Gv,
                                                 float* __restrict__ Tu,
                                                 float* __restrict__ Tv,
                                                 float* __restrict__ Tmp,
                                                 int s, int npair, int stage) {
  __shared__ short Ah[128][40], Al[128][40], Bh[128][40], Bl[128][40];
  const int z = blockIdx.z;
  const int side = z / npair, p = z % npair;
  const int a0 = p * 2 * s;
  const float* G = side ? Gv : Gu;
  float* T = side ? Tv : Tu;
  const float* Ab; const float* Bb; float* Cb;
  int lda, ldb, ldc; float alpha;
  if (stage == 1) {
    Ab = G + (size_t)a0 * DIM + (a0 + s); lda = DIM;
    Bb = T + (size_t)(a0 + s) * DIM + (a0 + s); ldb = DIM;
    Cb = Tmp + (size_t)z * s * s; ldc = s; alpha = 1.f;
  } else {
    Ab = T + (size_t)a0 * DIM + a0; lda = DIM;
    Bb = Tmp + (size_t)z * s * s; ldb = s;
    Cb = T + (size_t)a0 * DIM + (a0 + s); ldc = DIM; alpha = -1.f;
  }
  const int tid = threadIdx.x;
  const int bn = blockIdx.x, bm = blockIdx.y;
  const int wid = tid >> 6, wr = wid >> 1, wc = wid & 1;
  const int lane = tid & 63, l15 = lane & 15, k8 = (lane >> 4) << 3;
  f32x4 acc[4][4] = {};

  for (int kb = 0; kb < s; kb += 32) {
    __syncthreads();
#pragma unroll
    for (int ii = 0; ii < 4; ++ii) {
      int flat = tid + ii * 256;
      int r = flat >> 3, kq = (flat & 7) << 2;
      float4 v = *reinterpret_cast<const float4*>(Ab + (size_t)(bm * 128 + r) * lda + kb + kq);
      short4v h, l;
      float fv[4] = {v.x, v.y, v.z, v.w};
#pragma unroll
      for (int j = 0; j < 4; ++j) {
        short hh = f2bf(fv[j]); h[j] = hh; l[j] = f2bf(fv[j] - bf2f(hh));
      }
      *reinterpret_cast<short4v*>(&Ah[r][kq]) = h;
      *reinterpret_cast<short4v*>(&Al[r][kq]) = l;
    }
    // B transpose-stage: B[k][n] tile -> Bh/Bl[n][k]
#pragma unroll
    for (int ii = 0; ii < 4; ++ii) {
      int flat = tid + ii * 256;
      int kk = flat >> 5, n4 = (flat & 31) << 2;
      float4 v = *reinterpret_cast<const float4*>(Bb + (size_t)(kb + kk) * ldb + bn * 128 + n4);
      float fv[4] = {v.x, v.y, v.z, v.w};
#pragma unroll
      for (int j = 0; j < 4; ++j) {
        short hh = f2bf(fv[j]);
        Bh[n4 + j][kk] = hh;
        Bl[n4 + j][kk] = f2bf(fv[j] - bf2f(hh));
      }
    }
    __syncthreads();
    short8v ah[4], al_[4], bh[4], bl_[4];
#pragma unroll
    for (int m = 0; m < 4; ++m) {
      int r = wr * 64 + m * 16 + l15;
      ah[m] = *reinterpret_cast<const short8v*>(&Ah[r][k8]);
      al_[m] = *reinterpret_cast<const short8v*>(&Al[r][k8]);
    }
#pragma unroll
    for (int n = 0; n < 4; ++n) {
      int r = wc * 64 + n * 16 + l15;
      bh[n] = *reinterpret_cast<const short8v*>(&Bh[r][k8]);
      bl_[n] = *reinterpret_cast<const short8v*>(&Bl[r][k8]);
    }
#pragma unroll
    for (int m = 0; m < 4; ++m)
#pragma unroll
      for (int n = 0; n < 4; ++n) {
        acc[m][n] = __builtin_amdgcn_mfma_f32_16x16x32_bf16(ah[m], bh[n], acc[m][n], 0, 0, 0);
        acc[m][n] = __builtin_amdgcn_mfma_f32_16x16x32_bf16(ah[m], bl_[n], acc[m][n], 0, 0, 0);
        acc[m][n] = __builtin_amdgcn_mfma_f32_16x16x32_bf16(al_[m], bh[n], acc[m][n], 0, 0, 0);
      }
  }
#pragma unroll
  for (int n = 0; n < 4; ++n) {
    int gcol = bn * 128 + wc * 64 + n * 16 + l15;
#pragma unroll
    for (int m = 0; m < 4; ++m) {
      int grow0 = bm * 128 + wr * 64 + m * 16 + ((lane >> 4) << 2);
#pragma unroll
      for (int j = 0; j < 4; ++j)
        Cb[(size_t)(grow0 + j) * ldc + gcol] = alpha * acc[m][n][j];
    }
  }
}

// ---------------------------------------------------------------------------
// P = T @ Au : A = T f32 natural; B[k][c] = Au[k][c] (V: row-flipped on k),
// transpose-staged. Out f32.
__global__ __launch_bounds__(256) void pgemm_k(const float* __restrict__ Tu,
                                               const float* __restrict__ Tv,
                                               const float* __restrict__ U,
                                               const float* __restrict__ V,
                                               float* __restrict__ Pu,
                                               float* __restrict__ Pv) {
  __shared__ short Ah[128][40], Al[128][40], Bh[128][40], Bl[128][40];
  const int side = blockIdx.z;
  const float* A = side ? Tv : Tu;
  const float* B = side ? V : U;
  float* Out = side ? Pv : Pu;
  const int tid = threadIdx.x;
  const int bn = blockIdx.x, bm = blockIdx.y;
  const int wid = tid >> 6, wr = wid >> 1, wc = wid & 1;
  const int lane = tid & 63, l15 = lane & 15, k8 = (lane >> 4) << 3;
  f32x4 acc[4][4] = {};

  for (int kb = 0; kb < DIM; kb += 32) {
    __syncthreads();
#pragma unroll
    for (int ii = 0; ii < 4; ++ii) {
      int flat = tid + ii * 256;
      int r = flat >> 3, kq = (flat & 7) << 2;
      float4 v = *reinterpret_cast<const float4*>(A + (size_t)(bm * 128 + r) * DIM + kb + kq);
      short4v h, l;
      float fv[4] = {v.x, v.y, v.z, v.w};
#pragma unroll
      for (int j = 0; j < 4; ++j) {
        short hh = f2bf(fv[j]); h[j] = hh; l[j] = f2bf(fv[j] - bf2f(hh));
      }
      *reinterpret_cast<short4v*>(&Ah[r][kq]) = h;
      *reinterpret_cast<short4v*>(&Al[r][kq]) = l;
    }
#pragma unroll
    for (int ii = 0; ii < 4; ++ii) {
      int flat = tid + ii * 256;
      int kk = flat >> 5, n4 = (flat & 31) << 2;
      int ks = kb + kk;
      if (side) ks = 1023 - ks;
      float4 v = *reinterpret_cast<const float4*>(B + (size_t)ks * DIM + bn * 128 + n4);
      float fv[4] = {v.x, v.y, v.z, v.w};
#pragma unroll
      for (int j = 0; j < 4; ++j) {
        short hh = f2bf(fv[j]);
        Bh[n4 + j][kk] = hh;
        Bl[n4 + j][kk] = f2bf(fv[j] - bf2f(hh));
      }
    }
    __syncthreads();
    short8v ah[4], al_[4], bh[4], bl_[4];
#pragma unroll
    for (int m = 0; m < 4; ++m) {
      int r = wr * 64 + m * 16 + l15;
      ah[m] = *reinterpret_cast<const short8v*>(&Ah[r][k8]);
      al_[m] = *reinterpret_cast<const short8v*>(&Al[r][k8]);
    }
#pragma unroll
    for (int n = 0; n < 4; ++n) {
      int r = wc * 64 + n * 16 + l15;
      bh[n] = *reinterpret_cast<const short8v*>(&Bh[r][k8]);
      bl_[n] = *reinterpret_cast<const short8v*>(&Bl[r][k8]);
    }
#pragma unroll
    for (int m = 0; m < 4; ++m)
#pragma unroll
      for (int n = 0; n < 4; ++n) {
        acc[m][n] = __builtin_amdgcn_mfma_f32_16x16x32_bf16(ah[m], bh[n], acc[m][n], 0, 0, 0);
        acc[m][n] = __builtin_amdgcn_mfma_f32_16x16x32_bf16(ah[m], bl_[n], acc[m][n], 0, 0, 0);
        acc[m][n] = __builtin_amdgcn_mfma_f32_16x16x32_bf16(al_[m], bh[n], acc[m][n], 0, 0, 0);
      }
  }
#pragma unroll
  for (int n = 0; n < 4; ++n) {
    int gcol = bn * 128 + wc * 64 + n * 16 + l15;
#pragma unroll
    for (int m = 0; m < 4; ++m) {
      int grow0 = bm * 128 + wr * 64 + m * 16 + ((lane >> 4) << 2);
#pragma unroll
      for (int j = 0; j < 4; ++j)
        Out[(size_t)(grow0 + j) * DIM + gcol] = acc[m][n][j];
    }
  }
}

// ---------------------------------------------------------------------------
// N = Au^T @ P (both operands transpose-staged from f32). Epilogue:
// side0: Qu'[m][n] = (delta - N)*sg[n]; side1: Qv[m][n] = delta - N.
__global__ __launch_bounds__(256) void ngemm_k(const float* __restrict__ U,
                                               const float* __restrict__ V,
                                               const float* __restrict__ Pu,
                                               const float* __restrict__ Pv,
                                               const float* __restrict__ sg,
                                               float* __restrict__ Qup,
                                               float* __restrict__ Qv) {
  __shared__ short Ah[128][40], Al[128][40], Bh[128][40], Bl[128][40];
  const int side = blockIdx.z;
  const float* Asrc = side ? V : U;   // A[m][k] = Au[k][m]
  const float* Bsrc = side ? Pv : Pu;
  const int tid = threadIdx.x;
  const int bn = blockIdx.x, bm = blockIdx.y;
  const int wid = tid >> 6, wr = wid >> 1, wc = wid & 1;
  const int lane = tid & 63, l15 = lane & 15, k8 = (lane >> 4) << 3;
  f32x4 acc[4][4] = {};

  for (int kb = 0; kb < DIM; kb += 32) {
    __syncthreads();
    // A transpose-stage: load Asrc[k][m-range]
#pragma unroll
    for (int ii = 0; ii < 4; ++ii) {
      int flat = tid + ii * 256;
      int kk = flat >> 5, m4 = (flat & 31) << 2;
      int ks = kb + kk;
      if (side) ks = 1023 - ks;
      float4 v = *reinterpret_cast<const float4*>(Asrc + (size_t)ks * DIM + bm * 128 + m4);
      float fv[4] = {v.x, v.y, v.z, v.w};
#pragma unroll
      for (int j = 0; j < 4; ++j) {
        short hh = f2bf(fv[j]);
        Ah[m4 + j][kk] = hh;
        Al[m4 + j][kk] = f2bf(fv[j] - bf2f(hh));
      }
    }
    // B transpose-stage: Bsrc[k][n-range]
#pragma unroll
    for (int ii = 0; ii < 4; ++ii) {
      int flat = tid + ii * 256;
      int kk = flat >> 5, n4 = (flat & 31) << 2;
      float4 v = *reinterpret_cast<const float4*>(Bsrc + (size_t)(kb + kk) * DIM + bn * 128 + n4);
      float fv[4] = {v.x, v.y, v.z, v.w};
#pragma unroll
      for (int j = 0; j < 4; ++j) {
        short hh = f2bf(fv[j]);
        Bh[n4 + j][kk] = hh;
        Bl[n4 + j][kk] = f2bf(fv[j] - bf2f(hh));
      }
    }
    __syncthreads();
    short8v ah[4], al_[4], bh[4], bl_[4];
#pragma unroll
    for (int m = 0; m < 4; ++m) {
      int r = wr * 64 + m * 16 + l15;
      ah[m] = *reinterpret_cast<const short8v*>(&Ah[r][k8]);
      al_[m] = *reinterpret_cast<const short8v*>(&Al[r][k8]);
    }
#pragma unroll
    for (int n = 0; n < 4; ++n) {
      int r = wc * 64 + n * 16 + l15;
      bh[n] = *reinterpret_cast<const short8v*>(&Bh[r][k8]);
      bl_[n] = *reinterpret_cast<const short8v*>(&Bl[r][k8]);
    }
#pragma unroll
    for (int m = 0; m < 4; ++m)
#pragma unroll
      for (int n = 0; n < 4; ++n) {
        acc[m][n] = __builtin_amdgcn_mfma_f32_16x16x32_bf16(ah[m], bh[n], acc[m][n], 0, 0, 0);
        acc[m][n] = __builtin_amdgcn_mfma_f32_16x16x32_bf16(ah[m], bl_[n], acc[m][n], 0, 0, 0);
        acc[m][n] = __builtin_amdgcn_mfma_f32_16x16x32_bf16(al_[m], bh[n], acc[m][n], 0, 0, 0);
      }
  }
#pragma unroll
  for (int n = 0; n < 4; ++n) {
    int gcol = bn * 128 + wc * 64 + n * 16 + l15;
    float sgn = sg[gcol];
#pragma unroll
    for (int m = 0; m < 4; ++m) {
      int grow0 = bm * 128 + wr * 64 + m * 16 + ((lane >> 4) << 2);
#pragma unroll
      for (int j = 0; j < 4; ++j) {
        float del = ((grow0 + j) == gcol) ? 1.0f : 0.0f;
        float val = del - acc[m][n][j];
        if (side == 0)
          Qup[(size_t)(grow0 + j) * DIM + gcol] = val * sgn;
        else
          Qv[(size_t)(grow0 + j) * DIM + gcol] = val;
      }
    }
  }
}

// ---------------------------------------------------------------------------
// M = Qu' @ Qv; A = Qu' f32 natural; B = Qv transpose-staged.
// Epilogue writes M^T bf16 hi/lo directly ([n][k] for the final gemm).
__global__ __launch_bounds__(256) void mgemm2_k(const float* __restrict__ Qup,
                                                const float* __restrict__ Qv,
                                                short* __restrict__ MTh,
                                                short* __restrict__ MTl) {
  __shared__ short Ah[128][40], Al[128][40], Bh[128][40], Bl[128][40];
  const int tid = threadIdx.x;
  const int bn = blockIdx.x, bm = blockIdx.y;
  const int wid = tid >> 6, wr = wid >> 1, wc = wid & 1;
  const int lane = tid & 63, l15 = lane & 15, k8 = (lane >> 4) << 3;
  f32x4 acc[4][4] = {};

  for (int kb = 0; kb < DIM; kb += 32) {
    __syncthreads();
#pragma unroll
    for (int ii = 0; ii < 4; ++ii) {
      int flat = tid + ii * 256;
      int r = flat >> 3, kq = (flat & 7) << 2;
      float4 v = *reinterpret_cast<const float4*>(Qup + (size_t)(bm * 128 + r) * DIM + kb + kq);
      short4v h, l;
      float fv[4] = {v.x, v.y, v.z, v.w};
#pragma unroll
      for (int j = 0; j < 4; ++j) {
        short hh = f2bf(fv[j]); h[j] = hh; l[j] = f2bf(fv[j] - bf2f(hh));
      }
      *reinterpret_cast<short4v*>(&Ah[r][kq]) = h;
      *reinterpret_cast<short4v*>(&Al[r][kq]) = l;
    }
#pragma unroll
    for (int ii = 0; ii < 4; ++ii) {
      int flat = tid + ii * 256;
      int kk = flat >> 5, n4 = (flat & 31) << 2;
      float4 v = *reinterpret_cast<const float4*>(Qv + (size_t)(kb + kk) * DIM + bn * 128 + n4);
      float fv[4] = {v.x, v.y, v.z, v.w};
#pragma unroll
      for (int j = 0; j < 4; ++j) {
        short hh = f2bf(fv[j]);
        Bh[n4 + j][kk] = hh;
        Bl[n4 + j][kk] = f2bf(fv[j] - bf2f(hh));
      }
    }
    __syncthreads();
    short8v ah[4], al_[4], bh[4], bl_[4];
#pragma unroll
    for (int m = 0; m < 4; ++m) {
      int r = wr * 64 + m * 16 + l15;
      ah[m] = *reinterpret_cast<const short8v*>(&Ah[r][k8]);
      al_[m] = *reinterpret_cast<const short8v*>(&Al[r][k8]);
    }
#pragma unroll
    for (int n = 0; n < 4; ++n) {
      int r = wc * 64 + n * 16 + l15;
      bh[n] = *reinterpret_cast<const short8v*>(&Bh[r][k8]);
      bl_[n] = *reinterpret_cast<const short8v*>(&Bl[r][k8]);
    }
#pragma unroll
    for (int m = 0; m < 4; ++m)
#pragma unroll
      for (int n = 0; n < 4; ++n) {
        acc[m][n] = __builtin_amdgcn_mfma_f32_16x16x32_bf16(ah[m], bh[n], acc[m][n], 0, 0, 0);
        acc[m][n] = __builtin_amdgcn_mfma_f32_16x16x32_bf16(ah[m], bl_[n], acc[m][n], 0, 0, 0);
        acc[m][n] = __builtin_amdgcn_mfma_f32_16x16x32_bf16(al_[m], bh[n], acc[m][n], 0, 0, 0);
      }
  }
#pragma unroll
  for (int n = 0; n < 4; ++n) {
    int gcol = bn * 128 + wc * 64 + n * 16 + l15;
#pragma unroll
    for (int m = 0; m < 4; ++m) {
      int gk0 = bm * 128 + wr * 64 + m * 16 + ((lane >> 4) << 2);
      short4v h, l;
#pragma unroll
      for (int j = 0; j < 4; ++j) {
        float fv = acc[m][n][j];
        short hh = f2bf(fv);
        h[j] = hh;
        l[j] = f2bf(fv - bf2f(hh));
      }
      *reinterpret_cast<short4v*>(MTh + (size_t)gcol * DIM + gk0) = h;
      *reinterpret_cast<short4v*>(MTl + (size_t)gcol * DIM + gk0) = l;
    }
  }
}

// ---------------------------------------------------------------------------
// out[4096,1024] = x @ M + bias via split-bf16 MFMA (proven).
__global__ __launch_bounds__(256) void gemm_mfma_k(const float* __restrict__ x,
                                                   const short* __restrict__ Bthi,
                                                   const short* __restrict__ Btlo,
                                                   const float* __restrict__ bias,
                                                   float* __restrict__ out) {
  __shared__ short Ah[128][40], Al[128][40], Bh[128][40], Bl[128][40];
  const int tid = threadIdx.x;
  const int bn = blockIdx.x, bm = blockIdx.y;
  const int wid = tid >> 6, wr = wid >> 1, wc = wid & 1;
  const int lane = tid & 63, l15 = lane & 15, k8 = (lane >> 4) << 3;
  f32x4 acc[4][4] = {};

  for (int kb = 0; kb < DIM; kb += 32) {
    __syncthreads();
#pragma unroll
    for (int ii = 0; ii < 4; ++ii) {
      int flat = tid + ii * 256;
      int r = flat >> 3, kq = (flat & 7) << 2;
      float4 v = *reinterpret_cast<const float4*>(x + (size_t)(bm * 128 + r) * DIM + kb + kq);
      short4v h, l;
      float fv[4] = {v.x, v.y, v.z, v.w};
#pragma unroll
      for (int j = 0; j < 4; ++j) {
        short hh = f2bf(fv[j]); h[j] = hh; l[j] = f2bf(fv[j] - bf2f(hh));
      }
      *reinterpret_cast<short4v*>(&Ah[r][kq]) = h;
      *reinterpret_cast<short4v*>(&Al[r][kq]) = l;
    }
#pragma unroll
    for (int ii = 0; ii < 2; ++ii) {
      int flat = tid + ii * 256;
      int n = flat >> 2, kk8 = (flat & 3) << 3;
      size_t off = (size_t)(bn * 128 + n) * DIM + kb + kk8;
      *reinterpret_cast<short8v*>(&Bh[n][kk8]) = *reinterpret_cast<const short8v*>(Bthi + off);
      *reinterpret_cast<short8v*>(&Bl[n][kk8]) = *reinterpret_cast<const short8v*>(Btlo + off);
    }
    __syncthreads();
    short8v ah[4], al_[4], bh[4], bl_[4];
#pragma unroll
    for (int m = 0; m < 4; ++m) {
      int r = wr * 64 + m * 16 + l15;
      ah[m] = *reinterpret_cast<const short8v*>(&Ah[r][k8]);
      al_[m] = *reinterpret_cast<const short8v*>(&Al[r][k8]);
    }
#pragma unroll
    for (int n = 0; n < 4; ++n) {
      int r = wc * 64 + n * 16 + l15;
      bh[n] = *reinterpret_cast<const short8v*>(&Bh[r][k8]);
      bl_[n] = *reinterpret_cast<const short8v*>(&Bl[r][k8]);
    }
#pragma unroll
    for (int m = 0; m < 4; ++m)
#pragma unroll
      for (int n = 0; n < 4; ++n) {
        acc[m][n] = __builtin_amdgcn_mfma_f32_16x16x32_bf16(ah[m], bh[n], acc[m][n], 0, 0, 0);
        acc[m][n] = __builtin_amdgcn_mfma_f32_16x16x32_bf16(ah[m], bl_[n], acc[m][n], 0, 0, 0);
        acc[m][n] = __builtin_amdgcn_mfma_f32_16x16x32_bf16(al_[m], bh[n], acc[m][n], 0, 0, 0);
      }
  }
#pragma unroll
  for (int n = 0; n < 4; ++n) {
    int gcol = bn * 128 + wc * 64 + n * 16 + l15;
    float bv = bias[gcol];
#pragma unroll
    for (int m = 0; m < 4; ++m) {
      int grow0 = bm * 128 + wr * 64 + m * 16 + ((lane >> 4) << 2);
#pragma unroll
      for (int j = 0; j < 4; ++j)
        out[(size_t)(grow0 + j) * DIM + gcol] = acc[m][n][j] + bv;
    }
  }
}

// ---------------------------------------------------------------------------
extern "C" void kernel_launch(void* const* d_in, const int* in_sizes, int n_in,
                              void* d_out, int out_size, void* d_ws, size_t ws_size,
                              hipStream_t stream) {
  const float* x    = (const float*)d_in[0];
  const float* U    = (const float*)d_in[1];
  const float* V    = (const float*)d_in[2];
  const float* p    = (const float*)d_in[3];
  const float* bias = (const float*)d_in[4];
  float* out = (float*)d_out;

  float* F = (float*)d_ws;
  // [0,2M)   Au/Av natural splits (gram only)
  // [2M,3M)  Gu -> Qu'     [3M,4M) Gv -> Qv
  // [4M,5M)  Tu -> MTh/MTl [5M,6M) Tv
  // [6M,7M)  Pu            [7M,8M) Pv
  // [8M,8.5M) Tmp          [8.5M+) smalls    (peak ~34.5 MB)
  short* AuH = (short*)F;
  short* AuL = AuH + 1048576;
  short* AvH = AuL + 1048576;
  short* AvL = AvH + 1048576;
  float* Gu  = F + 2097152;
  float* Gv  = F + 3145728;
  float* Tu  = F + 4194304;
  float* Tv  = F + 5242880;
  float* Pu  = F + 6291456;
  float* Pv  = F + 7340032;
  float* Tmp = F + 8388608;          // 524288 floats
  float* tinu = F + 8912896;
  float* tinv = tinu + DIM;
  float* sg   = tinv + DIM;
  float* Qup = Gu;                   // overlay after tcomb
  float* Qv  = Gv;
  short* MTh = (short*)Tu;           // overlay after pgemm
  short* MTl = MTh + 1048576;

  prep_k<<<512, 256, 0, stream>>>(U, V, tinu, tinv);
  sig_k<<<4, 256, 0, stream>>>(p, sg);
  asplit_k<<<1024, 256, 0, stream>>>(U, V, AuH, AuL, AvH, AvL);
  gram_k<<<dim3(8, 8, 2), 256, 0, stream>>>(U, V, AuH, AuL, AvH, AvL, Gu, Gv);
  hipMemsetAsync(Tu, 0, (size_t)2 * 1048576 * sizeof(float), stream);  // Tu|Tv
  tdiag_k<<<32, 64, 0, stream>>>(Gu, Gv, tinu, tinv, Tu, Tv);
  tcomb64_k<<<16, 256, 0, stream>>>(Gu, Gv, Tu, Tv);
  tcombgg_k<<<dim3(1, 1, 8), 256, 0, stream>>>(Gu, Gv, Tu, Tv, Tmp, 128, 4, 1);
  tcombgg_k<<<dim3(1, 1, 8), 256, 0, stream>>>(Gu, Gv, Tu, Tv, Tmp, 128, 4, 2);
  tcombgg_k<<<dim3(2, 2, 4), 256, 0, stream>>>(Gu, Gv, Tu, Tv, Tmp, 256, 2, 1);
  tcombgg_k<<<dim3(2, 2, 4), 256, 0, stream>>>(Gu, Gv, Tu, Tv, Tmp, 256, 2, 2);
  tcombgg_k<<<dim3(4, 4, 2), 256, 0, stream>>>(Gu, Gv, Tu, Tv, Tmp, 512, 1, 1);
  tcombgg_k<<<dim3(4, 4, 2), 256, 0, stream>>>(Gu, Gv, Tu, Tv, Tmp, 512, 1, 2);
  pgemm_k<<<dim3(8, 8, 2), 256, 0, stream>>>(Tu, Tv, U, V, Pu, Pv);
  ngemm_k<<<dim3(8, 8, 2), 256, 0, stream>>>(U, V, Pu, Pv, sg, Qup, Qv);
  mgemm2_k<<<dim3(8, 8), 256, 0, stream>>>(Qup, Qv, MTh, MTl);
  gemm_mfma_k<<<dim3(8, 32), 256, 0, stream>>>(x, MTh, MTl, bias, out);
}

// Round 12
// 491.773 us; speedup vs baseline: 1.5161x; 1.5161x over previous
//
#include <hip/hip_runtime.h>

#define DIM 1024
#define BATCH 4096

typedef __attribute__((ext_vector_type(8))) short short8v;
typedef __attribute__((ext_vector_type(4))) short short4v;
typedef __attribute__((ext_vector_type(4))) float f32x4;

// ---------------------------------------------------------------------------
__device__ __forceinline__ float dpp_reduce_bcast(float x) {
  int v = __builtin_bit_cast(int, x);
#define DPP_STEP(ctrl)                                                        \
  {                                                                           \
    int s = __builtin_amdgcn_update_dpp(0, v, ctrl, 0xf, 0xf, true);          \
    v = __builtin_bit_cast(                                                   \
        int, __builtin_bit_cast(float, v) + __builtin_bit_cast(float, s));    \
  }
  DPP_STEP(0x111) DPP_STEP(0x112) DPP_STEP(0x114) DPP_STEP(0x118)
  DPP_STEP(0x142) DPP_STEP(0x143)
#undef DPP_STEP
  return __builtin_bit_cast(float, __builtin_amdgcn_readlane(v, 63));
}

__device__ __forceinline__ short f2bf(float f) {
  unsigned u = __builtin_bit_cast(unsigned, f);
  u += 0x7FFFu + ((u >> 16) & 1u);
  return (short)(u >> 16);
}
__device__ __forceinline__ float bf2f(short h) {
  unsigned u = ((unsigned)(unsigned short)h) << 16;
  return __builtin_bit_cast(float, u);
}

// ---------------------------------------------------------------------------
// tau[m] = 2/||row m||^2. U: row m of U. V: row (1023-m) of V.
__global__ __launch_bounds__(256) void prep_k(const float* __restrict__ U,
                                              const float* __restrict__ V,
                                              float* __restrict__ tinu,
                                              float* __restrict__ tinv) {
  int gw = (blockIdx.x * 256 + threadIdx.x) >> 6;
  int lane = threadIdx.x & 63;
  if (gw >= 2048) return;
  const float* src = (gw < 1024) ? (U + (size_t)gw * DIM)
                                 : (V + (size_t)(1023 - (gw - 1024)) * DIM);
  float s = 0.f;
#pragma unroll
  for (int q = 0; q < 4; ++q) {
    float4 v = *reinterpret_cast<const float4*>(src + q * 256 + lane * 4);
    s += v.x * v.x + v.y * v.y + v.z * v.z + v.w * v.w;
  }
  float tot = dpp_reduce_bcast(s);
  if (lane == 0) {
    float val = 2.0f / tot;
    if (gw < 1024) tinu[gw] = val; else tinv[gw - 1024] = val;
  }
}

__global__ __launch_bounds__(256) void sig_k(const float* __restrict__ p, float* __restrict__ sg) {
  int i = blockIdx.x * 256 + threadIdx.x;
  if (i < DIM) {
    sg[i] = 0.1f + 0.9f / (1.0f + __expf(-p[i]));  // 0.9*sigmoid(p)+0.1
  }
}

// ---------------------------------------------------------------------------
// Natural-layout bf16 hi/lo splits of Au = U and Av = rows-of-V-reversed.
__global__ __launch_bounds__(256) void asplit_k(const float* __restrict__ U,
                                                const float* __restrict__ V,
                                                short* __restrict__ AuH,
                                                short* __restrict__ AuL,
                                                short* __restrict__ AvH,
                                                short* __restrict__ AvL) {
  int e = (blockIdx.x * 256 + threadIdx.x) * 8;
  int side = e >> 20;
  int idx = e & 1048575;
  int r = idx >> 10, c = idx & 1023;
  const float* src = side ? (V + (size_t)(1023 - r) * DIM + c)
                          : (U + (size_t)r * DIM + c);
  float4 a = *reinterpret_cast<const float4*>(src);
  float4 b = *reinterpret_cast<const float4*>(src + 4);
  float fv[8] = {a.x, a.y, a.z, a.w, b.x, b.y, b.z, b.w};
  short8v h, l;
#pragma unroll
  for (int j = 0; j < 8; ++j) {
    short hh = f2bf(fv[j]);
    h[j] = hh;
    l[j] = f2bf(fv[j] - bf2f(hh));
  }
  *reinterpret_cast<short8v*>((side ? AvH : AuH) + idx) = h;
  *reinterpret_cast<short8v*>((side ? AvL : AuL) + idx) = l;
}

// ---------------------------------------------------------------------------
// Transpose-split of U / V-flipped: AuT[c][k] = split(U[k][c]),
// AvT[c][k] = split(V[1023-k][c]). LDS 64x64 tile, vectorized both sides.
__global__ __launch_bounds__(256) void tsplUV_k(const float* __restrict__ U,
                                                const float* __restrict__ V,
                                                short* __restrict__ AuTh,
                                                short* __restrict__ AuTl,
                                                short* __restrict__ AvTh,
                                                short* __restrict__ AvTl) {
  __shared__ float tile[64][68];
  const int side = blockIdx.z;
  const int rb = blockIdx.y * 64, cb = blockIdx.x * 64;
  const int f = threadIdx.x;
  const float* S = side ? V : U;
#pragma unroll
  for (int ii = 0; ii < 4; ++ii) {
    int flat = f + ii * 256;
    int r = flat >> 4, c4 = (flat & 15) << 2;
    int rs = rb + r;
    if (side) rs = 1023 - rs;
    float4 v = *reinterpret_cast<const float4*>(S + (size_t)rs * DIM + cb + c4);
    tile[r][c4 + 0] = v.x; tile[r][c4 + 1] = v.y; tile[r][c4 + 2] = v.z; tile[r][c4 + 3] = v.w;
  }
  __syncthreads();
#pragma unroll
  for (int ii = 0; ii < 2; ++ii) {
    int flat = f + ii * 256;
    int cc = flat >> 3, r8 = (flat & 7) << 3;
    short8v vh, vl;
#pragma unroll
    for (int j = 0; j < 8; ++j) {
      float fv = tile[r8 + j][cc];
      short hh = f2bf(fv);
      vh[j] = hh;
      vl[j] = f2bf(fv - bf2f(hh));
    }
    size_t off = (size_t)(cb + cc) * DIM + rb + r8;
    *reinterpret_cast<short8v*>((side ? AvTh : AuTh) + off) = vh;
    *reinterpret_cast<short8v*>((side ? AvTl : AuTl) + off) = vl;
  }
}

// ---------------------------------------------------------------------------
// Transpose-split of the level-s diagonal T_B blocks into Tt bf16 mirrors:
// for pair p, block origin o = p*2s+s: Tt[o+c][o+k] = split(T[o+k][o+c]).
__global__ __launch_bounds__(256) void tspldiag_k(const float* __restrict__ Tu,
                                                  const float* __restrict__ Tv,
                                                  short* __restrict__ TtuH,
                                                  short* __restrict__ TtuL,
                                                  short* __restrict__ TtvH,
                                                  short* __restrict__ TtvL,
                                                  int s, int npair) {
  __shared__ float tile[64][68];
  const int z = blockIdx.z;
  const int side = z / npair, p = z % npair;
  const int o = p * 2 * s + s;
  const int rb = blockIdx.y * 64, cb = blockIdx.x * 64;
  const int f = threadIdx.x;
  const float* S = side ? Tv : Tu;
#pragma unroll
  for (int ii = 0; ii < 4; ++ii) {
    int flat = f + ii * 256;
    int r = flat >> 4, c4 = (flat & 15) << 2;
    float4 v = *reinterpret_cast<const float4*>(S + (size_t)(o + rb + r) * DIM + o + cb + c4);
    tile[r][c4 + 0] = v.x; tile[r][c4 + 1] = v.y; tile[r][c4 + 2] = v.z; tile[r][c4 + 3] = v.w;
  }
  __syncthreads();
#pragma unroll
  for (int ii = 0; ii < 2; ++ii) {
    int flat = f + ii * 256;
    int cc = flat >> 3, r8 = (flat & 7) << 3;
    short8v vh, vl;
#pragma unroll
    for (int j = 0; j < 8; ++j) {
      float fv = tile[r8 + j][cc];
      short hh = f2bf(fv);
      vh[j] = hh;
      vl[j] = f2bf(fv - bf2f(hh));
    }
    size_t off = (size_t)(o + cb + cc) * DIM + o + rb + r8;
    *reinterpret_cast<short8v*>((side ? TtvH : TtuH) + off) = vh;
    *reinterpret_cast<short8v*>((side ? TtvL : TtuL) + off) = vl;
  }
}

// ---------------------------------------------------------------------------
// Gram: G[m][n] = Au_m . Au_n (4-term split-bf16). z = side. (proven fast)
__global__ __launch_bounds__(256) void gram_k(const float* __restrict__ U,
                                              const float* __restrict__ V,
                                              const short* __restrict__ AuH,
                                              const short* __restrict__ AuL,
                                              const short* __restrict__ AvH,
                                              const short* __restrict__ AvL,
                                              float* __restrict__ Gu,
                                              float* __restrict__ Gv) {
  __shared__ short Ah[128][40], Al[128][40], Bh[128][40], Bl[128][40];
  const int side = blockIdx.z;
  const float* A = side ? V : U;
  const short* BH = side ? AvH : AuH;
  const short* BL = side ? AvL : AuL;
  float* G = side ? Gv : Gu;
  const int tid = threadIdx.x;
  const int bn = blockIdx.x, bm = blockIdx.y;
  const int wid = tid >> 6, wr = wid >> 1, wc = wid & 1;
  const int lane = tid & 63, l15 = lane & 15, k8 = (lane >> 4) << 3;
  f32x4 acc[4][4] = {};

  for (int kb = 0; kb < DIM; kb += 32) {
    __syncthreads();
#pragma unroll
    for (int ii = 0; ii < 4; ++ii) {
      int flat = tid + ii * 256;
      int r = flat >> 3, kq = (flat & 7) << 2;
      int rg = bm * 128 + r;
      int rs = side ? (1023 - rg) : rg;
      float4 v = *reinterpret_cast<const float4*>(A + (size_t)rs * DIM + kb + kq);
      short4v h, l;
      float fv[4] = {v.x, v.y, v.z, v.w};
#pragma unroll
      for (int j = 0; j < 4; ++j) {
        short hh = f2bf(fv[j]); h[j] = hh; l[j] = f2bf(fv[j] - bf2f(hh));
      }
      *reinterpret_cast<short4v*>(&Ah[r][kq]) = h;
      *reinterpret_cast<short4v*>(&Al[r][kq]) = l;
    }
#pragma unroll
    for (int ii = 0; ii < 2; ++ii) {
      int flat = tid + ii * 256;
      int n = flat >> 2, kk8 = (flat & 3) << 3;
      size_t off = (size_t)(bn * 128 + n) * DIM + kb + kk8;
      *reinterpret_cast<short8v*>(&Bh[n][kk8]) = *reinterpret_cast<const short8v*>(BH + off);
      *reinterpret_cast<short8v*>(&Bl[n][kk8]) = *reinterpret_cast<const short8v*>(BL + off);
    }
    __syncthreads();
    short8v ah[4], al_[4], bh[4], bl_[4];
#pragma unroll
    for (int m = 0; m < 4; ++m) {
      int r = wr * 64 + m * 16 + l15;
      ah[m] = *reinterpret_cast<const short8v*>(&Ah[r][k8]);
      al_[m] = *reinterpret_cast<const short8v*>(&Al[r][k8]);
    }
#pragma unroll
    for (int n = 0; n < 4; ++n) {
      int r = wc * 64 + n * 16 + l15;
      bh[n] = *reinterpret_cast<const short8v*>(&Bh[r][k8]);
      bl_[n] = *reinterpret_cast<const short8v*>(&Bl[r][k8]);
    }
#pragma unroll
    for (int m = 0; m < 4; ++m)
#pragma unroll
      for (int n = 0; n < 4; ++n) {
        acc[m][n] = __builtin_amdgcn_mfma_f32_16x16x32_bf16(ah[m], bh[n], acc[m][n], 0, 0, 0);
        acc[m][n] = __builtin_amdgcn_mfma_f32_16x16x32_bf16(ah[m], bl_[n], acc[m][n], 0, 0, 0);
        acc[m][n] = __builtin_amdgcn_mfma_f32_16x16x32_bf16(al_[m], bh[n], acc[m][n], 0, 0, 0);
        acc[m][n] = __builtin_amdgcn_mfma_f32_16x16x32_bf16(al_[m], bl_[n], acc[m][n], 0, 0, 0);
      }
  }
#pragma unroll
  for (int n = 0; n < 4; ++n) {
    int gcol = bn * 128 + wc * 64 + n * 16 + l15;
#pragma unroll
    for (int m = 0; m < 4; ++m) {
      int grow0 = bm * 128 + wr * 64 + m * 16 + ((lane >> 4) << 2);
#pragma unroll
      for (int j = 0; j < 4; ++j)
        G[(size_t)(grow0 + j) * DIM + gcol] = acc[m][n][j];
    }
  }
}

// ---------------------------------------------------------------------------
// 64x64 diagonal T blocks (proven). One wave per block.
__global__ __launch_bounds__(64) void tdiag_k(const float* __restrict__ Gu,
                                              const float* __restrict__ Gv,
                                              const float* __restrict__ tinu,
                                              const float* __restrict__ tinv,
                                              float* __restrict__ Tu,
                                              float* __restrict__ Tv) {
  __shared__ float S[64][68], Tl[64][68];
  int z = blockIdx.x >> 4;
  int d = blockIdx.x & 15;
  const float* G = z ? Gv : Gu;
  const float* tau = z ? tinv : tinu;
  float* T = z ? Tv : Tu;
  int b0 = d * 64;
  int lane = threadIdx.x;
#pragma unroll
  for (int j = 0; j < 64; j += 4) {
    *reinterpret_cast<float4*>(&S[lane][j]) =
        *reinterpret_cast<const float4*>(G + (size_t)(b0 + lane) * DIM + b0 + j);
    float4 zz = {0.f, 0.f, 0.f, 0.f};
    *reinterpret_cast<float4*>(&Tl[lane][j]) = zz;
  }
  __syncthreads();
  Tl[lane][lane] = tau[b0 + lane];
  __syncthreads();
  for (int k = 1; k < 64; ++k) {
    float tk = tau[b0 + k];
    float acc = 0.f;
    if (lane < k) {
      for (int m = lane; m < k; ++m) acc = fmaf(Tl[lane][m], S[m][k], acc);
    }
    __syncthreads();
    if (lane < k) Tl[lane][k] = -tk * acc;
    __syncthreads();
  }
#pragma unroll
  for (int j = 0; j < 64; j += 4)
    *reinterpret_cast<float4*>(T + (size_t)(b0 + lane) * DIM + b0 + j) =
        *reinterpret_cast<const float4*>(&Tl[lane][j]);
}

// ---------------------------------------------------------------------------
// Level s=64 combine, in-LDS (proven).
__global__ __launch_bounds__(256) void tcomb64_k(const float* __restrict__ Gu,
                                                 const float* __restrict__ Gv,
                                                 float* __restrict__ Tu,
                                                 float* __restrict__ Tv) {
  __shared__ float TA[64][68], SS[64][68], TB[64][68], W[64][68];
  int zz = blockIdx.x;
  int side = zz >> 3, p = zz & 7;
  int a0 = p * 128;
  const float* G = side ? Gv : Gu;
  float* T = side ? Tv : Tu;
  int tid = threadIdx.x;
#pragma unroll
  for (int ii = 0; ii < 4; ++ii) {
    int flat = tid + ii * 256;
    int r = flat >> 4, c4 = (flat & 15) << 2;
    *reinterpret_cast<float4*>(&TA[r][c4]) =
        *reinterpret_cast<const float4*>(T + (size_t)(a0 + r) * DIM + a0 + c4);
    *reinterpret_cast<float4*>(&SS[r][c4]) =
        *reinterpret_cast<const float4*>(G + (size_t)(a0 + r) * DIM + a0 + 64 + c4);
    *reinterpret_cast<float4*>(&TB[r][c4]) =
        *reinterpret_cast<const float4*>(T + (size_t)(a0 + 64 + r) * DIM + a0 + 64 + c4);
  }
  __syncthreads();
  int tx = tid & 15, ty = tid >> 4;
  float acc[4][4] = {};
  for (int k = 0; k < 64; ++k) {
    float a[4], b[4];
#pragma unroll
    for (int m = 0; m < 4; ++m) a[m] = SS[ty * 4 + m][k];
#pragma unroll
    for (int n = 0; n < 4; ++n) b[n] = TB[k][tx * 4 + n];
#pragma unroll
    for (int m = 0; m < 4; ++m)
#pragma unroll
      for (int n = 0; n < 4; ++n) acc[m][n] = fmaf(a[m], b[n], acc[m][n]);
  }
#pragma unroll
  for (int m = 0; m < 4; ++m)
#pragma unroll
    for (int n = 0; n < 4; ++n) W[ty * 4 + m][tx * 4 + n] = acc[m][n];
  __syncthreads();
  float acc2[4][4] = {};
  for (int k = 0; k < 64; ++k) {
    float a[4], b[4];
#pragma unroll
    for (int m = 0; m < 4; ++m) a[m] = TA[ty * 4 + m][k];
#pragma unroll
    for (int n = 0; n < 4; ++n) b[n] = W[k][tx * 4 + n];
#pragma unroll
    for (int m = 0; m < 4; ++m)
#pragma unroll
      for (int n = 0; n < 4; ++n) acc2[m][n] = fmaf(a[m], b[n], acc2[m][n]);
  }
#pragma unroll
  for (int m = 0; m < 4; ++m)
#pragma unroll
    for (int n = 0; n < 4; ++n)
      T[(size_t)(a0 + ty * 4 + m) * DIM + a0 + 64 + tx * 4 + n] = -acc2[m][n];
}

// ---------------------------------------------------------------------------
// Tree levels s>=128, no in-kernel transposes.
// stage1: TmpT = (S_AB @ T_B)^T bf16; A = G block f32, Bt = Tt diag bf16.
// stage2: T[a0..][a0+s..] = -T_A @ Tmp; A = T_A f32, Bt = TmpT bf16.
__global__ __launch_bounds__(256) void tcombgg_k(const float* __restrict__ Gu,
                                                 const float* __restrict__ Gv,
                                                 float* __restrict__ Tu,
                                                 float* __restrict__ Tv,
                                                 const short* __restrict__ TtuH,
                                                 const short* __restrict__ TtuL,
                                                 const short* __restrict__ TtvH,
                                                 const short* __restrict__ TtvL,
                                                 short* __restrict__ TmpTh,
                                                 short* __restrict__ TmpTl,
                                                 int s, int npair, int stage) {
  __shared__ short Ah[128][40], Al[128][40], Bh[128][40], Bl[128][40];
  const int z = blockIdx.z;
  const int side = z / npair, p = z % npair;
  const int a0 = p * 2 * s;
  const float* Ab;
  const short* BH; const short* BL;
  int ldb;
  if (stage == 1) {
    Ab = (side ? Gv : Gu) + (size_t)a0 * DIM + (a0 + s);
    BH = (side ? TtvH : TtuH) + (size_t)(a0 + s) * DIM + (a0 + s);
    BL = (side ? TtvL : TtuL) + (size_t)(a0 + s) * DIM + (a0 + s);
    ldb = DIM;
  } else {
    Ab = (side ? Tv : Tu) + (size_t)a0 * DIM + a0;
    BH = TmpTh + (size_t)z * s * s;
    BL = TmpTl + (size_t)z * s * s;
    ldb = s;
  }
  const int tid = threadIdx.x;
  const int bn = blockIdx.x, bm = blockIdx.y;
  const int wid = tid >> 6, wr = wid >> 1, wc = wid & 1;
  const int lane = tid & 63, l15 = lane & 15, k8 = (lane >> 4) << 3;
  f32x4 acc[4][4] = {};

  for (int kb = 0; kb < s; kb += 32) {
    __syncthreads();
#pragma unroll
    for (int ii = 0; ii < 4; ++ii) {
      int flat = tid + ii * 256;
      int r = flat >> 3, kq = (flat & 7) << 2;
      float4 v = *reinterpret_cast<const float4*>(Ab + (size_t)(bm * 128 + r) * DIM + kb + kq);
      short4v h, l;
      float fv[4] = {v.x, v.y, v.z, v.w};
#pragma unroll
      for (int j = 0; j < 4; ++j) {
        short hh = f2bf(fv[j]); h[j] = hh; l[j] = f2bf(fv[j] - bf2f(hh));
      }
      *reinterpret_cast<short4v*>(&Ah[r][kq]) = h;
      *reinterpret_cast<short4v*>(&Al[r][kq]) = l;
    }
#pragma unroll
    for (int ii = 0; ii < 2; ++ii) {
      int flat = tid + ii * 256;
      int n = flat >> 2, kk8 = (flat & 3) << 3;
      size_t off = (size_t)(bn * 128 + n) * ldb + kb + kk8;
      *reinterpret_cast<short8v*>(&Bh[n][kk8]) = *reinterpret_cast<const short8v*>(BH + off);
      *reinterpret_cast<short8v*>(&Bl[n][kk8]) = *reinterpret_cast<const short8v*>(BL + off);
    }
    __syncthreads();
    short8v ah[4], al_[4], bh[4], bl_[4];
#pragma unroll
    for (int m = 0; m < 4; ++m) {
      int r = wr * 64 + m * 16 + l15;
      ah[m] = *reinterpret_cast<const short8v*>(&Ah[r][k8]);
      al_[m] = *reinterpret_cast<const short8v*>(&Al[r][k8]);
    }
#pragma unroll
    for (int n = 0; n < 4; ++n) {
      int r = wc * 64 + n * 16 + l15;
      bh[n] = *reinterpret_cast<const short8v*>(&Bh[r][k8]);
      bl_[n] = *reinterpret_cast<const short8v*>(&Bl[r][k8]);
    }
#pragma unroll
    for (int m = 0; m < 4; ++m)
#pragma unroll
      for (int n = 0; n < 4; ++n) {
        acc[m][n] = __builtin_amdgcn_mfma_f32_16x16x32_bf16(ah[m], bh[n], acc[m][n], 0, 0, 0);
        acc[m][n] = __builtin_amdgcn_mfma_f32_16x16x32_bf16(ah[m], bl_[n], acc[m][n], 0, 0, 0);
        acc[m][n] = __builtin_amdgcn_mfma_f32_16x16x32_bf16(al_[m], bh[n], acc[m][n], 0, 0, 0);
      }
  }
  if (stage == 1) {
    size_t base = (size_t)z * s * s;
#pragma unroll
    for (int n = 0; n < 4; ++n) {
      int gcol = bn * 128 + wc * 64 + n * 16 + l15;
#pragma unroll
      for (int m = 0; m < 4; ++m) {
        int gk0 = bm * 128 + wr * 64 + m * 16 + ((lane >> 4) << 2);
        short4v h, l;
#pragma unroll
        for (int j = 0; j < 4; ++j) {
          float fv = acc[m][n][j];
          short hh = f2bf(fv);
          h[j] = hh;
          l[j] = f2bf(fv - bf2f(hh));
        }
        *reinterpret_cast<short4v*>(TmpTh + base + (size_t)gcol * s + gk0) = h;
        *reinterpret_cast<short4v*>(TmpTl + base + (size_t)gcol * s + gk0) = l;
      }
    }
  } else {
    float* T = side ? Tv : Tu;
    float* Cb = T + (size_t)a0 * DIM + (a0 + s);
#pragma unroll
    for (int n = 0; n < 4; ++n) {
      int gcol = bn * 128 + wc * 64 + n * 16 + l15;
#pragma unroll
      for (int m = 0; m < 4; ++m) {
        int grow0 = bm * 128 + wr * 64 + m * 16 + ((lane >> 4) << 2);
#pragma unroll
        for (int j = 0; j < 4; ++j)
          Cb[(size_t)(grow0 + j) * DIM + gcol] = -acc[m][n][j];
      }
    }
  }
}

// ---------------------------------------------------------------------------
// P = T @ Au ; A = T f32 natural, Bt = AuT/AvT bf16 [c][k].
// Output Pt = P^T f32 (float4 epilogue).
__global__ __launch_bounds__(256) void pgemm_k(const float* __restrict__ Tu,
                                               const float* __restrict__ Tv,
                                               const short* __restrict__ AuTh,
                                               const short* __restrict__ AuTl,
                                               const short* __restrict__ AvTh,
                                               const short* __restrict__ AvTl,
                                               float* __restrict__ Ptu,
                                               float* __restrict__ Ptv) {
  __shared__ short Ah[128][40], Al[128][40], Bh[128][40], Bl[128][40];
  const int side = blockIdx.z;
  const float* A = side ? Tv : Tu;
  const short* BH = side ? AvTh : AuTh;
  const short* BL = side ? AvTl : AuTl;
  float* Out = side ? Ptv : Ptu;
  const int tid = threadIdx.x;
  const int bn = blockIdx.x, bm = blockIdx.y;
  const int wid = tid >> 6, wr = wid >> 1, wc = wid & 1;
  const int lane = tid & 63, l15 = lane & 15, k8 = (lane >> 4) << 3;
  f32x4 acc[4][4] = {};

  for (int kb = 0; kb < DIM; kb += 32) {
    __syncthreads();
#pragma unroll
    for (int ii = 0; ii < 4; ++ii) {
      int flat = tid + ii * 256;
      int r = flat >> 3, kq = (flat & 7) << 2;
      float4 v = *reinterpret_cast<const float4*>(A + (size_t)(bm * 128 + r) * DIM + kb + kq);
      short4v h, l;
      float fv[4] = {v.x, v.y, v.z, v.w};
#pragma unroll
      for (int j = 0; j < 4; ++j) {
        short hh = f2bf(fv[j]); h[j] = hh; l[j] = f2bf(fv[j] - bf2f(hh));
      }
      *reinterpret_cast<short4v*>(&Ah[r][kq]) = h;
      *reinterpret_cast<short4v*>(&Al[r][kq]) = l;
    }
#pragma unroll
    for (int ii = 0; ii < 2; ++ii) {
      int flat = tid + ii * 256;
      int n = flat >> 2, kk8 = (flat & 3) << 3;
      size_t off = (size_t)(bn * 128 + n) * DIM + kb + kk8;
      *reinterpret_cast<short8v*>(&Bh[n][kk8]) = *reinterpret_cast<const short8v*>(BH + off);
      *reinterpret_cast<short8v*>(&Bl[n][kk8]) = *reinterpret_cast<const short8v*>(BL + off);
    }
    __syncthreads();
    short8v ah[4], al_[4], bh[4], bl_[4];
#pragma unroll
    for (int m = 0; m < 4; ++m) {
      int r = wr * 64 + m * 16 + l15;
      ah[m] = *reinterpret_cast<const short8v*>(&Ah[r][k8]);
      al_[m] = *reinterpret_cast<const short8v*>(&Al[r][k8]);
    }
#pragma unroll
    for (int n = 0; n < 4; ++n) {
      int r = wc * 64 + n * 16 + l15;
      bh[n] = *reinterpret_cast<const short8v*>(&Bh[r][k8]);
      bl_[n] = *reinterpret_cast<const short8v*>(&Bl[r][k8]);
    }
#pragma unroll
    for (int m = 0; m < 4; ++m)
#pragma unroll
      for (int n = 0; n < 4; ++n) {
        acc[m][n] = __builtin_amdgcn_mfma_f32_16x16x32_bf16(ah[m], bh[n], acc[m][n], 0, 0, 0);
        acc[m][n] = __builtin_amdgcn_mfma_f32_16x16x32_bf16(ah[m], bl_[n], acc[m][n], 0, 0, 0);
        acc[m][n] = __builtin_amdgcn_mfma_f32_16x16x32_bf16(al_[m], bh[n], acc[m][n], 0, 0, 0);
      }
  }
#pragma unroll
  for (int n = 0; n < 4; ++n) {
    int gcol = bn * 128 + wc * 64 + n * 16 + l15;
#pragma unroll
    for (int m = 0; m < 4; ++m) {
      int grow0 = bm * 128 + wr * 64 + m * 16 + ((lane >> 4) << 2);
      float4 o;
      o.x = acc[m][n][0]; o.y = acc[m][n][1]; o.z = acc[m][n][2]; o.w = acc[m][n][3];
      *reinterpret_cast<float4*>(Out + (size_t)gcol * DIM + grow0) = o;
    }
  }
}

// ---------------------------------------------------------------------------
// Nt = N^T: A = Pt f32, Bt = AuT/AvT bf16. Epilogues:
// side0: Qu'[gcol][row] = (del - Nt)*sg[row] bf16 hi/lo (short4v along row);
// side1: Qvt[row][gcol] = del - Nt (f32 natural).
__global__ __launch_bounds__(256) void ngemm_k(const float* __restrict__ Ptu,
                                               const float* __restrict__ Ptv,
                                               const short* __restrict__ AuTh,
                                               const short* __restrict__ AuTl,
                                               const short* __restrict__ AvTh,
                                               const short* __restrict__ AvTl,
                                               const float* __restrict__ sg,
                                               short* __restrict__ QupH,
                                               short* __restrict__ QupL,
                                               float* __restrict__ Qvt) {
  __shared__ short Ah[128][40], Al[128][40], Bh[128][40], Bl[128][40];
  const int side = blockIdx.z;
  const float* A = side ? Ptv : Ptu;
  const short* BH = side ? AvTh : AuTh;
  const short* BL = side ? AvTl : AuTl;
  const int tid = threadIdx.x;
  const int bn = blockIdx.x, bm = blockIdx.y;
  const int wid = tid >> 6, wr = wid >> 1, wc = wid & 1;
  const int lane = tid & 63, l15 = lane & 15, k8 = (lane >> 4) << 3;
  f32x4 acc[4][4] = {};

  for (int kb = 0; kb < DIM; kb += 32) {
    __syncthreads();
#pragma unroll
    for (int ii = 0; ii < 4; ++ii) {
      int flat = tid + ii * 256;
      int r = flat >> 3, kq = (flat & 7) << 2;
      float4 v = *reinterpret_cast<const float4*>(A + (size_t)(bm * 128 + r) * DIM + kb + kq);
      short4v h, l;
      float fv[4] = {v.x, v.y, v.z, v.w};
#pragma unroll
      for (int j = 0; j < 4; ++j) {
        short hh = f2bf(fv[j]); h[j] = hh; l[j] = f2bf(fv[j] - bf2f(hh));
      }
      *reinterpret_cast<short4v*>(&Ah[r][kq]) = h;
      *reinterpret_cast<short4v*>(&Al[r][kq]) = l;
    }
#pragma unroll
    for (int ii = 0; ii < 2; ++ii) {
      int flat = tid + ii * 256;
      int n = flat >> 2, kk8 = (flat & 3) << 3;
      size_t off = (size_t)(bn * 128 + n) * DIM + kb + kk8;
      *reinterpret_cast<short8v*>(&Bh[n][kk8]) = *reinterpret_cast<const short8v*>(BH + off);
      *reinterpret_cast<short8v*>(&Bl[n][kk8]) = *reinterpret_cast<const short8v*>(BL + off);
    }
    __syncthreads();
    short8v ah[4], al_[4], bh[4], bl_[4];
#pragma unroll
    for (int m = 0; m < 4; ++m) {
      int r = wr * 64 + m * 16 + l15;
      ah[m] = *reinterpret_cast<const short8v*>(&Ah[r][k8]);
      al_[m] = *reinterpret_cast<const short8v*>(&Al[r][k8]);
    }
#pragma unroll
    for (int n = 0; n < 4; ++n) {
      int r = wc * 64 + n * 16 + l15;
      bh[n] = *reinterpret_cast<const short8v*>(&Bh[r][k8]);
      bl_[n] = *reinterpret_cast<const short8v*>(&Bl[r][k8]);
    }
#pragma unroll
    for (int m = 0; m < 4; ++m)
#pragma unroll
      for (int n = 0; n < 4; ++n) {
        acc[m][n] = __builtin_amdgcn_mfma_f32_16x16x32_bf16(ah[m], bh[n], acc[m][n], 0, 0, 0);
        acc[m][n] = __builtin_amdgcn_mfma_f32_16x16x32_bf16(ah[m], bl_[n], acc[m][n], 0, 0, 0);
        acc[m][n] = __builtin_amdgcn_mfma_f32_16x16x32_bf16(al_[m], bh[n], acc[m][n], 0, 0, 0);
      }
  }
#pragma unroll
  for (int n = 0; n < 4; ++n) {
    int gcol = bn * 128 + wc * 64 + n * 16 + l15;
#pragma unroll
    for (int m = 0; m < 4; ++m) {
      int grow0 = bm * 128 + wr * 64 + m * 16 + ((lane >> 4) << 2);
      if (side == 0) {
        short4v h, l;
#pragma unroll
        for (int j = 0; j < 4; ++j) {
          int row = grow0 + j;
          float del = (row == gcol) ? 1.0f : 0.0f;
          float q = (del - acc[m][n][j]) * sg[row];
          short hh = f2bf(q);
          h[j] = hh;
          l[j] = f2bf(q - bf2f(hh));
        }
        *reinterpret_cast<short4v*>(QupH + (size_t)gcol * DIM + grow0) = h;
        *reinterpret_cast<short4v*>(QupL + (size_t)gcol * DIM + grow0) = l;
      } else {
#pragma unroll
        for (int j = 0; j < 4; ++j) {
          int row = grow0 + j;
          float del = (row == gcol) ? 1.0f : 0.0f;
          Qvt[(size_t)row * DIM + gcol] = del - acc[m][n][j];
        }
      }
    }
  }
}

// ---------------------------------------------------------------------------
// MT = M^T = Qv^T @ Qu'^T : A = Qvt f32, Bt = Qu' bf16. Natural bf16 store.
__global__ __launch_bounds__(256) void mgemm2_k(const float* __restrict__ Qvt,
                                                const short* __restrict__ QupH,
                                                const short* __restrict__ QupL,
                                                short* __restrict__ MTh,
                                                short* __restrict__ MTl) {
  __shared__ short Ah[128][40], Al[128][40], Bh[128][40], Bl[128][40];
  const int tid = threadIdx.x;
  const int bn = blockIdx.x, bm = blockIdx.y;
  const int wid = tid >> 6, wr = wid >> 1, wc = wid & 1;
  const int lane = tid & 63, l15 = lane & 15, k8 = (lane >> 4) << 3;
  f32x4 acc[4][4] = {};

  for (int kb = 0; kb < DIM; kb += 32) {
    __syncthreads();
#pragma unroll
    for (int ii = 0; ii < 4; ++ii) {
      int flat = tid + ii * 256;
      int r = flat >> 3, kq = (flat & 7) << 2;
      float4 v = *reinterpret_cast<const float4*>(Qvt + (size_t)(bm * 128 + r) * DIM + kb + kq);
      short4v h, l;
      float fv[4] = {v.x, v.y, v.z, v.w};
#pragma unroll
      for (int j = 0; j < 4; ++j) {
        short hh = f2bf(fv[j]); h[j] = hh; l[j] = f2bf(fv[j] - bf2f(hh));
      }
      *reinterpret_cast<short4v*>(&Ah[r][kq]) = h;
      *reinterpret_cast<short4v*>(&Al[r][kq]) = l;
    }
#pragma unroll
    for (int ii = 0; ii < 2; ++ii) {
      int flat = tid + ii * 256;
      int n = flat >> 2, kk8 = (flat & 3) << 3;
      size_t off = (size_t)(bn * 128 + n) * DIM + kb + kk8;
      *reinterpret_cast<short8v*>(&Bh[n][kk8]) = *reinterpret_cast<const short8v*>(QupH + off);
      *reinterpret_cast<short8v*>(&Bl[n][kk8]) = *reinterpret_cast<const short8v*>(QupL + off);
    }
    __syncthreads();
    short8v ah[4], al_[4], bh[4], bl_[4];
#pragma unroll
    for (int m = 0; m < 4; ++m) {
      int r = wr * 64 + m * 16 + l15;
      ah[m] = *reinterpret_cast<const short8v*>(&Ah[r][k8]);
      al_[m] = *reinterpret_cast<const short8v*>(&Al[r][k8]);
    }
#pragma unroll
    for (int n = 0; n < 4; ++n) {
      int r = wc * 64 + n * 16 + l15;
      bh[n] = *reinterpret_cast<const short8v*>(&Bh[r][k8]);
      bl_[n] = *reinterpret_cast<const short8v*>(&Bl[r][k8]);
    }
#pragma unroll
    for (int m = 0; m < 4; ++m)
#pragma unroll
      for (int n = 0; n < 4; ++n) {
        acc[m][n] = __builtin_amdgcn_mfma_f32_16x16x32_bf16(ah[m], bh[n], acc[m][n], 0, 0, 0);
        acc[m][n] = __builtin_amdgcn_mfma_f32_16x16x32_bf16(ah[m], bl_[n], acc[m][n], 0, 0, 0);
        acc[m][n] = __builtin_amdgcn_mfma_f32_16x16x32_bf16(al_[m], bh[n], acc[m][n], 0, 0, 0);
      }
  }
#pragma unroll
  for (int n = 0; n < 4; ++n) {
    int gcol = bn * 128 + wc * 64 + n * 16 + l15;
#pragma unroll
    for (int m = 0; m < 4; ++m) {
      int grow0 = bm * 128 + wr * 64 + m * 16 + ((lane >> 4) << 2);
#pragma unroll
      for (int j = 0; j < 4; ++j) {
        float fv = acc[m][n][j];
        short hh = f2bf(fv);
        MTh[(size_t)(grow0 + j) * DIM + gcol] = hh;
        MTl[(size_t)(grow0 + j) * DIM + gcol] = f2bf(fv - bf2f(hh));
      }
    }
  }
}

// ---------------------------------------------------------------------------
// out[4096,1024] = x @ M + bias (proven).
__global__ __launch_bounds__(256) void gemm_mfma_k(const float* __restrict__ x,
                                                   const short* __restrict__ Bthi,
                                                   const short* __restrict__ Btlo,
                                                   const float* __restrict__ bias,
                                                   float* __restrict__ out) {
  __shared__ short Ah[128][40], Al[128][40], Bh[128][40], Bl[128][40];
  const int tid = threadIdx.x;
  const int bn = blockIdx.x, bm = blockIdx.y;
  const int wid = tid >> 6, wr = wid >> 1, wc = wid & 1;
  const int lane = tid & 63, l15 = lane & 15, k8 = (lane >> 4) << 3;
  f32x4 acc[4][4] = {};

  for (int kb = 0; kb < DIM; kb += 32) {
    __syncthreads();
#pragma unroll
    for (int ii = 0; ii < 4; ++ii) {
      int flat = tid + ii * 256;
      int r = flat >> 3, kq = (flat & 7) << 2;
      float4 v = *reinterpret_cast<const float4*>(x + (size_t)(bm * 128 + r) * DIM + kb + kq);
      short4v h, l;
      float fv[4] = {v.x, v.y, v.z, v.w};
#pragma unroll
      for (int j = 0; j < 4; ++j) {
        short hh = f2bf(fv[j]); h[j] = hh; l[j] = f2bf(fv[j] - bf2f(hh));
      }
      *reinterpret_cast<short4v*>(&Ah[r][kq]) = h;
      *reinterpret_cast<short4v*>(&Al[r][kq]) = l;
    }
#pragma unroll
    for (int ii = 0; ii < 2; ++ii) {
      int flat = tid + ii * 256;
      int n = flat >> 2, kk8 = (flat & 3) << 3;
      size_t off = (size_t)(bn * 128 + n) * DIM + kb + kk8;
      *reinterpret_cast<short8v*>(&Bh[n][kk8]) = *reinterpret_cast<const short8v*>(Bthi + off);
      *reinterpret_cast<short8v*>(&Bl[n][kk8]) = *reinterpret_cast<const short8v*>(Btlo + off);
    }
    __syncthreads();
    short8v ah[4], al_[4], bh[4], bl_[4];
#pragma unroll
    for (int m = 0; m < 4; ++m) {
      int r = wr * 64 + m * 16 + l15;
      ah[m] = *reinterpret_cast<const short8v*>(&Ah[r][k8]);
      al_[m] = *reinterpret_cast<const short8v*>(&Al[r][k8]);
    }
#pragma unroll
    for (int n = 0; n < 4; ++n) {
      int r = wc * 64 + n * 16 + l15;
      bh[n] = *reinterpret_cast<const short8v*>(&Bh[r][k8]);
      bl_[n] = *reinterpret_cast<const short8v*>(&Bl[r][k8]);
    }
#pragma unroll
    for (int m = 0; m < 4; ++m)
#pragma unroll
      for (int n = 0; n < 4; ++n) {
        acc[m][n] = __builtin_amdgcn_mfma_f32_16x16x32_bf16(ah[m], bh[n], acc[m][n], 0, 0, 0);
        acc[m][n] = __builtin_amdgcn_mfma_f32_16x16x32_bf16(ah[m], bl_[n], acc[m][n], 0, 0, 0);
        acc[m][n] = __builtin_amdgcn_mfma_f32_16x16x32_bf16(al_[m], bh[n], acc[m][n], 0, 0, 0);
      }
  }
#pragma unroll
  for (int n = 0; n < 4; ++n) {
    int gcol = bn * 128 + wc * 64 + n * 16 + l15;
    float bv = bias[gcol];
#pragma unroll
    for (int m = 0; m < 4; ++m) {
      int grow0 = bm * 128 + wr * 64 + m * 16 + ((lane >> 4) << 2);
#pragma unroll
      for (int j = 0; j < 4; ++j)
        out[(size_t)(grow0 + j) * DIM + gcol] = acc[m][n][j] + bv;
    }
  }
}

// ---------------------------------------------------------------------------
extern "C" void kernel_launch(void* const* d_in, const int* in_sizes, int n_in,
                              void* d_out, int out_size, void* d_ws, size_t ws_size,
                              hipStream_t stream) {
  const float* x    = (const float*)d_in[0];
  const float* U    = (const float*)d_in[1];
  const float* V    = (const float*)d_in[2];
  const float* p    = (const float*)d_in[3];
  const float* bias = (const float*)d_in[4];
  float* out = (float*)d_out;

  float* F = (float*)d_ws;
  // Layout (float offsets), peak 10.5M floats = 42 MB:
  // [0,2M)    AuH/AuL/AvH/AvL (gram only) -> after gram: QupH/QupL/Qvt
  // [2M,4M)   Gu,Gv -> Ptu,Ptv (after last stage1)
  // [4M,6M)   Tu,Tv f32 -> MTh/MTl overlay Tu after pgemm
  // [6M,8M)   TtuH/TtuL/TtvH/TtvL (diag-block bf16 mirrors)
  // [8M,10M)  AuTh/AuTl/AvTh/AvTl
  // [10M,10.5M) TmpTh/TmpTl
  // [10.5M+)  smalls
  short* AuH  = (short*)F;
  short* AuL  = AuH + 1048576;
  short* AvH  = AuL + 1048576;
  short* AvL  = AvH + 1048576;
  short* QupH = AuH;                  // overlay after gram
  short* QupL = AuL;
  float* Qvt  = F + 1048576;          // overlays AvH/AvL
  float* Gu   = F + 2097152;
  float* Gv   = F + 3145728;
  float* Ptu  = Gu;                   // overlay after tree
  float* Ptv  = Gv;
  float* Tu   = F + 4194304;
  float* Tv   = F + 5242880;
  short* MTh  = (short*)Tu;           // overlay after pgemm
  short* MTl  = MTh + 1048576;
  short* TtuH = (short*)(F + 6291456);
  short* TtuL = TtuH + 1048576;
  short* TtvH = TtuL + 1048576;
  short* TtvL = TtvH + 1048576;
  short* AuTh = (short*)(F + 8388608);
  short* AuTl = AuTh + 1048576;
  short* AvTh = AuTl + 1048576;
  short* AvTl = AvTh + 1048576;
  short* TmpTh = (short*)(F + 10485760);
  short* TmpTl = TmpTh + 524288;
  float* tinu = F + 11010048;
  float* tinv = tinu + DIM;
  float* sg   = tinv + DIM;

  prep_k<<<512, 256, 0, stream>>>(U, V, tinu, tinv);
  sig_k<<<4, 256, 0, stream>>>(p, sg);
  asplit_k<<<1024, 256, 0, stream>>>(U, V, AuH, AuL, AvH, AvL);
  tsplUV_k<<<dim3(16, 16, 2), 256, 0, stream>>>(U, V, AuTh, AuTl, AvTh, AvTl);
  gram_k<<<dim3(8, 8, 2), 256, 0, stream>>>(U, V, AuH, AuL, AvH, AvL, Gu, Gv);
  hipMemsetAsync(Tu, 0, (size_t)2 * 1048576 * sizeof(float), stream);  // Tu|Tv
  tdiag_k<<<32, 64, 0, stream>>>(Gu, Gv, tinu, tinv, Tu, Tv);
  tcomb64_k<<<16, 256, 0, stream>>>(Gu, Gv, Tu, Tv);
  tspldiag_k<<<dim3(2, 2, 8), 256, 0, stream>>>(Tu, Tv, TtuH, TtuL, TtvH, TtvL, 128, 4);
  tcombgg_k<<<dim3(1, 1, 8), 256, 0, stream>>>(Gu, Gv, Tu, Tv, TtuH, TtuL, TtvH, TtvL, TmpTh, TmpTl, 128, 4, 1);
  tcombgg_k<<<dim3(1, 1, 8), 256, 0, stream>>>(Gu, Gv, Tu, Tv, TtuH, TtuL, TtvH, TtvL, TmpTh, TmpTl, 128, 4, 2);
  tspldiag_k<<<dim3(4, 4, 4), 256, 0, stream>>>(Tu, Tv, TtuH, TtuL, TtvH, TtvL, 256, 2);
  tcombgg_k<<<dim3(2, 2, 4), 256, 0, stream>>>(Gu, Gv, Tu, Tv, TtuH, TtuL, TtvH, TtvL, TmpTh, TmpTl, 256, 2, 1);
  tcombgg_k<<<dim3(2, 2, 4), 256, 0, stream>>>(Gu, Gv, Tu, Tv, TtuH, TtuL, TtvH, TtvL, TmpTh, TmpTl, 256, 2, 2);
  tspldiag_k<<<dim3(8, 8, 2), 256, 0, stream>>>(Tu, Tv, TtuH, TtuL, TtvH, TtvL, 512, 1);
  tcombgg_k<<<dim3(4, 4, 2), 256, 0, stream>>>(Gu, Gv, Tu, Tv, TtuH, TtuL, TtvH, TtvL, TmpTh, TmpTl, 512, 1, 1);
  tcombgg_k<<<dim3(4, 4, 2), 256, 0, stream>>>(Gu, Gv, Tu, Tv, TtuH, TtuL, TtvH, TtvL, TmpTh, TmpTl, 512, 1, 2);
  pgemm_k<<<dim3(8, 8, 2), 256, 0, stream>>>(Tu, Tv, AuTh, AuTl, AvTh, AvTl, Ptu, Ptv);
  ngemm_k<<<dim3(8, 8, 2), 256, 0, stream>>>(Ptu, Ptv, AuTh, AuTl, AvTh, AvTl, sg, QupH, QupL, Qvt);
  mgemm2_k<<<dim3(8, 8), 256, 0, stream>>>(Qvt, QupH, QupL, MTh, MTl);
  gemm_mfma_k<<<dim3(8, 32), 256, 0, stream>>>(x, MTh, MTl, bias, out);
}

// Round 13
// 416.449 us; speedup vs baseline: 1.7904x; 1.1809x over previous
//
#include <hip/hip_runtime.h>

#define DIM 1024
#define BATCH 4096

typedef __attribute__((ext_vector_type(8))) short short8v;
typedef __attribute__((ext_vector_type(4))) short short4v;
typedef __attribute__((ext_vector_type(4))) float f32x4;

// ---------------------------------------------------------------------------
__device__ __forceinline__ float dpp_reduce_bcast(float x) {
  int v = __builtin_bit_cast(int, x);
#define DPP_STEP(ctrl)                                                        \
  {                                                                           \
    int s = __builtin_amdgcn_update_dpp(0, v, ctrl, 0xf, 0xf, true);          \
    v = __builtin_bit_cast(                                                   \
        int, __builtin_bit_cast(float, v) + __builtin_bit_cast(float, s));    \
  }
  DPP_STEP(0x111) DPP_STEP(0x112) DPP_STEP(0x114) DPP_STEP(0x118)
  DPP_STEP(0x142) DPP_STEP(0x143)
#undef DPP_STEP
  return __builtin_bit_cast(float, __builtin_amdgcn_readlane(v, 63));
}

__device__ __forceinline__ short f2bf(float f) {
  unsigned u = __builtin_bit_cast(unsigned, f);
  u += 0x7FFFu + ((u >> 16) & 1u);
  return (short)(u >> 16);
}
__device__ __forceinline__ float bf2f(short h) {
  unsigned u = ((unsigned)(unsigned short)h) << 16;
  return __builtin_bit_cast(float, u);
}

// ---------------------------------------------------------------------------
// tau[m] = 2/||row m||^2 (U: row m; V: row 1023-m). Fused: sg sigmoid map.
__global__ __launch_bounds__(256) void prep_k(const float* __restrict__ U,
                                              const float* __restrict__ V,
                                              const float* __restrict__ p,
                                              float* __restrict__ tinu,
                                              float* __restrict__ tinv,
                                              float* __restrict__ sg) {
  int gi = blockIdx.x * 256 + threadIdx.x;
  if (gi < DIM) sg[gi] = 0.1f + 0.9f / (1.0f + __expf(-p[gi]));
  int gw = gi >> 6;
  int lane = threadIdx.x & 63;
  if (gw >= 2048) return;
  const float* src = (gw < 1024) ? (U + (size_t)gw * DIM)
                                 : (V + (size_t)(1023 - (gw - 1024)) * DIM);
  float s = 0.f;
#pragma unroll
  for (int q = 0; q < 4; ++q) {
    float4 v = *reinterpret_cast<const float4*>(src + q * 256 + lane * 4);
    s += v.x * v.x + v.y * v.y + v.z * v.z + v.w * v.w;
  }
  float tot = dpp_reduce_bcast(s);
  if (lane == 0) {
    float val = 2.0f / tot;
    if (gw < 1024) tinu[gw] = val; else tinv[gw - 1024] = val;
  }
}

// ---------------------------------------------------------------------------
// Natural-layout bf16 hi/lo splits of Au = U and Av = rows-of-V-reversed.
__global__ __launch_bounds__(256) void asplit_k(const float* __restrict__ U,
                                                const float* __restrict__ V,
                                                short* __restrict__ AuH,
                                                short* __restrict__ AuL,
                                                short* __restrict__ AvH,
                                                short* __restrict__ AvL) {
  int e = (blockIdx.x * 256 + threadIdx.x) * 8;
  int side = e >> 20;
  int idx = e & 1048575;
  int r = idx >> 10, c = idx & 1023;
  const float* src = side ? (V + (size_t)(1023 - r) * DIM + c)
                          : (U + (size_t)r * DIM + c);
  float4 a = *reinterpret_cast<const float4*>(src);
  float4 b = *reinterpret_cast<const float4*>(src + 4);
  float fv[8] = {a.x, a.y, a.z, a.w, b.x, b.y, b.z, b.w};
  short8v h, l;
#pragma unroll
  for (int j = 0; j < 8; ++j) {
    short hh = f2bf(fv[j]);
    h[j] = hh;
    l[j] = f2bf(fv[j] - bf2f(hh));
  }
  *reinterpret_cast<short8v*>((side ? AvH : AuH) + idx) = h;
  *reinterpret_cast<short8v*>((side ? AvL : AuL) + idx) = l;
}

// ---------------------------------------------------------------------------
// Transpose-split of U / V-flipped: AuT[c][k] = split(U[k][c]),
// AvT[c][k] = split(V[1023-k][c]).
__global__ __launch_bounds__(256) void tsplUV_k(const float* __restrict__ U,
                                                const float* __restrict__ V,
                                                short* __restrict__ AuTh,
                                                short* __restrict__ AuTl,
                                                short* __restrict__ AvTh,
                                                short* __restrict__ AvTl) {
  __shared__ float tile[64][68];
  const int side = blockIdx.z;
  const int rb = blockIdx.y * 64, cb = blockIdx.x * 64;
  const int f = threadIdx.x;
  const float* S = side ? V : U;
#pragma unroll
  for (int ii = 0; ii < 4; ++ii) {
    int flat = f + ii * 256;
    int r = flat >> 4, c4 = (flat & 15) << 2;
    int rs = rb + r;
    if (side) rs = 1023 - rs;
    float4 v = *reinterpret_cast<const float4*>(S + (size_t)rs * DIM + cb + c4);
    tile[r][c4 + 0] = v.x; tile[r][c4 + 1] = v.y; tile[r][c4 + 2] = v.z; tile[r][c4 + 3] = v.w;
  }
  __syncthreads();
#pragma unroll
  for (int ii = 0; ii < 2; ++ii) {
    int flat = f + ii * 256;
    int cc = flat >> 3, r8 = (flat & 7) << 3;
    short8v vh, vl;
#pragma unroll
    for (int j = 0; j < 8; ++j) {
      float fv = tile[r8 + j][cc];
      short hh = f2bf(fv);
      vh[j] = hh;
      vl[j] = f2bf(fv - bf2f(hh));
    }
    size_t off = (size_t)(cb + cc) * DIM + rb + r8;
    *reinterpret_cast<short8v*>((side ? AvTh : AuTh) + off) = vh;
    *reinterpret_cast<short8v*>((side ? AvTl : AuTl) + off) = vl;
  }
}

// ---------------------------------------------------------------------------
// Gram: G[m][n] = Au_m . Au_n (3-term split-bf16; lo*lo ~2^-32 negligible).
__global__ __launch_bounds__(256) void gram_k(const float* __restrict__ U,
                                              const float* __restrict__ V,
                                              const short* __restrict__ AuH,
                                              const short* __restrict__ AuL,
                                              const short* __restrict__ AvH,
                                              const short* __restrict__ AvL,
                                              float* __restrict__ Gu,
                                              float* __restrict__ Gv) {
  __shared__ short Ah[128][40], Al[128][40], Bh[128][40], Bl[128][40];
  const int side = blockIdx.z;
  const float* A = side ? V : U;
  const short* BH = side ? AvH : AuH;
  const short* BL = side ? AvL : AuL;
  float* G = side ? Gv : Gu;
  const int tid = threadIdx.x;
  const int bn = blockIdx.x, bm = blockIdx.y;
  const int wid = tid >> 6, wr = wid >> 1, wc = wid & 1;
  const int lane = tid & 63, l15 = lane & 15, k8 = (lane >> 4) << 3;
  f32x4 acc[4][4] = {};

  for (int kb = 0; kb < DIM; kb += 32) {
    __syncthreads();
#pragma unroll
    for (int ii = 0; ii < 4; ++ii) {
      int flat = tid + ii * 256;
      int r = flat >> 3, kq = (flat & 7) << 2;
      int rg = bm * 128 + r;
      int rs = side ? (1023 - rg) : rg;
      float4 v = *reinterpret_cast<const float4*>(A + (size_t)rs * DIM + kb + kq);
      short4v h, l;
      float fv[4] = {v.x, v.y, v.z, v.w};
#pragma unroll
      for (int j = 0; j < 4; ++j) {
        short hh = f2bf(fv[j]); h[j] = hh; l[j] = f2bf(fv[j] - bf2f(hh));
      }
      *reinterpret_cast<short4v*>(&Ah[r][kq]) = h;
      *reinterpret_cast<short4v*>(&Al[r][kq]) = l;
    }
#pragma unroll
    for (int ii = 0; ii < 2; ++ii) {
      int flat = tid + ii * 256;
      int n = flat >> 2, kk8 = (flat & 3) << 3;
      size_t off = (size_t)(bn * 128 + n) * DIM + kb + kk8;
      *reinterpret_cast<short8v*>(&Bh[n][kk8]) = *reinterpret_cast<const short8v*>(BH + off);
      *reinterpret_cast<short8v*>(&Bl[n][kk8]) = *reinterpret_cast<const short8v*>(BL + off);
    }
    __syncthreads();
    short8v ah[4], al_[4], bh[4], bl_[4];
#pragma unroll
    for (int m = 0; m < 4; ++m) {
      int r = wr * 64 + m * 16 + l15;
      ah[m] = *reinterpret_cast<const short8v*>(&Ah[r][k8]);
      al_[m] = *reinterpret_cast<const short8v*>(&Al[r][k8]);
    }
#pragma unroll
    for (int n = 0; n < 4; ++n) {
      int r = wc * 64 + n * 16 + l15;
      bh[n] = *reinterpret_cast<const short8v*>(&Bh[r][k8]);
      bl_[n] = *reinterpret_cast<const short8v*>(&Bl[r][k8]);
    }
#pragma unroll
    for (int m = 0; m < 4; ++m)
#pragma unroll
      for (int n = 0; n < 4; ++n) {
        acc[m][n] = __builtin_amdgcn_mfma_f32_16x16x32_bf16(ah[m], bh[n], acc[m][n], 0, 0, 0);
        acc[m][n] = __builtin_amdgcn_mfma_f32_16x16x32_bf16(ah[m], bl_[n], acc[m][n], 0, 0, 0);
        acc[m][n] = __builtin_amdgcn_mfma_f32_16x16x32_bf16(al_[m], bh[n], acc[m][n], 0, 0, 0);
      }
  }
#pragma unroll
  for (int n = 0; n < 4; ++n) {
    int gcol = bn * 128 + wc * 64 + n * 16 + l15;
#pragma unroll
    for (int m = 0; m < 4; ++m) {
      int grow0 = bm * 128 + wr * 64 + m * 16 + ((lane >> 4) << 2);
#pragma unroll
      for (int j = 0; j < 4; ++j)
        G[(size_t)(grow0 + j) * DIM + gcol] = acc[m][n][j];
    }
  }
}

// ---------------------------------------------------------------------------
// 64x64 diagonal T blocks via recursive in-LDS triangular inversion:
// T = B^{-1}, B = diag(1/tau) + strict_upper(G). Base 4x4 direct inverse,
// levels 4->8->16->32->64 via X = -TA (SAB TB), all element-parallel.
// Writes T f32 + bf16 transposed mirror. One 256-thread WG per block.
__global__ __launch_bounds__(256) void tdiag64_k(const float* __restrict__ Gu,
                                                 const float* __restrict__ Gv,
                                                 const float* __restrict__ tinu,
                                                 const float* __restrict__ tinv,
                                                 float* __restrict__ Tu,
                                                 float* __restrict__ Tv,
                                                 short* __restrict__ TtuH,
                                                 short* __restrict__ TtuL,
                                                 short* __restrict__ TtvH,
                                                 short* __restrict__ TtvL) {
  __shared__ float B[64][65];
  __shared__ float T[64][65];
  __shared__ float Wb[1024];
  int z = blockIdx.x >> 4;
  int d = blockIdx.x & 15;
  const float* G = z ? Gv : Gu;
  const float* tau = z ? tinv : tinu;
  float* Tg = z ? Tv : Tu;
  short* TH = z ? TtvH : TtuH;
  short* TL = z ? TtvL : TtuL;
  int b0 = d * 64;
  int tid = threadIdx.x;

  for (int e = tid; e < 4096; e += 256) {
    int r = e >> 6, c = e & 63;
    float v;
    if (r < c) v = G[(size_t)(b0 + r) * DIM + b0 + c];
    else if (r == c) v = 1.0f / tau[b0 + r];
    else v = 0.f;
    B[r][c] = v;
    T[r][c] = 0.f;
  }
  __syncthreads();

  // base: invert 16 4x4 upper-tri blocks; thread t<16 -> block t.
  if (tid < 16) {
    int o = tid * 4;
    float X[4][4];
#pragma unroll
    for (int k = 0; k < 4; ++k) {
      X[k][k] = 1.0f / B[o + k][o + k];
#pragma unroll
      for (int i = 2; i >= 0; --i) {
        if (i < k) {
          float s = 0.f;
#pragma unroll
          for (int j = 0; j < 4; ++j)
            if (j > i && j <= k) s = fmaf(B[o + i][o + j], X[j][k], s);
          X[i][k] = -s / B[o + i][o + i];
        }
      }
    }
#pragma unroll
    for (int k = 0; k < 4; ++k)
#pragma unroll
      for (int i = 0; i < 4; ++i)
        if (i <= k) T[o + i][o + k] = X[i][k];
  }
  __syncthreads();

  // recursive doubling: s = 4,8,16,32
  for (int s = 4; s <= 32; s <<= 1) {
    int ss = s * s;
    int tot = (32 / s) * ss;  // 128..1024
    for (int e = tid; e < tot; e += 256) {
      int p = e / ss;
      int rem = e - p * ss;
      int m = rem / s;
      int j = rem - m * s;
      int o = p * 2 * s;
      float acc = 0.f;
      for (int l = 0; l < s; ++l)
        acc = fmaf(B[o + m][o + s + l], T[o + s + l][o + s + j], acc);
      Wb[e] = acc;
    }
    __syncthreads();
    for (int e = tid; e < tot; e += 256) {
      int p = e / ss;
      int rem = e - p * ss;
      int i = rem / s;
      int j = rem - i * s;
      int o = p * 2 * s;
      float acc = 0.f;
      for (int m = 0; m < s; ++m)
        acc = fmaf(T[o + i][o + m], Wb[p * ss + m * s + j], acc);
      T[o + i][o + s + j] = -acc;
    }
    __syncthreads();
  }

  // epilogue: f32 T block + bf16 transposed mirror
  for (int e = tid; e < 1024; e += 256) {
    int r = e >> 4, c4 = (e & 15) << 2;
    float4 v;
    v.x = T[r][c4]; v.y = T[r][c4 + 1]; v.z = T[r][c4 + 2]; v.w = T[r][c4 + 3];
    *reinterpret_cast<float4*>(Tg + (size_t)(b0 + r) * DIM + b0 + c4) = v;
  }
  for (int e = tid; e < 512; e += 256) {
    int c = e >> 3, r8 = (e & 7) << 3;
    short8v h, l;
#pragma unroll
    for (int j = 0; j < 8; ++j) {
      float fv = T[r8 + j][c];
      short hh = f2bf(fv);
      h[j] = hh;
      l[j] = f2bf(fv - bf2f(hh));
    }
    size_t off = (size_t)(b0 + c) * DIM + b0 + r8;
    *reinterpret_cast<short8v*>(TH + off) = h;
    *reinterpret_cast<short8v*>(TL + off) = l;
  }
}

// ---------------------------------------------------------------------------
// Level s=64 combine, in-LDS; also writes bf16 transposed mirror of X.
__global__ __launch_bounds__(256) void tcomb64_k(const float* __restrict__ Gu,
                                                 const float* __restrict__ Gv,
                                                 float* __restrict__ Tu,
                                                 float* __restrict__ Tv,
                                                 short* __restrict__ TtuH,
                                                 short* __restrict__ TtuL,
                                                 short* __restrict__ TtvH,
                                                 short* __restrict__ TtvL) {
  __shared__ float TA[64][68], SS[64][68], TB[64][68], W[64][68];
  int zz = blockIdx.x;
  int side = zz >> 3, p = zz & 7;
  int a0 = p * 128;
  const float* G = side ? Gv : Gu;
  float* T = side ? Tv : Tu;
  short* TH = side ? TtvH : TtuH;
  short* TL = side ? TtvL : TtuL;
  int tid = threadIdx.x;
#pragma unroll
  for (int ii = 0; ii < 4; ++ii) {
    int flat = tid + ii * 256;
    int r = flat >> 4, c4 = (flat & 15) << 2;
    *reinterpret_cast<float4*>(&TA[r][c4]) =
        *reinterpret_cast<const float4*>(T + (size_t)(a0 + r) * DIM + a0 + c4);
    *reinterpret_cast<float4*>(&SS[r][c4]) =
        *reinterpret_cast<const float4*>(G + (size_t)(a0 + r) * DIM + a0 + 64 + c4);
    *reinterpret_cast<float4*>(&TB[r][c4]) =
        *reinterpret_cast<const float4*>(T + (size_t)(a0 + 64 + r) * DIM + a0 + 64 + c4);
  }
  __syncthreads();
  int tx = tid & 15, ty = tid >> 4;
  float acc[4][4] = {};
  for (int k = 0; k < 64; ++k) {
    float a[4], b[4];
#pragma unroll
    for (int m = 0; m < 4; ++m) a[m] = SS[ty * 4 + m][k];
#pragma unroll
    for (int n = 0; n < 4; ++n) b[n] = TB[k][tx * 4 + n];
#pragma unroll
    for (int m = 0; m < 4; ++m)
#pragma unroll
      for (int n = 0; n < 4; ++n) acc[m][n] = fmaf(a[m], b[n], acc[m][n]);
  }
#pragma unroll
  for (int m = 0; m < 4; ++m)
#pragma unroll
    for (int n = 0; n < 4; ++n) W[ty * 4 + m][tx * 4 + n] = acc[m][n];
  __syncthreads();
  float acc2[4][4] = {};
  for (int k = 0; k < 64; ++k) {
    float a[4], b[4];
#pragma unroll
    for (int m = 0; m < 4; ++m) a[m] = TA[ty * 4 + m][k];
#pragma unroll
    for (int n = 0; n < 4; ++n) b[n] = W[k][tx * 4 + n];
#pragma unroll
    for (int m = 0; m < 4; ++m)
#pragma unroll
      for (int n = 0; n < 4; ++n) acc2[m][n] = fmaf(a[m], b[n], acc2[m][n]);
  }
#pragma unroll
  for (int m = 0; m < 4; ++m)
#pragma unroll
    for (int n = 0; n < 4; ++n)
      T[(size_t)(a0 + ty * 4 + m) * DIM + a0 + 64 + tx * 4 + n] = -acc2[m][n];
  // bf16 transposed mirror of X: Tt[a0+64+col][a0+row]
#pragma unroll
  for (int n = 0; n < 4; ++n) {
    short4v h, l;
#pragma unroll
    for (int j = 0; j < 4; ++j) {
      float fv = -acc2[j][n];
      short hh = f2bf(fv);
      h[j] = hh;
      l[j] = f2bf(fv - bf2f(hh));
    }
    size_t off = (size_t)(a0 + 64 + tx * 4 + n) * DIM + a0 + ty * 4;
    *reinterpret_cast<short4v*>(TH + off) = h;
    *reinterpret_cast<short4v*>(TL + off) = l;
  }
}

// ---------------------------------------------------------------------------
// Tree levels s>=128. stage1: TmpT = (S_AB @ T_B)^T bf16 (Bt = Tt diag).
// stage2: T off-diag = -T_A @ Tmp (Bt = TmpT); also writes bf16 mirror of X.
__global__ __launch_bounds__(256) void tcombgg_k(const float* __restrict__ Gu,
                                                 const float* __restrict__ Gv,
                                                 float* __restrict__ Tu,
                                                 float* __restrict__ Tv,
                                                 short* __restrict__ TtuH,
                                                 short* __restrict__ TtuL,
                                                 short* __restrict__ TtvH,
                                                 short* __restrict__ TtvL,
                                                 short* __restrict__ TmpTh,
                                                 short* __restrict__ TmpTl,
                                                 int s, int npair, int stage) {
  __shared__ short Ah[128][40], Al[128][40], Bh[128][40], Bl[128][40];
  const int z = blockIdx.z;
  const int side = z / npair, p = z % npair;
  const int a0 = p * 2 * s;
  const float* Ab;
  const short* BH; const short* BL;
  int ldb;
  if (stage == 1) {
    Ab = (side ? Gv : Gu) + (size_t)a0 * DIM + (a0 + s);
    BH = (side ? TtvH : TtuH) + (size_t)(a0 + s) * DIM + (a0 + s);
    BL = (side ? TtvL : TtuL) + (size_t)(a0 + s) * DIM + (a0 + s);
    ldb = DIM;
  } else {
    Ab = (side ? Tv : Tu) + (size_t)a0 * DIM + a0;
    BH = TmpTh + (size_t)z * s * s;
    BL = TmpTl + (size_t)z * s * s;
    ldb = s;
  }
  const int tid = threadIdx.x;
  const int bn = blockIdx.x, bm = blockIdx.y;
  const int wid = tid >> 6, wr = wid >> 1, wc = wid & 1;
  const int lane = tid & 63, l15 = lane & 15, k8 = (lane >> 4) << 3;
  f32x4 acc[4][4] = {};

  for (int kb = 0; kb < s; kb += 32) {
    __syncthreads();
#pragma unroll
    for (int ii = 0; ii < 4; ++ii) {
      int flat = tid + ii * 256;
      int r = flat >> 3, kq = (flat & 7) << 2;
      float4 v = *reinterpret_cast<const float4*>(Ab + (size_t)(bm * 128 + r) * DIM + kb + kq);
      short4v h, l;
      float fv[4] = {v.x, v.y, v.z, v.w};
#pragma unroll
      for (int j = 0; j < 4; ++j) {
        short hh = f2bf(fv[j]); h[j] = hh; l[j] = f2bf(fv[j] - bf2f(hh));
      }
      *reinterpret_cast<short4v*>(&Ah[r][kq]) = h;
      *reinterpret_cast<short4v*>(&Al[r][kq]) = l;
    }
#pragma unroll
    for (int ii = 0; ii < 2; ++ii) {
      int flat = tid + ii * 256;
      int n = flat >> 2, kk8 = (flat & 3) << 3;
      size_t off = (size_t)(bn * 128 + n) * ldb + kb + kk8;
      *reinterpret_cast<short8v*>(&Bh[n][kk8]) = *reinterpret_cast<const short8v*>(BH + off);
      *reinterpret_cast<short8v*>(&Bl[n][kk8]) = *reinterpret_cast<const short8v*>(BL + off);
    }
    __syncthreads();
    short8v ah[4], al_[4], bh[4], bl_[4];
#pragma unroll
    for (int m = 0; m < 4; ++m) {
      int r = wr * 64 + m * 16 + l15;
      ah[m] = *reinterpret_cast<const short8v*>(&Ah[r][k8]);
      al_[m] = *reinterpret_cast<const short8v*>(&Al[r][k8]);
    }
#pragma unroll
    for (int n = 0; n < 4; ++n) {
      int r = wc * 64 + n * 16 + l15;
      bh[n] = *reinterpret_cast<const short8v*>(&Bh[r][k8]);
      bl_[n] = *reinterpret_cast<const short8v*>(&Bl[r][k8]);
    }
#pragma unroll
    for (int m = 0; m < 4; ++m)
#pragma unroll
      for (int n = 0; n < 4; ++n) {
        acc[m][n] = __builtin_amdgcn_mfma_f32_16x16x32_bf16(ah[m], bh[n], acc[m][n], 0, 0, 0);
        acc[m][n] = __builtin_amdgcn_mfma_f32_16x16x32_bf16(ah[m], bl_[n], acc[m][n], 0, 0, 0);
        acc[m][n] = __builtin_amdgcn_mfma_f32_16x16x32_bf16(al_[m], bh[n], acc[m][n], 0, 0, 0);
      }
  }
  if (stage == 1) {
    size_t base = (size_t)z * s * s;
#pragma unroll
    for (int n = 0; n < 4; ++n) {
      int gcol = bn * 128 + wc * 64 + n * 16 + l15;
#pragma unroll
      for (int m = 0; m < 4; ++m) {
        int gk0 = bm * 128 + wr * 64 + m * 16 + ((lane >> 4) << 2);
        short4v h, l;
#pragma unroll
        for (int j = 0; j < 4; ++j) {
          float fv = acc[m][n][j];
          short hh = f2bf(fv);
          h[j] = hh;
          l[j] = f2bf(fv - bf2f(hh));
        }
        *reinterpret_cast<short4v*>(TmpTh + base + (size_t)gcol * s + gk0) = h;
        *reinterpret_cast<short4v*>(TmpTl + base + (size_t)gcol * s + gk0) = l;
      }
    }
  } else {
    float* T = side ? Tv : Tu;
    float* Cb = T + (size_t)a0 * DIM + (a0 + s);
    short* TH = side ? TtvH : TtuH;
    short* TL = side ? TtvL : TtuL;
#pragma unroll
    for (int n = 0; n < 4; ++n) {
      int gcol = bn * 128 + wc * 64 + n * 16 + l15;
#pragma unroll
      for (int m = 0; m < 4; ++m) {
        int grow0 = bm * 128 + wr * 64 + m * 16 + ((lane >> 4) << 2);
        short4v h, l;
#pragma unroll
        for (int j = 0; j < 4; ++j) {
          float fv = -acc[m][n][j];
          Cb[(size_t)(grow0 + j) * DIM + gcol] = fv;
          short hh = f2bf(fv);
          h[j] = hh;
          l[j] = f2bf(fv - bf2f(hh));
        }
        size_t off = (size_t)(a0 + s + gcol) * DIM + a0 + grow0;
        *reinterpret_cast<short4v*>(TH + off) = h;
        *reinterpret_cast<short4v*>(TL + off) = l;
      }
    }
  }
}

// ---------------------------------------------------------------------------
// P = T @ Au ; A = T f32 natural, Bt = AuT/AvT bf16 [c][k]. Out Pt = P^T f32.
__global__ __launch_bounds__(256) void pgemm_k(const float* __restrict__ Tu,
                                               const float* __restrict__ Tv,
                                               const short* __restrict__ AuTh,
                                               const short* __restrict__ AuTl,
                                               const short* __restrict__ AvTh,
                                               const short* __restrict__ AvTl,
                                               float* __restrict__ Ptu,
                                               float* __restrict__ Ptv) {
  __shared__ short Ah[128][40], Al[128][40], Bh[128][40], Bl[128][40];
  const int side = blockIdx.z;
  const float* A = side ? Tv : Tu;
  const short* BH = side ? AvTh : AuTh;
  const short* BL = side ? AvTl : AuTl;
  float* Out = side ? Ptv : Ptu;
  const int tid = threadIdx.x;
  const int bn = blockIdx.x, bm = blockIdx.y;
  const int wid = tid >> 6, wr = wid >> 1, wc = wid & 1;
  const int lane = tid & 63, l15 = lane & 15, k8 = (lane >> 4) << 3;
  f32x4 acc[4][4] = {};

  for (int kb = 0; kb < DIM; kb += 32) {
    __syncthreads();
#pragma unroll
    for (int ii = 0; ii < 4; ++ii) {
      int flat = tid + ii * 256;
      int r = flat >> 3, kq = (flat & 7) << 2;
      float4 v = *reinterpret_cast<const float4*>(A + (size_t)(bm * 128 + r) * DIM + kb + kq);
      short4v h, l;
      float fv[4] = {v.x, v.y, v.z, v.w};
#pragma unroll
      for (int j = 0; j < 4; ++j) {
        short hh = f2bf(fv[j]); h[j] = hh; l[j] = f2bf(fv[j] - bf2f(hh));
      }
      *reinterpret_cast<short4v*>(&Ah[r][kq]) = h;
      *reinterpret_cast<short4v*>(&Al[r][kq]) = l;
    }
#pragma unroll
    for (int ii = 0; ii < 2; ++ii) {
      int flat = tid + ii * 256;
      int n = flat >> 2, kk8 = (flat & 3) << 3;
      size_t off = (size_t)(bn * 128 + n) * DIM + kb + kk8;
      *reinterpret_cast<short8v*>(&Bh[n][kk8]) = *reinterpret_cast<const short8v*>(BH + off);
      *reinterpret_cast<short8v*>(&Bl[n][kk8]) = *reinterpret_cast<const short8v*>(BL + off);
    }
    __syncthreads();
    short8v ah[4], al_[4], bh[4], bl_[4];
#pragma unroll
    for (int m = 0; m < 4; ++m) {
      int r = wr * 64 + m * 16 + l15;
      ah[m] = *reinterpret_cast<const short8v*>(&Ah[r][k8]);
      al_[m] = *reinterpret_cast<const short8v*>(&Al[r][k8]);
    }
#pragma unroll
    for (int n = 0; n < 4; ++n) {
      int r = wc * 64 + n * 16 + l15;
      bh[n] = *reinterpret_cast<const short8v*>(&Bh[r][k8]);
      bl_[n] = *reinterpret_cast<const short8v*>(&Bl[r][k8]);
    }
#pragma unroll
    for (int m = 0; m < 4; ++m)
#pragma unroll
      for (int n = 0; n < 4; ++n) {
        acc[m][n] = __builtin_amdgcn_mfma_f32_16x16x32_bf16(ah[m], bh[n], acc[m][n], 0, 0, 0);
        acc[m][n] = __builtin_amdgcn_mfma_f32_16x16x32_bf16(ah[m], bl_[n], acc[m][n], 0, 0, 0);
        acc[m][n] = __builtin_amdgcn_mfma_f32_16x16x32_bf16(al_[m], bh[n], acc[m][n], 0, 0, 0);
      }
  }
#pragma unroll
  for (int n = 0; n < 4; ++n) {
    int gcol = bn * 128 + wc * 64 + n * 16 + l15;
#pragma unroll
    for (int m = 0; m < 4; ++m) {
      int grow0 = bm * 128 + wr * 64 + m * 16 + ((lane >> 4) << 2);
      float4 o;
      o.x = acc[m][n][0]; o.y = acc[m][n][1]; o.z = acc[m][n][2]; o.w = acc[m][n][3];
      *reinterpret_cast<float4*>(Out + (size_t)gcol * DIM + grow0) = o;
    }
  }
}

// ---------------------------------------------------------------------------
// Nt = N^T: A = Pt f32, Bt = AuT/AvT bf16.
// side0: Qu'[gcol][row] = (del - Nt)*sg[row] bf16; side1: Qvt f32 natural.
__global__ __launch_bounds__(256) void ngemm_k(const float* __restrict__ Ptu,
                                               const float* __restrict__ Ptv,
                                               const short* __restrict__ AuTh,
                                               const short* __restrict__ AuTl,
                                               const short* __restrict__ AvTh,
                                               const short* __restrict__ AvTl,
                                               const float* __restrict__ sg,
                                               short* __restrict__ QupH,
                                               short* __restrict__ QupL,
                                               float* __restrict__ Qvt) {
  __shared__ short Ah[128][40], Al[128][40], Bh[128][40], Bl[128][40];
  const int side = blockIdx.z;
  const float* A = side ? Ptv : Ptu;
  const short* BH = side ? AvTh : AuTh;
  const short* BL = side ? AvTl : AuTl;
  const int tid = threadIdx.x;
  const int bn = blockIdx.x, bm = blockIdx.y;
  const int wid = tid >> 6, wr = wid >> 1, wc = wid & 1;
  const int lane = tid & 63, l15 = lane & 15, k8 = (lane >> 4) << 3;
  f32x4 acc[4][4] = {};

  for (int kb = 0; kb < DIM; kb += 32) {
    __syncthreads();
#pragma unroll
    for (int ii = 0; ii < 4; ++ii) {
      int flat = tid + ii * 256;
      int r = flat >> 3, kq = (flat & 7) << 2;
      float4 v = *reinterpret_cast<const float4*>(A + (size_t)(bm * 128 + r) * DIM + kb + kq);
      short4v h, l;
      float fv[4] = {v.x, v.y, v.z, v.w};
#pragma unroll
      for (int j = 0; j < 4; ++j) {
        short hh = f2bf(fv[j]); h[j] = hh; l[j] = f2bf(fv[j] - bf2f(hh));
      }
      *reinterpret_cast<short4v*>(&Ah[r][kq]) = h;
      *reinterpret_cast<short4v*>(&Al[r][kq]) = l;
    }
#pragma unroll
    for (int ii = 0; ii < 2; ++ii) {
      int flat = tid + ii * 256;
      int n = flat >> 2, kk8 = (flat & 3) << 3;
      size_t off = (size_t)(bn * 128 + n) * DIM + kb + kk8;
      *reinterpret_cast<short8v*>(&Bh[n][kk8]) = *reinterpret_cast<const short8v*>(BH + off);
      *reinterpret_cast<short8v*>(&Bl[n][kk8]) = *reinterpret_cast<const short8v*>(BL + off);
    }
    __syncthreads();
    short8v ah[4], al_[4], bh[4], bl_[4];
#pragma unroll
    for (int m = 0; m < 4; ++m) {
      int r = wr * 64 + m * 16 + l15;
      ah[m] = *reinterpret_cast<const short8v*>(&Ah[r][k8]);
      al_[m] = *reinterpret_cast<const short8v*>(&Al[r][k8]);
    }
#pragma unroll
    for (int n = 0; n < 4; ++n) {
      int r = wc * 64 + n * 16 + l15;
      bh[n] = *reinterpret_cast<const short8v*>(&Bh[r][k8]);
      bl_[n] = *reinterpret_cast<const short8v*>(&Bl[r][k8]);
    }
#pragma unroll
    for (int m = 0; m < 4; ++m)
#pragma unroll
      for (int n = 0; n < 4; ++n) {
        acc[m][n] = __builtin_amdgcn_mfma_f32_16x16x32_bf16(ah[m], bh[n], acc[m][n], 0, 0, 0);
        acc[m][n] = __builtin_amdgcn_mfma_f32_16x16x32_bf16(ah[m], bl_[n], acc[m][n], 0, 0, 0);
        acc[m][n] = __builtin_amdgcn_mfma_f32_16x16x32_bf16(al_[m], bh[n], acc[m][n], 0, 0, 0);
      }
  }
#pragma unroll
  for (int n = 0; n < 4; ++n) {
    int gcol = bn * 128 + wc * 64 + n * 16 + l15;
#pragma unroll
    for (int m = 0; m < 4; ++m) {
      int grow0 = bm * 128 + wr * 64 + m * 16 + ((lane >> 4) << 2);
      if (side == 0) {
        short4v h, l;
#pragma unroll
        for (int j = 0; j < 4; ++j) {
          int row = grow0 + j;
          float del = (row == gcol) ? 1.0f : 0.0f;
          float q = (del - acc[m][n][j]) * sg[row];
          short hh = f2bf(q);
          h[j] = hh;
          l[j] = f2bf(q - bf2f(hh));
        }
        *reinterpret_cast<short4v*>(QupH + (size_t)gcol * DIM + grow0) = h;
        *reinterpret_cast<short4v*>(QupL + (size_t)gcol * DIM + grow0) = l;
      } else {
#pragma unroll
        for (int j = 0; j < 4; ++j) {
          int row = grow0 + j;
          float del = (row == gcol) ? 1.0f : 0.0f;
          Qvt[(size_t)row * DIM + gcol] = del - acc[m][n][j];
        }
      }
    }
  }
}

// ---------------------------------------------------------------------------
// MT = M^T = Qv^T @ Qu'^T : A = Qvt f32, Bt = Qu' bf16. Natural bf16 store.
__global__ __launch_bounds__(256) void mgemm2_k(const float* __restrict__ Qvt,
                                                const short* __restrict__ QupH,
                                                const short* __restrict__ QupL,
                                                short* __restrict__ MTh,
                                                short* __restrict__ MTl) {
  __shared__ short Ah[128][40], Al[128][40], Bh[128][40], Bl[128][40];
  const int tid = threadIdx.x;
  const int bn = blockIdx.x, bm = blockIdx.y;
  const int wid = tid >> 6, wr = wid >> 1, wc = wid & 1;
  const int lane = tid & 63, l15 = lane & 15, k8 = (lane >> 4) << 3;
  f32x4 acc[4][4] = {};

  for (int kb = 0; kb < DIM; kb += 32) {
    __syncthreads();
#pragma unroll
    for (int ii = 0; ii < 4; ++ii) {
      int flat = tid + ii * 256;
      int r = flat >> 3, kq = (flat & 7) << 2;
      float4 v = *reinterpret_cast<const float4*>(Qvt + (size_t)(bm * 128 + r) * DIM + kb + kq);
      short4v h, l;
      float fv[4] = {v.x, v.y, v.z, v.w};
#pragma unroll
      for (int j = 0; j < 4; ++j) {
        short hh = f2bf(fv[j]); h[j] = hh; l[j] = f2bf(fv[j] - bf2f(hh));
      }
      *reinterpret_cast<short4v*>(&Ah[r][kq]) = h;
      *reinterpret_cast<short4v*>(&Al[r][kq]) = l;
    }
#pragma unroll
    for (int ii = 0; ii < 2; ++ii) {
      int flat = tid + ii * 256;
      int n = flat >> 2, kk8 = (flat & 3) << 3;
      size_t off = (size_t)(bn * 128 + n) * DIM + kb + kk8;
      *reinterpret_cast<short8v*>(&Bh[n][kk8]) = *reinterpret_cast<const short8v*>(QupH + off);
      *reinterpret_cast<short8v*>(&Bl[n][kk8]) = *reinterpret_cast<const short8v*>(QupL + off);
    }
    __syncthreads();
    short8v ah[4], al_[4], bh[4], bl_[4];
#pragma unroll
    for (int m = 0; m < 4; ++m) {
      int r = wr * 64 + m * 16 + l15;
      ah[m] = *reinterpret_cast<const short8v*>(&Ah[r][k8]);
      al_[m] = *reinterpret_cast<const short8v*>(&Al[r][k8]);
    }
#pragma unroll
    for (int n = 0; n < 4; ++n) {
      int r = wc * 64 + n * 16 + l15;
      bh[n] = *reinterpret_cast<const short8v*>(&Bh[r][k8]);
      bl_[n] = *reinterpret_cast<const short8v*>(&Bl[r][k8]);
    }
#pragma unroll
    for (int m = 0; m < 4; ++m)
#pragma unroll
      for (int n = 0; n < 4; ++n) {
        acc[m][n] = __builtin_amdgcn_mfma_f32_16x16x32_bf16(ah[m], bh[n], acc[m][n], 0, 0, 0);
        acc[m][n] = __builtin_amdgcn_mfma_f32_16x16x32_bf16(ah[m], bl_[n], acc[m][n], 0, 0, 0);
        acc[m][n] = __builtin_amdgcn_mfma_f32_16x16x32_bf16(al_[m], bh[n], acc[m][n], 0, 0, 0);
      }
  }
#pragma unroll
  for (int n = 0; n < 4; ++n) {
    int gcol = bn * 128 + wc * 64 + n * 16 + l15;
#pragma unroll
    for (int m = 0; m < 4; ++m) {
      int grow0 = bm * 128 + wr * 64 + m * 16 + ((lane >> 4) << 2);
#pragma unroll
      for (int j = 0; j < 4; ++j) {
        float fv = acc[m][n][j];
        short hh = f2bf(fv);
        MTh[(size_t)(grow0 + j) * DIM + gcol] = hh;
        MTl[(size_t)(grow0 + j) * DIM + gcol] = f2bf(fv - bf2f(hh));
      }
    }
  }
}

// ---------------------------------------------------------------------------
// out[4096,1024] = x @ M + bias (proven).
__global__ __launch_bounds__(256) void gemm_mfma_k(const float* __restrict__ x,
                                                   const short* __restrict__ Bthi,
                                                   const short* __restrict__ Btlo,
                                                   const float* __restrict__ bias,
                                                   float* __restrict__ out) {
  __shared__ short Ah[128][40], Al[128][40], Bh[128][40], Bl[128][40];
  const int tid = threadIdx.x;
  const int bn = blockIdx.x, bm = blockIdx.y;
  const int wid = tid >> 6, wr = wid >> 1, wc = wid & 1;
  const int lane = tid & 63, l15 = lane & 15, k8 = (lane >> 4) << 3;
  f32x4 acc[4][4] = {};

  for (int kb = 0; kb < DIM; kb += 32) {
    __syncthreads();
#pragma unroll
    for (int ii = 0; ii < 4; ++ii) {
      int flat = tid + ii * 256;
      int r = flat >> 3, kq = (flat & 7) << 2;
      float4 v = *reinterpret_cast<const float4*>(x + (size_t)(bm * 128 + r) * DIM + kb + kq);
      short4v h, l;
      float fv[4] = {v.x, v.y, v.z, v.w};
#pragma unroll
      for (int j = 0; j < 4; ++j) {
        short hh = f2bf(fv[j]); h[j] = hh; l[j] = f2bf(fv[j] - bf2f(hh));
      }
      *reinterpret_cast<short4v*>(&Ah[r][kq]) = h;
      *reinterpret_cast<short4v*>(&Al[r][kq]) = l;
    }
#pragma unroll
    for (int ii = 0; ii < 2; ++ii) {
      int flat = tid + ii * 256;
      int n = flat >> 2, kk8 = (flat & 3) << 3;
      size_t off = (size_t)(bn * 128 + n) * DIM + kb + kk8;
      *reinterpret_cast<short8v*>(&Bh[n][kk8]) = *reinterpret_cast<const short8v*>(Bthi + off);
      *reinterpret_cast<short8v*>(&Bl[n][kk8]) = *reinterpret_cast<const short8v*>(Btlo + off);
    }
    __syncthreads();
    short8v ah[4], al_[4], bh[4], bl_[4];
#pragma unroll
    for (int m = 0; m < 4; ++m) {
      int r = wr * 64 + m * 16 + l15;
      ah[m] = *reinterpret_cast<const short8v*>(&Ah[r][k8]);
      al_[m] = *reinterpret_cast<const short8v*>(&Al[r][k8]);
    }
#pragma unroll
    for (int n = 0; n < 4; ++n) {
      int r = wc * 64 + n * 16 + l15;
      bh[n] = *reinterpret_cast<const short8v*>(&Bh[r][k8]);
      bl_[n] = *reinterpret_cast<const short8v*>(&Bl[r][k8]);
    }
#pragma unroll
    for (int m = 0; m < 4; ++m)
#pragma unroll
      for (int n = 0; n < 4; ++n) {
        acc[m][n] = __builtin_amdgcn_mfma_f32_16x16x32_bf16(ah[m], bh[n], acc[m][n], 0, 0, 0);
        acc[m][n] = __builtin_amdgcn_mfma_f32_16x16x32_bf16(ah[m], bl_[n], acc[m][n], 0, 0, 0);
        acc[m][n] = __builtin_amdgcn_mfma_f32_16x16x32_bf16(al_[m], bh[n], acc[m][n], 0, 0, 0);
      }
  }
#pragma unroll
  for (int n = 0; n < 4; ++n) {
    int gcol = bn * 128 + wc * 64 + n * 16 + l15;
    float bv = bias[gcol];
#pragma unroll
    for (int m = 0; m < 4; ++m) {
      int grow0 = bm * 128 + wr * 64 + m * 16 + ((lane >> 4) << 2);
#pragma unroll
      for (int j = 0; j < 4; ++j)
        out[(size_t)(grow0 + j) * DIM + gcol] = acc[m][n][j] + bv;
    }
  }
}

// ---------------------------------------------------------------------------
extern "C" void kernel_launch(void* const* d_in, const int* in_sizes, int n_in,
                              void* d_out, int out_size, void* d_ws, size_t ws_size,
                              hipStream_t stream) {
  const float* x    = (const float*)d_in[0];
  const float* U    = (const float*)d_in[1];
  const float* V    = (const float*)d_in[2];
  const float* p    = (const float*)d_in[3];
  const float* bias = (const float*)d_in[4];
  float* out = (float*)d_out;

  float* F = (float*)d_ws;
  short* AuH  = (short*)F;
  short* AuL  = AuH + 1048576;
  short* AvH  = AuL + 1048576;
  short* AvL  = AvH + 1048576;
  short* QupH = AuH;                  // overlay after gram
  short* QupL = AuL;
  float* Qvt  = F + 1048576;          // overlays AvH/AvL
  float* Gu   = F + 2097152;
  float* Gv   = F + 3145728;
  float* Ptu  = Gu;                   // overlay after tree
  float* Ptv  = Gv;
  float* Tu   = F + 4194304;
  float* Tv   = F + 5242880;
  short* MTh  = (short*)Tu;           // overlay after pgemm
  short* MTl  = MTh + 1048576;
  short* TtuH = (short*)(F + 6291456);
  short* TtuL = TtuH + 1048576;
  short* TtvH = TtuL + 1048576;
  short* TtvL = TtvH + 1048576;
  short* AuTh = (short*)(F + 8388608);
  short* AuTl = AuTh + 1048576;
  short* AvTh = AuTl + 1048576;
  short* AvTl = AvTh + 1048576;
  short* TmpTh = (short*)(F + 10485760);
  short* TmpTl = TmpTh + 524288;
  float* tinu = F + 11010048;
  float* tinv = tinu + DIM;
  float* sg   = tinv + DIM;

  prep_k<<<512, 256, 0, stream>>>(U, V, p, tinu, tinv, sg);
  asplit_k<<<1024, 256, 0, stream>>>(U, V, AuH, AuL, AvH, AvL);
  tsplUV_k<<<dim3(16, 16, 2), 256, 0, stream>>>(U, V, AuTh, AuTl, AvTh, AvTl);
  gram_k<<<dim3(8, 8, 2), 256, 0, stream>>>(U, V, AuH, AuL, AvH, AvL, Gu, Gv);
  // zero Tu,Tv (f32) + all Tt bf16 mirrors in one contiguous 16MB memset
  hipMemsetAsync(Tu, 0, (size_t)4194304 * sizeof(float), stream);
  tdiag64_k<<<32, 256, 0, stream>>>(Gu, Gv, tinu, tinv, Tu, Tv,
                                    TtuH, TtuL, TtvH, TtvL);
  tcomb64_k<<<16, 256, 0, stream>>>(Gu, Gv, Tu, Tv, TtuH, TtuL, TtvH, TtvL);
  tcombgg_k<<<dim3(1, 1, 8), 256, 0, stream>>>(Gu, Gv, Tu, Tv, TtuH, TtuL, TtvH, TtvL, TmpTh, TmpTl, 128, 4, 1);
  tcombgg_k<<<dim3(1, 1, 8), 256, 0, stream>>>(Gu, Gv, Tu, Tv, TtuH, TtuL, TtvH, TtvL, TmpTh, TmpTl, 128, 4, 2);
  tcombgg_k<<<dim3(2, 2, 4), 256, 0, stream>>>(Gu, Gv, Tu, Tv, TtuH, TtuL, TtvH, TtvL, TmpTh, TmpTl, 256, 2, 1);
  tcombgg_k<<<dim3(2, 2, 4), 256, 0, stream>>>(Gu, Gv, Tu, Tv, TtuH, TtuL, TtvH, TtvL, TmpTh, TmpTl, 256, 2, 2);
  tcombgg_k<<<dim3(4, 4, 2), 256, 0, stream>>>(Gu, Gv, Tu, Tv, TtuH, TtuL, TtvH, TtvL, TmpTh, TmpTl, 512, 1, 1);
  tcombgg_k<<<dim3(4, 4, 2), 256, 0, stream>>>(Gu, Gv, Tu, Tv, TtuH, TtuL, TtvH, TtvL, TmpTh, TmpTl, 512, 1, 2);
  pgemm_k<<<dim3(8, 8, 2), 256, 0, stream>>>(Tu, Tv, AuTh, AuTl, AvTh, AvTl, Ptu, Ptv);
  ngemm_k<<<dim3(8, 8, 2), 256, 0, stream>>>(Ptu, Ptv, AuTh, AuTl, AvTh, AvTl, sg, QupH, QupL, Qvt);
  mgemm2_k<<<dim3(8, 8), 256, 0, stream>>>(Qvt, QupH, QupL, MTh, MTl);
  gemm_mfma_k<<<dim3(8, 32), 256, 0, stream>>>(x, MTh, MTl, bias, out);
}

// Round 14
// 415.607 us; speedup vs baseline: 1.7940x; 1.0020x over previous
//
#include <hip/hip_runtime.h>

#define DIM 1024
#define BATCH 4096

typedef __attribute__((ext_vector_type(8))) short short8v;
typedef __attribute__((ext_vector_type(4))) short short4v;
typedef __attribute__((ext_vector_type(4))) float f32x4;

// ---------------------------------------------------------------------------
__device__ __forceinline__ float dpp_reduce_bcast(float x) {
  int v = __builtin_bit_cast(int, x);
#define DPP_STEP(ctrl)                                                        \
  {                                                                           \
    int s = __builtin_amdgcn_update_dpp(0, v, ctrl, 0xf, 0xf, true);          \
    v = __builtin_bit_cast(                                                   \
        int, __builtin_bit_cast(float, v) + __builtin_bit_cast(float, s));    \
  }
  DPP_STEP(0x111) DPP_STEP(0x112) DPP_STEP(0x114) DPP_STEP(0x118)
  DPP_STEP(0x142) DPP_STEP(0x143)
#undef DPP_STEP
  return __builtin_bit_cast(float, __builtin_amdgcn_readlane(v, 63));
}

__device__ __forceinline__ short f2bf(float f) {
  unsigned u = __builtin_bit_cast(unsigned, f);
  u += 0x7FFFu + ((u >> 16) & 1u);
  return (short)(u >> 16);
}
__device__ __forceinline__ float bf2f(short h) {
  unsigned u = ((unsigned)(unsigned short)h) << 16;
  return __builtin_bit_cast(float, u);
}

// ---------------------------------------------------------------------------
// tau[m] = 2/||row m||^2 (U: row m; V: row 1023-m). Fused: sg sigmoid map.
__global__ __launch_bounds__(256) void prep_k(const float* __restrict__ U,
                                              const float* __restrict__ V,
                                              const float* __restrict__ p,
                                              float* __restrict__ tinu,
                                              float* __restrict__ tinv,
                                              float* __restrict__ sg) {
  int gi = blockIdx.x * 256 + threadIdx.x;
  if (gi < DIM) sg[gi] = 0.1f + 0.9f / (1.0f + __expf(-p[gi]));
  int gw = gi >> 6;
  int lane = threadIdx.x & 63;
  if (gw >= 2048) return;
  const float* src = (gw < 1024) ? (U + (size_t)gw * DIM)
                                 : (V + (size_t)(1023 - (gw - 1024)) * DIM);
  float s = 0.f;
#pragma unroll
  for (int q = 0; q < 4; ++q) {
    float4 v = *reinterpret_cast<const float4*>(src + q * 256 + lane * 4);
    s += v.x * v.x + v.y * v.y + v.z * v.z + v.w * v.w;
  }
  float tot = dpp_reduce_bcast(s);
  if (lane == 0) {
    float val = 2.0f / tot;
    if (gw < 1024) tinu[gw] = val; else tinv[gw - 1024] = val;
  }
}

// ---------------------------------------------------------------------------
// Natural-layout bf16 hi/lo splits of Au = U and Av = rows-of-V-reversed.
__global__ __launch_bounds__(256) void asplit_k(const float* __restrict__ U,
                                                const float* __restrict__ V,
                                                short* __restrict__ AuH,
                                                short* __restrict__ AuL,
                                                short* __restrict__ AvH,
                                                short* __restrict__ AvL) {
  int e = (blockIdx.x * 256 + threadIdx.x) * 8;
  int side = e >> 20;
  int idx = e & 1048575;
  int r = idx >> 10, c = idx & 1023;
  const float* src = side ? (V + (size_t)(1023 - r) * DIM + c)
                          : (U + (size_t)r * DIM + c);
  float4 a = *reinterpret_cast<const float4*>(src);
  float4 b = *reinterpret_cast<const float4*>(src + 4);
  float fv[8] = {a.x, a.y, a.z, a.w, b.x, b.y, b.z, b.w};
  short8v h, l;
#pragma unroll
  for (int j = 0; j < 8; ++j) {
    short hh = f2bf(fv[j]);
    h[j] = hh;
    l[j] = f2bf(fv[j] - bf2f(hh));
  }
  *reinterpret_cast<short8v*>((side ? AvH : AuH) + idx) = h;
  *reinterpret_cast<short8v*>((side ? AvL : AuL) + idx) = l;
}

// ---------------------------------------------------------------------------
// bf16 hi/lo split of x (natural layout). One pass, 8 elems/thread.
__global__ __launch_bounds__(256) void xsplit_k(const float* __restrict__ x,
                                                short* __restrict__ xH,
                                                short* __restrict__ xL) {
  int idx = (blockIdx.x * 256 + threadIdx.x) * 8;
  float4 a = *reinterpret_cast<const float4*>(x + idx);
  float4 b = *reinterpret_cast<const float4*>(x + idx + 4);
  float fv[8] = {a.x, a.y, a.z, a.w, b.x, b.y, b.z, b.w};
  short8v h, l;
#pragma unroll
  for (int j = 0; j < 8; ++j) {
    short hh = f2bf(fv[j]);
    h[j] = hh;
    l[j] = f2bf(fv[j] - bf2f(hh));
  }
  *reinterpret_cast<short8v*>(xH + idx) = h;
  *reinterpret_cast<short8v*>(xL + idx) = l;
}

// ---------------------------------------------------------------------------
// Transpose-split of U / V-flipped: AuT[c][k] = split(U[k][c]),
// AvT[c][k] = split(V[1023-k][c]).
__global__ __launch_bounds__(256) void tsplUV_k(const float* __restrict__ U,
                                                const float* __restrict__ V,
                                                short* __restrict__ AuTh,
                                                short* __restrict__ AuTl,
                                                short* __restrict__ AvTh,
                                                short* __restrict__ AvTl) {
  __shared__ float tile[64][68];
  const int side = blockIdx.z;
  const int rb = blockIdx.y * 64, cb = blockIdx.x * 64;
  const int f = threadIdx.x;
  const float* S = side ? V : U;
#pragma unroll
  for (int ii = 0; ii < 4; ++ii) {
    int flat = f + ii * 256;
    int r = flat >> 4, c4 = (flat & 15) << 2;
    int rs = rb + r;
    if (side) rs = 1023 - rs;
    float4 v = *reinterpret_cast<const float4*>(S + (size_t)rs * DIM + cb + c4);
    tile[r][c4 + 0] = v.x; tile[r][c4 + 1] = v.y; tile[r][c4 + 2] = v.z; tile[r][c4 + 3] = v.w;
  }
  __syncthreads();
#pragma unroll
  for (int ii = 0; ii < 2; ++ii) {
    int flat = f + ii * 256;
    int cc = flat >> 3, r8 = (flat & 7) << 3;
    short8v vh, vl;
#pragma unroll
    for (int j = 0; j < 8; ++j) {
      float fv = tile[r8 + j][cc];
      short hh = f2bf(fv);
      vh[j] = hh;
      vl[j] = f2bf(fv - bf2f(hh));
    }
    size_t off = (size_t)(cb + cc) * DIM + rb + r8;
    *reinterpret_cast<short8v*>((side ? AvTh : AuTh) + off) = vh;
    *reinterpret_cast<short8v*>((side ? AvTl : AuTl) + off) = vl;
  }
}

// ---------------------------------------------------------------------------
// Gram: G[m][n] = Au_m . Au_n (3-term split-bf16). Padded LDS (44: 22-dword
// stride -> all-distinct banks on b128 frag reads).
__global__ __launch_bounds__(256) void gram_k(const float* __restrict__ U,
                                              const float* __restrict__ V,
                                              const short* __restrict__ AuH,
                                              const short* __restrict__ AuL,
                                              const short* __restrict__ AvH,
                                              const short* __restrict__ AvL,
                                              float* __restrict__ Gu,
                                              float* __restrict__ Gv) {
  __shared__ short Ah[128][44], Al[128][44], Bh[128][44], Bl[128][44];
  const int side = blockIdx.z;
  const float* A = side ? V : U;
  const short* BH = side ? AvH : AuH;
  const short* BL = side ? AvL : AuL;
  float* G = side ? Gv : Gu;
  const int tid = threadIdx.x;
  const int bn = blockIdx.x, bm = blockIdx.y;
  const int wid = tid >> 6, wr = wid >> 1, wc = wid & 1;
  const int lane = tid & 63, l15 = lane & 15, k8 = (lane >> 4) << 3;
  f32x4 acc[4][4] = {};

  for (int kb = 0; kb < DIM; kb += 32) {
    __syncthreads();
#pragma unroll
    for (int ii = 0; ii < 4; ++ii) {
      int flat = tid + ii * 256;
      int r = flat >> 3, kq = (flat & 7) << 2;
      int rg = bm * 128 + r;
      int rs = side ? (1023 - rg) : rg;
      float4 v = *reinterpret_cast<const float4*>(A + (size_t)rs * DIM + kb + kq);
      short4v h, l;
      float fv[4] = {v.x, v.y, v.z, v.w};
#pragma unroll
      for (int j = 0; j < 4; ++j) {
        short hh = f2bf(fv[j]); h[j] = hh; l[j] = f2bf(fv[j] - bf2f(hh));
      }
      *reinterpret_cast<short4v*>(&Ah[r][kq]) = h;
      *reinterpret_cast<short4v*>(&Al[r][kq]) = l;
    }
#pragma unroll
    for (int ii = 0; ii < 2; ++ii) {
      int flat = tid + ii * 256;
      int n = flat >> 2, kk8 = (flat & 3) << 3;
      size_t off = (size_t)(bn * 128 + n) * DIM + kb + kk8;
      *reinterpret_cast<short8v*>(&Bh[n][kk8]) = *reinterpret_cast<const short8v*>(BH + off);
      *reinterpret_cast<short8v*>(&Bl[n][kk8]) = *reinterpret_cast<const short8v*>(BL + off);
    }
    __syncthreads();
    short8v ah[4], al_[4], bh[4], bl_[4];
#pragma unroll
    for (int m = 0; m < 4; ++m) {
      int r = wr * 64 + m * 16 + l15;
      ah[m] = *reinterpret_cast<const short8v*>(&Ah[r][k8]);
      al_[m] = *reinterpret_cast<const short8v*>(&Al[r][k8]);
    }
#pragma unroll
    for (int n = 0; n < 4; ++n) {
      int r = wc * 64 + n * 16 + l15;
      bh[n] = *reinterpret_cast<const short8v*>(&Bh[r][k8]);
      bl_[n] = *reinterpret_cast<const short8v*>(&Bl[r][k8]);
    }
#pragma unroll
    for (int m = 0; m < 4; ++m)
#pragma unroll
      for (int n = 0; n < 4; ++n) {
        acc[m][n] = __builtin_amdgcn_mfma_f32_16x16x32_bf16(ah[m], bh[n], acc[m][n], 0, 0, 0);
        acc[m][n] = __builtin_amdgcn_mfma_f32_16x16x32_bf16(ah[m], bl_[n], acc[m][n], 0, 0, 0);
        acc[m][n] = __builtin_amdgcn_mfma_f32_16x16x32_bf16(al_[m], bh[n], acc[m][n], 0, 0, 0);
      }
  }
#pragma unroll
  for (int n = 0; n < 4; ++n) {
    int gcol = bn * 128 + wc * 64 + n * 16 + l15;
#pragma unroll
    for (int m = 0; m < 4; ++m) {
      int grow0 = bm * 128 + wr * 64 + m * 16 + ((lane >> 4) << 2);
#pragma unroll
      for (int j = 0; j < 4; ++j)
        G[(size_t)(grow0 + j) * DIM + gcol] = acc[m][n][j];
    }
  }
}

// ---------------------------------------------------------------------------
// 64x64 diagonal T blocks via recursive in-LDS triangular inversion (proven).
__global__ __launch_bounds__(256) void tdiag64_k(const float* __restrict__ Gu,
                                                 const float* __restrict__ Gv,
                                                 const float* __restrict__ tinu,
                                                 const float* __restrict__ tinv,
                                                 float* __restrict__ Tu,
                                                 float* __restrict__ Tv,
                                                 short* __restrict__ TtuH,
                                                 short* __restrict__ TtuL,
                                                 short* __restrict__ TtvH,
                                                 short* __restrict__ TtvL) {
  __shared__ float B[64][65];
  __shared__ float T[64][65];
  __shared__ float Wb[1024];
  int z = blockIdx.x >> 4;
  int d = blockIdx.x & 15;
  const float* G = z ? Gv : Gu;
  const float* tau = z ? tinv : tinu;
  float* Tg = z ? Tv : Tu;
  short* TH = z ? TtvH : TtuH;
  short* TL = z ? TtvL : TtuL;
  int b0 = d * 64;
  int tid = threadIdx.x;

  for (int e = tid; e < 4096; e += 256) {
    int r = e >> 6, c = e & 63;
    float v;
    if (r < c) v = G[(size_t)(b0 + r) * DIM + b0 + c];
    else if (r == c) v = 1.0f / tau[b0 + r];
    else v = 0.f;
    B[r][c] = v;
    T[r][c] = 0.f;
  }
  __syncthreads();

  if (tid < 16) {
    int o = tid * 4;
    float X[4][4];
#pragma unroll
    for (int k = 0; k < 4; ++k) {
      X[k][k] = 1.0f / B[o + k][o + k];
#pragma unroll
      for (int i = 2; i >= 0; --i) {
        if (i < k) {
          float s = 0.f;
#pragma unroll
          for (int j = 0; j < 4; ++j)
            if (j > i && j <= k) s = fmaf(B[o + i][o + j], X[j][k], s);
          X[i][k] = -s / B[o + i][o + i];
        }
      }
    }
#pragma unroll
    for (int k = 0; k < 4; ++k)
#pragma unroll
      for (int i = 0; i < 4; ++i)
        if (i <= k) T[o + i][o + k] = X[i][k];
  }
  __syncthreads();

  for (int s = 4; s <= 32; s <<= 1) {
    int ss = s * s;
    int tot = (32 / s) * ss;
    for (int e = tid; e < tot; e += 256) {
      int p = e / ss;
      int rem = e - p * ss;
      int m = rem / s;
      int j = rem - m * s;
      int o = p * 2 * s;
      float acc = 0.f;
      for (int l = 0; l < s; ++l)
        acc = fmaf(B[o + m][o + s + l], T[o + s + l][o + s + j], acc);
      Wb[e] = acc;
    }
    __syncthreads();
    for (int e = tid; e < tot; e += 256) {
      int p = e / ss;
      int rem = e - p * ss;
      int i = rem / s;
      int j = rem - i * s;
      int o = p * 2 * s;
      float acc = 0.f;
      for (int m = 0; m < s; ++m)
        acc = fmaf(T[o + i][o + m], Wb[p * ss + m * s + j], acc);
      T[o + i][o + s + j] = -acc;
    }
    __syncthreads();
  }

  for (int e = tid; e < 1024; e += 256) {
    int r = e >> 4, c4 = (e & 15) << 2;
    float4 v;
    v.x = T[r][c4]; v.y = T[r][c4 + 1]; v.z = T[r][c4 + 2]; v.w = T[r][c4 + 3];
    *reinterpret_cast<float4*>(Tg + (size_t)(b0 + r) * DIM + b0 + c4) = v;
  }
  for (int e = tid; e < 512; e += 256) {
    int c = e >> 3, r8 = (e & 7) << 3;
    short8v h, l;
#pragma unroll
    for (int j = 0; j < 8; ++j) {
      float fv = T[r8 + j][c];
      short hh = f2bf(fv);
      h[j] = hh;
      l[j] = f2bf(fv - bf2f(hh));
    }
    size_t off = (size_t)(b0 + c) * DIM + b0 + r8;
    *reinterpret_cast<short8v*>(TH + off) = h;
    *reinterpret_cast<short8v*>(TL + off) = l;
  }
}

// ---------------------------------------------------------------------------
// Level s=64 combine, in-LDS; also writes bf16 transposed mirror of X.
__global__ __launch_bounds__(256) void tcomb64_k(const float* __restrict__ Gu,
                                                 const float* __restrict__ Gv,
                                                 float* __restrict__ Tu,
                                                 float* __restrict__ Tv,
                                                 short* __restrict__ TtuH,
                                                 short* __restrict__ TtuL,
                                                 short* __restrict__ TtvH,
                                                 short* __restrict__ TtvL) {
  __shared__ float TA[64][68], SS[64][68], TB[64][68], W[64][68];
  int zz = blockIdx.x;
  int side = zz >> 3, p = zz & 7;
  int a0 = p * 128;
  const float* G = side ? Gv : Gu;
  float* T = side ? Tv : Tu;
  short* TH = side ? TtvH : TtuH;
  short* TL = side ? TtvL : TtuL;
  int tid = threadIdx.x;
#pragma unroll
  for (int ii = 0; ii < 4; ++ii) {
    int flat = tid + ii * 256;
    int r = flat >> 4, c4 = (flat & 15) << 2;
    *reinterpret_cast<float4*>(&TA[r][c4]) =
        *reinterpret_cast<const float4*>(T + (size_t)(a0 + r) * DIM + a0 + c4);
    *reinterpret_cast<float4*>(&SS[r][c4]) =
        *reinterpret_cast<const float4*>(G + (size_t)(a0 + r) * DIM + a0 + 64 + c4);
    *reinterpret_cast<float4*>(&TB[r][c4]) =
        *reinterpret_cast<const float4*>(T + (size_t)(a0 + 64 + r) * DIM + a0 + 64 + c4);
  }
  __syncthreads();
  int tx = tid & 15, ty = tid >> 4;
  float acc[4][4] = {};
  for (int k = 0; k < 64; ++k) {
    float a[4], b[4];
#pragma unroll
    for (int m = 0; m < 4; ++m) a[m] = SS[ty * 4 + m][k];
#pragma unroll
    for (int n = 0; n < 4; ++n) b[n] = TB[k][tx * 4 + n];
#pragma unroll
    for (int m = 0; m < 4; ++m)
#pragma unroll
      for (int n = 0; n < 4; ++n) acc[m][n] = fmaf(a[m], b[n], acc[m][n]);
  }
#pragma unroll
  for (int m = 0; m < 4; ++m)
#pragma unroll
    for (int n = 0; n < 4; ++n) W[ty * 4 + m][tx * 4 + n] = acc[m][n];
  __syncthreads();
  float acc2[4][4] = {};
  for (int k = 0; k < 64; ++k) {
    float a[4], b[4];
#pragma unroll
    for (int m = 0; m < 4; ++m) a[m] = TA[ty * 4 + m][k];
#pragma unroll
    for (int n = 0; n < 4; ++n) b[n] = W[k][tx * 4 + n];
#pragma unroll
    for (int m = 0; m < 4; ++m)
#pragma unroll
      for (int n = 0; n < 4; ++n) acc2[m][n] = fmaf(a[m], b[n], acc2[m][n]);
  }
#pragma unroll
  for (int m = 0; m < 4; ++m)
#pragma unroll
    for (int n = 0; n < 4; ++n)
      T[(size_t)(a0 + ty * 4 + m) * DIM + a0 + 64 + tx * 4 + n] = -acc2[m][n];
#pragma unroll
  for (int n = 0; n < 4; ++n) {
    short4v h, l;
#pragma unroll
    for (int j = 0; j < 4; ++j) {
      float fv = -acc2[j][n];
      short hh = f2bf(fv);
      h[j] = hh;
      l[j] = f2bf(fv - bf2f(hh));
    }
    size_t off = (size_t)(a0 + 64 + tx * 4 + n) * DIM + a0 + ty * 4;
    *reinterpret_cast<short4v*>(TH + off) = h;
    *reinterpret_cast<short4v*>(TL + off) = l;
  }
}

// ---------------------------------------------------------------------------
// Tree levels s>=128. stage1: TmpT = (S_AB @ T_B)^T bf16 (Bt = Tt diag).
// stage2: T off-diag = -T_A @ Tmp (Bt = TmpT); also writes bf16 mirror of X.
__global__ __launch_bounds__(256) void tcombgg_k(const float* __restrict__ Gu,
                                                 const float* __restrict__ Gv,
                                                 float* __restrict__ Tu,
                                                 float* __restrict__ Tv,
                                                 short* __restrict__ TtuH,
                                                 short* __restrict__ TtuL,
                                                 short* __restrict__ TtvH,
                                                 short* __restrict__ TtvL,
                                                 short* __restrict__ TmpTh,
                                                 short* __restrict__ TmpTl,
                                                 int s, int npair, int stage) {
  __shared__ short Ah[128][44], Al[128][44], Bh[128][44], Bl[128][44];
  const int z = blockIdx.z;
  const int side = z / npair, p = z % npair;
  const int a0 = p * 2 * s;
  const float* Ab;
  const short* BH; const short* BL;
  int ldb;
  if (stage == 1) {
    Ab = (side ? Gv : Gu) + (size_t)a0 * DIM + (a0 + s);
    BH = (side ? TtvH : TtuH) + (size_t)(a0 + s) * DIM + (a0 + s);
    BL = (side ? TtvL : TtuL) + (size_t)(a0 + s) * DIM + (a0 + s);
    ldb = DIM;
  } else {
    Ab = (side ? Tv : Tu) + (size_t)a0 * DIM + a0;
    BH = TmpTh + (size_t)z * s * s;
    BL = TmpTl + (size_t)z * s * s;
    ldb = s;
  }
  const int tid = threadIdx.x;
  const int bn = blockIdx.x, bm = blockIdx.y;
  const int wid = tid >> 6, wr = wid >> 1, wc = wid & 1;
  const int lane = tid & 63, l15 = lane & 15, k8 = (lane >> 4) << 3;
  f32x4 acc[4][4] = {};

  for (int kb = 0; kb < s; kb += 32) {
    __syncthreads();
#pragma unroll
    for (int ii = 0; ii < 4; ++ii) {
      int flat = tid + ii * 256;
      int r = flat >> 3, kq = (flat & 7) << 2;
      float4 v = *reinterpret_cast<const float4*>(Ab + (size_t)(bm * 128 + r) * DIM + kb + kq);
      short4v h, l;
      float fv[4] = {v.x, v.y, v.z, v.w};
#pragma unroll
      for (int j = 0; j < 4; ++j) {
        short hh = f2bf(fv[j]); h[j] = hh; l[j] = f2bf(fv[j] - bf2f(hh));
      }
      *reinterpret_cast<short4v*>(&Ah[r][kq]) = h;
      *reinterpret_cast<short4v*>(&Al[r][kq]) = l;
    }
#pragma unroll
    for (int ii = 0; ii < 2; ++ii) {
      int flat = tid + ii * 256;
      int n = flat >> 2, kk8 = (flat & 3) << 3;
      size_t off = (size_t)(bn * 128 + n) * ldb + kb + kk8;
      *reinterpret_cast<short8v*>(&Bh[n][kk8]) = *reinterpret_cast<const short8v*>(BH + off);
      *reinterpret_cast<short8v*>(&Bl[n][kk8]) = *reinterpret_cast<const short8v*>(BL + off);
    }
    __syncthreads();
    short8v ah[4], al_[4], bh[4], bl_[4];
#pragma unroll
    for (int m = 0; m < 4; ++m) {
      int r = wr * 64 + m * 16 + l15;
      ah[m] = *reinterpret_cast<const short8v*>(&Ah[r][k8]);
      al_[m] = *reinterpret_cast<const short8v*>(&Al[r][k8]);
    }
#pragma unroll
    for (int n = 0; n < 4; ++n) {
      int r = wc * 64 + n * 16 + l15;
      bh[n] = *reinterpret_cast<const short8v*>(&Bh[r][k8]);
      bl_[n] = *reinterpret_cast<const short8v*>(&Bl[r][k8]);
    }
#pragma unroll
    for (int m = 0; m < 4; ++m)
#pragma unroll
      for (int n = 0; n < 4; ++n) {
        acc[m][n] = __builtin_amdgcn_mfma_f32_16x16x32_bf16(ah[m], bh[n], acc[m][n], 0, 0, 0);
        acc[m][n] = __builtin_amdgcn_mfma_f32_16x16x32_bf16(ah[m], bl_[n], acc[m][n], 0, 0, 0);
        acc[m][n] = __builtin_amdgcn_mfma_f32_16x16x32_bf16(al_[m], bh[n], acc[m][n], 0, 0, 0);
      }
  }
  if (stage == 1) {
    size_t base = (size_t)z * s * s;
#pragma unroll
    for (int n = 0; n < 4; ++n) {
      int gcol = bn * 128 + wc * 64 + n * 16 + l15;
#pragma unroll
      for (int m = 0; m < 4; ++m) {
        int gk0 = bm * 128 + wr * 64 + m * 16 + ((lane >> 4) << 2);
        short4v h, l;
#pragma unroll
        for (int j = 0; j < 4; ++j) {
          float fv = acc[m][n][j];
          short hh = f2bf(fv);
          h[j] = hh;
          l[j] = f2bf(fv - bf2f(hh));
        }
        *reinterpret_cast<short4v*>(TmpTh + base + (size_t)gcol * s + gk0) = h;
        *reinterpret_cast<short4v*>(TmpTl + base + (size_t)gcol * s + gk0) = l;
      }
    }
  } else {
    float* T = side ? Tv : Tu;
    float* Cb = T + (size_t)a0 * DIM + (a0 + s);
    short* TH = side ? TtvH : TtuH;
    short* TL = side ? TtvL : TtuL;
#pragma unroll
    for (int n = 0; n < 4; ++n) {
      int gcol = bn * 128 + wc * 64 + n * 16 + l15;
#pragma unroll
      for (int m = 0; m < 4; ++m) {
        int grow0 = bm * 128 + wr * 64 + m * 16 + ((lane >> 4) << 2);
        short4v h, l;
#pragma unroll
        for (int j = 0; j < 4; ++j) {
          float fv = -acc[m][n][j];
          Cb[(size_t)(grow0 + j) * DIM + gcol] = fv;
          short hh = f2bf(fv);
          h[j] = hh;
          l[j] = f2bf(fv - bf2f(hh));
        }
        size_t off = (size_t)(a0 + s + gcol) * DIM + a0 + grow0;
        *reinterpret_cast<short4v*>(TH + off) = h;
        *reinterpret_cast<short4v*>(TL + off) = l;
      }
    }
  }
}

// ---------------------------------------------------------------------------
// P = T @ Au ; A = T f32 natural, Bt = AuT/AvT bf16 [c][k]. Out Pt = P^T f32.
__global__ __launch_bounds__(256) void pgemm_k(const float* __restrict__ Tu,
                                               const float* __restrict__ Tv,
                                               const short* __restrict__ AuTh,
                                               const short* __restrict__ AuTl,
                                               const short* __restrict__ AvTh,
                                               const short* __restrict__ AvTl,
                                               float* __restrict__ Ptu,
                                               float* __restrict__ Ptv) {
  __shared__ short Ah[128][44], Al[128][44], Bh[128][44], Bl[128][44];
  const int side = blockIdx.z;
  const float* A = side ? Tv : Tu;
  const short* BH = side ? AvTh : AuTh;
  const short* BL = side ? AvTl : AuTl;
  float* Out = side ? Ptv : Ptu;
  const int tid = threadIdx.x;
  const int bn = blockIdx.x, bm = blockIdx.y;
  const int wid = tid >> 6, wr = wid >> 1, wc = wid & 1;
  const int lane = tid & 63, l15 = lane & 15, k8 = (lane >> 4) << 3;
  f32x4 acc[4][4] = {};

  for (int kb = 0; kb < DIM; kb += 32) {
    __syncthreads();
#pragma unroll
    for (int ii = 0; ii < 4; ++ii) {
      int flat = tid + ii * 256;
      int r = flat >> 3, kq = (flat & 7) << 2;
      float4 v = *reinterpret_cast<const float4*>(A + (size_t)(bm * 128 + r) * DIM + kb + kq);
      short4v h, l;
      float fv[4] = {v.x, v.y, v.z, v.w};
#pragma unroll
      for (int j = 0; j < 4; ++j) {
        short hh = f2bf(fv[j]); h[j] = hh; l[j] = f2bf(fv[j] - bf2f(hh));
      }
      *reinterpret_cast<short4v*>(&Ah[r][kq]) = h;
      *reinterpret_cast<short4v*>(&Al[r][kq]) = l;
    }
#pragma unroll
    for (int ii = 0; ii < 2; ++ii) {
      int flat = tid + ii * 256;
      int n = flat >> 2, kk8 = (flat & 3) << 3;
      size_t off = (size_t)(bn * 128 + n) * DIM + kb + kk8;
      *reinterpret_cast<short8v*>(&Bh[n][kk8]) = *reinterpret_cast<const short8v*>(BH + off);
      *reinterpret_cast<short8v*>(&Bl[n][kk8]) = *reinterpret_cast<const short8v*>(BL + off);
    }
    __syncthreads();
    short8v ah[4], al_[4], bh[4], bl_[4];
#pragma unroll
    for (int m = 0; m < 4; ++m) {
      int r = wr * 64 + m * 16 + l15;
      ah[m] = *reinterpret_cast<const short8v*>(&Ah[r][k8]);
      al_[m] = *reinterpret_cast<const short8v*>(&Al[r][k8]);
    }
#pragma unroll
    for (int n = 0; n < 4; ++n) {
      int r = wc * 64 + n * 16 + l15;
      bh[n] = *reinterpret_cast<const short8v*>(&Bh[r][k8]);
      bl_[n] = *reinterpret_cast<const short8v*>(&Bl[r][k8]);
    }
#pragma unroll
    for (int m = 0; m < 4; ++m)
#pragma unroll
      for (int n = 0; n < 4; ++n) {
        acc[m][n] = __builtin_amdgcn_mfma_f32_16x16x32_bf16(ah[m], bh[n], acc[m][n], 0, 0, 0);
        acc[m][n] = __builtin_amdgcn_mfma_f32_16x16x32_bf16(ah[m], bl_[n], acc[m][n], 0, 0, 0);
        acc[m][n] = __builtin_amdgcn_mfma_f32_16x16x32_bf16(al_[m], bh[n], acc[m][n], 0, 0, 0);
      }
  }
#pragma unroll
  for (int n = 0; n < 4; ++n) {
    int gcol = bn * 128 + wc * 64 + n * 16 + l15;
#pragma unroll
    for (int m = 0; m < 4; ++m) {
      int grow0 = bm * 128 + wr * 64 + m * 16 + ((lane >> 4) << 2);
      float4 o;
      o.x = acc[m][n][0]; o.y = acc[m][n][1]; o.z = acc[m][n][2]; o.w = acc[m][n][3];
      *reinterpret_cast<float4*>(Out + (size_t)gcol * DIM + grow0) = o;
    }
  }
}

// ---------------------------------------------------------------------------
// Nt = N^T: A = Pt f32, Bt = AuT/AvT bf16.
// side0: Qu'[gcol][row] = (del - Nt)*sg[row] bf16; side1: Qvt f32 natural.
__global__ __launch_bounds__(256) void ngemm_k(const float* __restrict__ Ptu,
                                               const float* __restrict__ Ptv,
                                               const short* __restrict__ AuTh,
                                               const short* __restrict__ AuTl,
                                               const short* __restrict__ AvTh,
                                               const short* __restrict__ AvTl,
                                               const float* __restrict__ sg,
                                               short* __restrict__ QupH,
                                               short* __restrict__ QupL,
                                               float* __restrict__ Qvt) {
  __shared__ short Ah[128][44], Al[128][44], Bh[128][44], Bl[128][44];
  const int side = blockIdx.z;
  const float* A = side ? Ptv : Ptu;
  const short* BH = side ? AvTh : AuTh;
  const short* BL = side ? AvTl : AuTl;
  const int tid = threadIdx.x;
  const int bn = blockIdx.x, bm = blockIdx.y;
  const int wid = tid >> 6, wr = wid >> 1, wc = wid & 1;
  const int lane = tid & 63, l15 = lane & 15, k8 = (lane >> 4) << 3;
  f32x4 acc[4][4] = {};

  for (int kb = 0; kb < DIM; kb += 32) {
    __syncthreads();
#pragma unroll
    for (int ii = 0; ii < 4; ++ii) {
      int flat = tid + ii * 256;
      int r = flat >> 3, kq = (flat & 7) << 2;
      float4 v = *reinterpret_cast<const float4*>(A + (size_t)(bm * 128 + r) * DIM + kb + kq);
      short4v h, l;
      float fv[4] = {v.x, v.y, v.z, v.w};
#pragma unroll
      for (int j = 0; j < 4; ++j) {
        short hh = f2bf(fv[j]); h[j] = hh; l[j] = f2bf(fv[j] - bf2f(hh));
      }
      *reinterpret_cast<short4v*>(&Ah[r][kq]) = h;
      *reinterpret_cast<short4v*>(&Al[r][kq]) = l;
    }
#pragma unroll
    for (int ii = 0; ii < 2; ++ii) {
      int flat = tid + ii * 256;
      int n = flat >> 2, kk8 = (flat & 3) << 3;
      size_t off = (size_t)(bn * 128 + n) * DIM + kb + kk8;
      *reinterpret_cast<short8v*>(&Bh[n][kk8]) = *reinterpret_cast<const short8v*>(BH + off);
      *reinterpret_cast<short8v*>(&Bl[n][kk8]) = *reinterpret_cast<const short8v*>(BL + off);
    }
    __syncthreads();
    short8v ah[4], al_[4], bh[4], bl_[4];
#pragma unroll
    for (int m = 0; m < 4; ++m) {
      int r = wr * 64 + m * 16 + l15;
      ah[m] = *reinterpret_cast<const short8v*>(&Ah[r][k8]);
      al_[m] = *reinterpret_cast<const short8v*>(&Al[r][k8]);
    }
#pragma unroll
    for (int n = 0; n < 4; ++n) {
      int r = wc * 64 + n * 16 + l15;
      bh[n] = *reinterpret_cast<const short8v*>(&Bh[r][k8]);
      bl_[n] = *reinterpret_cast<const short8v*>(&Bl[r][k8]);
    }
#pragma unroll
    for (int m = 0; m < 4; ++m)
#pragma unroll
      for (int n = 0; n < 4; ++n) {
        acc[m][n] = __builtin_amdgcn_mfma_f32_16x16x32_bf16(ah[m], bh[n], acc[m][n], 0, 0, 0);
        acc[m][n] = __builtin_amdgcn_mfma_f32_16x16x32_bf16(ah[m], bl_[n], acc[m][n], 0, 0, 0);
        acc[m][n] = __builtin_amdgcn_mfma_f32_16x16x32_bf16(al_[m], bh[n], acc[m][n], 0, 0, 0);
      }
  }
#pragma unroll
  for (int n = 0; n < 4; ++n) {
    int gcol = bn * 128 + wc * 64 + n * 16 + l15;
#pragma unroll
    for (int m = 0; m < 4; ++m) {
      int grow0 = bm * 128 + wr * 64 + m * 16 + ((lane >> 4) << 2);
      if (side == 0) {
        short4v h, l;
#pragma unroll
        for (int j = 0; j < 4; ++j) {
          int row = grow0 + j;
          float del = (row == gcol) ? 1.0f : 0.0f;
          float q = (del - acc[m][n][j]) * sg[row];
          short hh = f2bf(q);
          h[j] = hh;
          l[j] = f2bf(q - bf2f(hh));
        }
        *reinterpret_cast<short4v*>(QupH + (size_t)gcol * DIM + grow0) = h;
        *reinterpret_cast<short4v*>(QupL + (size_t)gcol * DIM + grow0) = l;
      } else {
#pragma unroll
        for (int j = 0; j < 4; ++j) {
          int row = grow0 + j;
          float del = (row == gcol) ? 1.0f : 0.0f;
          Qvt[(size_t)row * DIM + gcol] = del - acc[m][n][j];
        }
      }
    }
  }
}

// ---------------------------------------------------------------------------
// MT = M^T = Qv^T @ Qu'^T : A = Qvt f32, Bt = Qu' bf16. Natural bf16 store.
__global__ __launch_bounds__(256) void mgemm2_k(const float* __restrict__ Qvt,
                                                const short* __restrict__ QupH,
                                                const short* __restrict__ QupL,
                                                short* __restrict__ MTh,
                                                short* __restrict__ MTl) {
  __shared__ short Ah[128][44], Al[128][44], Bh[128][44], Bl[128][44];
  const int tid = threadIdx.x;
  const int bn = blockIdx.x, bm = blockIdx.y;
  const int wid = tid >> 6, wr = wid >> 1, wc = wid & 1;
  const int lane = tid & 63, l15 = lane & 15, k8 = (lane >> 4) << 3;
  f32x4 acc[4][4] = {};

  for (int kb = 0; kb < DIM; kb += 32) {
    __syncthreads();
#pragma unroll
    for (int ii = 0; ii < 4; ++ii) {
      int flat = tid + ii * 256;
      int r = flat >> 3, kq = (flat & 7) << 2;
      float4 v = *reinterpret_cast<const float4*>(Qvt + (size_t)(bm * 128 + r) * DIM + kb + kq);
      short4v h, l;
      float fv[4] = {v.x, v.y, v.z, v.w};
#pragma unroll
      for (int j = 0; j < 4; ++j) {
        short hh = f2bf(fv[j]); h[j] = hh; l[j] = f2bf(fv[j] - bf2f(hh));
      }
      *reinterpret_cast<short4v*>(&Ah[r][kq]) = h;
      *reinterpret_cast<short4v*>(&Al[r][kq]) = l;
    }
#pragma unroll
    for (int ii = 0; ii < 2; ++ii) {
      int flat = tid + ii * 256;
      int n = flat >> 2, kk8 = (flat & 3) << 3;
      size_t off = (size_t)(bn * 128 + n) * DIM + kb + kk8;
      *reinterpret_cast<short8v*>(&Bh[n][kk8]) = *reinterpret_cast<const short8v*>(QupH + off);
      *reinterpret_cast<short8v*>(&Bl[n][kk8]) = *reinterpret_cast<const short8v*>(QupL + off);
    }
    __syncthreads();
    short8v ah[4], al_[4], bh[4], bl_[4];
#pragma unroll
    for (int m = 0; m < 4; ++m) {
      int r = wr * 64 + m * 16 + l15;
      ah[m] = *reinterpret_cast<const short8v*>(&Ah[r][k8]);
      al_[m] = *reinterpret_cast<const short8v*>(&Al[r][k8]);
    }
#pragma unroll
    for (int n = 0; n < 4; ++n) {
      int r = wc * 64 + n * 16 + l15;
      bh[n] = *reinterpret_cast<const short8v*>(&Bh[r][k8]);
      bl_[n] = *reinterpret_cast<const short8v*>(&Bl[r][k8]);
    }
#pragma unroll
    for (int m = 0; m < 4; ++m)
#pragma unroll
      for (int n = 0; n < 4; ++n) {
        acc[m][n] = __builtin_amdgcn_mfma_f32_16x16x32_bf16(ah[m], bh[n], acc[m][n], 0, 0, 0);
        acc[m][n] = __builtin_amdgcn_mfma_f32_16x16x32_bf16(ah[m], bl_[n], acc[m][n], 0, 0, 0);
        acc[m][n] = __builtin_amdgcn_mfma_f32_16x16x32_bf16(al_[m], bh[n], acc[m][n], 0, 0, 0);
      }
  }
#pragma unroll
  for (int n = 0; n < 4; ++n) {
    int gcol = bn * 128 + wc * 64 + n * 16 + l15;
#pragma unroll
    for (int m = 0; m < 4; ++m) {
      int grow0 = bm * 128 + wr * 64 + m * 16 + ((lane >> 4) << 2);
#pragma unroll
      for (int j = 0; j < 4; ++j) {
        float fv = acc[m][n][j];
        short hh = f2bf(fv);
        MTh[(size_t)(grow0 + j) * DIM + gcol] = hh;
        MTl[(size_t)(grow0 + j) * DIM + gcol] = f2bf(fv - bf2f(hh));
      }
    }
  }
}

// ---------------------------------------------------------------------------
// out[4096,1024] = x @ M + bias. Pure bf16-load GEMM: x pre-split (xH/xL),
// M^T pre-split (MTh/MTl). BM=128, BN=64 -> 512 blocks = 2/CU (2 waves/SIMD
// hide barrier stalls). LDS stride 36 shorts (18 dwords: l15*18 mod 32 is a
// full 16-cycle -> conflict-free b128 frag reads).
__global__ __launch_bounds__(256) void gemm_mfma_k(const short* __restrict__ xH,
                                                   const short* __restrict__ xL,
                                                   const short* __restrict__ Bthi,
                                                   const short* __restrict__ Btlo,
                                                   const float* __restrict__ bias,
                                                   float* __restrict__ out) {
  __shared__ short Ah[128][36], Al[128][36], Bh[64][36], Bl[64][36];
  const int tid = threadIdx.x;
  const int bn = blockIdx.x;  // 0..15
  const int bm = blockIdx.y;  // 0..31
  const int wid = tid >> 6, wr = wid >> 1, wc = wid & 1;
  const int lane = tid & 63, l15 = lane & 15, k8 = (lane >> 4) << 3;
  f32x4 acc[4][2] = {};

  for (int kb = 0; kb < DIM; kb += 32) {
    __syncthreads();
    // A: 128 rows x 32 k of xH/xL (short8v copies, no conversion)
#pragma unroll
    for (int ii = 0; ii < 2; ++ii) {
      int flat = tid + ii * 256;           // 0..511
      int r = flat >> 2, k8s = (flat & 3) << 3;
      size_t off = (size_t)(bm * 128 + r) * DIM + kb + k8s;
      *reinterpret_cast<short8v*>(&Ah[r][k8s]) = *reinterpret_cast<const short8v*>(xH + off);
      *reinterpret_cast<short8v*>(&Al[r][k8s]) = *reinterpret_cast<const short8v*>(xL + off);
    }
    // B: 64 n x 32 k of MTh/MTl
    {
      int n = tid >> 2, k8s = (tid & 3) << 3;
      size_t off = (size_t)(bn * 64 + n) * DIM + kb + k8s;
      *reinterpret_cast<short8v*>(&Bh[n][k8s]) = *reinterpret_cast<const short8v*>(Bthi + off);
      *reinterpret_cast<short8v*>(&Bl[n][k8s]) = *reinterpret_cast<const short8v*>(Btlo + off);
    }
    __syncthreads();

    short8v ah[4], al_[4], bh[2], bl_[2];
#pragma unroll
    for (int m = 0; m < 4; ++m) {
      int r = wr * 64 + m * 16 + l15;
      ah[m] = *reinterpret_cast<const short8v*>(&Ah[r][k8]);
      al_[m] = *reinterpret_cast<const short8v*>(&Al[r][k8]);
    }
#pragma unroll
    for (int n = 0; n < 2; ++n) {
      int r = wc * 32 + n * 16 + l15;
      bh[n] = *reinterpret_cast<const short8v*>(&Bh[r][k8]);
      bl_[n] = *reinterpret_cast<const short8v*>(&Bl[r][k8]);
    }
#pragma unroll
    for (int m = 0; m < 4; ++m)
#pragma unroll
      for (int n = 0; n < 2; ++n) {
        acc[m][n] = __builtin_amdgcn_mfma_f32_16x16x32_bf16(ah[m], bh[n], acc[m][n], 0, 0, 0);
        acc[m][n] = __builtin_amdgcn_mfma_f32_16x16x32_bf16(ah[m], bl_[n], acc[m][n], 0, 0, 0);
        acc[m][n] = __builtin_amdgcn_mfma_f32_16x16x32_bf16(al_[m], bh[n], acc[m][n], 0, 0, 0);
      }
  }

#pragma unroll
  for (int n = 0; n < 2; ++n) {
    int gcol = bn * 64 + wc * 32 + n * 16 + l15;
    float bv = bias[gcol];
#pragma unroll
    for (int m = 0; m < 4; ++m) {
      int grow0 = bm * 128 + wr * 64 + m * 16 + ((lane >> 4) << 2);
#pragma unroll
      for (int j = 0; j < 4; ++j)
        out[(size_t)(grow0 + j) * DIM + gcol] = acc[m][n][j] + bv;
    }
  }
}

// ---------------------------------------------------------------------------
extern "C" void kernel_launch(void* const* d_in, const int* in_sizes, int n_in,
                              void* d_out, int out_size, void* d_ws, size_t ws_size,
                              hipStream_t stream) {
  const float* x    = (const float*)d_in[0];
  const float* U    = (const float*)d_in[1];
  const float* V    = (const float*)d_in[2];
  const float* p    = (const float*)d_in[3];
  const float* bias = (const float*)d_in[4];
  float* out = (float*)d_out;

  float* F = (float*)d_ws;
  short* AuH  = (short*)F;
  short* AuL  = AuH + 1048576;
  short* AvH  = AuL + 1048576;
  short* AvL  = AvH + 1048576;
  short* QupH = AuH;                  // overlay after gram
  short* QupL = AuL;
  float* Qvt  = F + 1048576;          // overlays AvH/AvL
  float* Gu   = F + 2097152;
  float* Gv   = F + 3145728;
  float* Ptu  = Gu;                   // overlay after tree
  float* Ptv  = Gv;
  // xH overlays Gu+Gv (dead after ngemm): 4096x1024 shorts = 8 MB
  short* xH   = (short*)(F + 2097152);
  float* Tu   = F + 4194304;
  float* Tv   = F + 5242880;
  short* MTh  = (short*)Tu;           // overlay after pgemm
  short* MTl  = MTh + 1048576;
  short* TtuH = (short*)(F + 6291456);
  short* TtuL = TtuH + 1048576;
  short* TtvH = TtuL + 1048576;
  short* TtvL = TtvH + 1048576;
  // xL overlays all four Tt mirrors (dead after last tcombgg): 8 MB
  short* xL   = (short*)(F + 6291456);
  short* AuTh = (short*)(F + 8388608);
  short* AuTl = AuTh + 1048576;
  short* AvTh = AuTl + 1048576;
  short* AvTl = AvTh + 1048576;
  short* TmpTh = (short*)(F + 10485760);
  short* TmpTl = TmpTh + 524288;
  float* tinu = F + 11010048;
  float* tinv = tinu + DIM;
  float* sg   = tinv + DIM;

  prep_k<<<512, 256, 0, stream>>>(U, V, p, tinu, tinv, sg);
  asplit_k<<<1024, 256, 0, stream>>>(U, V, AuH, AuL, AvH, AvL);
  tsplUV_k<<<dim3(16, 16, 2), 256, 0, stream>>>(U, V, AuTh, AuTl, AvTh, AvTl);
  gram_k<<<dim3(8, 8, 2), 256, 0, stream>>>(U, V, AuH, AuL, AvH, AvL, Gu, Gv);
  hipMemsetAsync(Tu, 0, (size_t)4194304 * sizeof(float), stream);  // Tu|Tv|Tt
  tdiag64_k<<<32, 256, 0, stream>>>(Gu, Gv, tinu, tinv, Tu, Tv,
                                    TtuH, TtuL, TtvH, TtvL);
  tcomb64_k<<<16, 256, 0, stream>>>(Gu, Gv, Tu, Tv, TtuH, TtuL, TtvH, TtvL);
  tcombgg_k<<<dim3(1, 1, 8), 256, 0, stream>>>(Gu, Gv, Tu, Tv, TtuH, TtuL, TtvH, TtvL, TmpTh, TmpTl, 128, 4, 1);
  tcombgg_k<<<dim3(1, 1, 8), 256, 0, stream>>>(Gu, Gv, Tu, Tv, TtuH, TtuL, TtvH, TtvL, TmpTh, TmpTl, 128, 4, 2);
  tcombgg_k<<<dim3(2, 2, 4), 256, 0, stream>>>(Gu, Gv, Tu, Tv, TtuH, TtuL, TtvH, TtvL, TmpTh, TmpTl, 256, 2, 1);
  tcombgg_k<<<dim3(2, 2, 4), 256, 0, stream>>>(Gu, Gv, Tu, Tv, TtuH, TtuL, TtvH, TtvL, TmpTh, TmpTl, 256, 2, 2);
  tcombgg_k<<<dim3(4, 4, 2), 256, 0, stream>>>(Gu, Gv, Tu, Tv, TtuH, TtuL, TtvH, TtvL, TmpTh, TmpTl, 512, 1, 1);
  tcombgg_k<<<dim3(4, 4, 2), 256, 0, stream>>>(Gu, Gv, Tu, Tv, TtuH, TtuL, TtvH, TtvL, TmpTh, TmpTl, 512, 1, 2);
  pgemm_k<<<dim3(8, 8, 2), 256, 0, stream>>>(Tu, Tv, AuTh, AuTl, AvTh, AvTl, Ptu, Ptv);
  ngemm_k<<<dim3(8, 8, 2), 256, 0, stream>>>(Ptu, Ptv, AuTh, AuTl, AvTh, AvTl, sg, QupH, QupL, Qvt);
  // xH overlays Ptu/Ptv (dead now); xL overlays Tt (dead after tree)
  xsplit_k<<<2048, 256, 0, stream>>>(x, xH, xL);
  mgemm2_k<<<dim3(8, 8), 256, 0, stream>>>(Qvt, QupH, QupL, MTh, MTl);
  gemm_mfma_k<<<dim3(16, 32), 256, 0, stream>>>(xH, xL, MTh, MTl, bias, out);
}

// Round 15
// 325.673 us; speedup vs baseline: 2.2894x; 1.2761x over previous
//
#include <hip/hip_runtime.h>

#define DIM 1024
#define BATCH 4096

typedef __attribute__((ext_vector_type(8))) short short8v;
typedef __attribute__((ext_vector_type(4))) short short4v;
typedef __attribute__((ext_vector_type(4))) float f32x4;

// ---------------------------------------------------------------------------
__device__ __forceinline__ float dpp_reduce_bcast(float x) {
  int v = __builtin_bit_cast(int, x);
#define DPP_STEP(ctrl)                                                        \
  {                                                                           \
    int s = __builtin_amdgcn_update_dpp(0, v, ctrl, 0xf, 0xf, true);          \
    v = __builtin_bit_cast(                                                   \
        int, __builtin_bit_cast(float, v) + __builtin_bit_cast(float, s));    \
  }
  DPP_STEP(0x111) DPP_STEP(0x112) DPP_STEP(0x114) DPP_STEP(0x118)
  DPP_STEP(0x142) DPP_STEP(0x143)
#undef DPP_STEP
  return __builtin_bit_cast(float, __builtin_amdgcn_readlane(v, 63));
}

__device__ __forceinline__ short f2bf(float f) {
  unsigned u = __builtin_bit_cast(unsigned, f);
  u += 0x7FFFu + ((u >> 16) & 1u);
  return (short)(u >> 16);
}
__device__ __forceinline__ float bf2f(short h) {
  unsigned u = ((unsigned)(unsigned short)h) << 16;
  return __builtin_bit_cast(float, u);
}

// ---------------------------------------------------------------------------
// tau[m] = 2/||row m||^2 (U: row m; V: row 1023-m). Fused: sg sigmoid map.
__global__ __launch_bounds__(256) void prep_k(const float* __restrict__ U,
                                              const float* __restrict__ V,
                                              const float* __restrict__ p,
                                              float* __restrict__ tinu,
                                              float* __restrict__ tinv,
                                              float* __restrict__ sg) {
  int gi = blockIdx.x * 256 + threadIdx.x;
  if (gi < DIM) sg[gi] = 0.1f + 0.9f / (1.0f + __expf(-p[gi]));
  int gw = gi >> 6;
  int lane = threadIdx.x & 63;
  if (gw >= 2048) return;
  const float* src = (gw < 1024) ? (U + (size_t)gw * DIM)
                                 : (V + (size_t)(1023 - (gw - 1024)) * DIM);
  float s = 0.f;
#pragma unroll
  for (int q = 0; q < 4; ++q) {
    float4 v = *reinterpret_cast<const float4*>(src + q * 256 + lane * 4);
    s += v.x * v.x + v.y * v.y + v.z * v.z + v.w * v.w;
  }
  float tot = dpp_reduce_bcast(s);
  if (lane == 0) {
    float val = 2.0f / tot;
    if (gw < 1024) tinu[gw] = val; else tinv[gw - 1024] = val;
  }
}

// ---------------------------------------------------------------------------
// Natural-layout bf16 hi/lo splits of Au = U and Av = rows-of-V-reversed.
__global__ __launch_bounds__(256) void asplit_k(const float* __restrict__ U,
                                                const float* __restrict__ V,
                                                short* __restrict__ AuH,
                                                short* __restrict__ AuL,
                                                short* __restrict__ AvH,
                                                short* __restrict__ AvL) {
  int e = (blockIdx.x * 256 + threadIdx.x) * 8;
  int side = e >> 20;
  int idx = e & 1048575;
  int r = idx >> 10, c = idx & 1023;
  const float* src = side ? (V + (size_t)(1023 - r) * DIM + c)
                          : (U + (size_t)r * DIM + c);
  float4 a = *reinterpret_cast<const float4*>(src);
  float4 b = *reinterpret_cast<const float4*>(src + 4);
  float fv[8] = {a.x, a.y, a.z, a.w, b.x, b.y, b.z, b.w};
  short8v h, l;
#pragma unroll
  for (int j = 0; j < 8; ++j) {
    short hh = f2bf(fv[j]);
    h[j] = hh;
    l[j] = f2bf(fv[j] - bf2f(hh));
  }
  *reinterpret_cast<short8v*>((side ? AvH : AuH) + idx) = h;
  *reinterpret_cast<short8v*>((side ? AvL : AuL) + idx) = l;
}

// ---------------------------------------------------------------------------
// bf16 hi/lo split of x (natural layout). One pass, 8 elems/thread.
__global__ __launch_bounds__(256) void xsplit_k(const float* __restrict__ x,
                                                short* __restrict__ xH,
                                                short* __restrict__ xL) {
  int idx = (blockIdx.x * 256 + threadIdx.x) * 8;
  float4 a = *reinterpret_cast<const float4*>(x + idx);
  float4 b = *reinterpret_cast<const float4*>(x + idx + 4);
  float fv[8] = {a.x, a.y, a.z, a.w, b.x, b.y, b.z, b.w};
  short8v h, l;
#pragma unroll
  for (int j = 0; j < 8; ++j) {
    short hh = f2bf(fv[j]);
    h[j] = hh;
    l[j] = f2bf(fv[j] - bf2f(hh));
  }
  *reinterpret_cast<short8v*>(xH + idx) = h;
  *reinterpret_cast<short8v*>(xL + idx) = l;
}

// ---------------------------------------------------------------------------
// Transpose-split of U / V-flipped: AuT[c][k] = split(U[k][c]),
// AvT[c][k] = split(V[1023-k][c]).
__global__ __launch_bounds__(256) void tsplUV_k(const float* __restrict__ U,
                                                const float* __restrict__ V,
                                                short* __restrict__ AuTh,
                                                short* __restrict__ AuTl,
                                                short* __restrict__ AvTh,
                                                short* __restrict__ AvTl) {
  __shared__ float tile[64][68];
  const int side = blockIdx.z;
  const int rb = blockIdx.y * 64, cb = blockIdx.x * 64;
  const int f = threadIdx.x;
  const float* S = side ? V : U;
#pragma unroll
  for (int ii = 0; ii < 4; ++ii) {
    int flat = f + ii * 256;
    int r = flat >> 4, c4 = (flat & 15) << 2;
    int rs = rb + r;
    if (side) rs = 1023 - rs;
    float4 v = *reinterpret_cast<const float4*>(S + (size_t)rs * DIM + cb + c4);
    tile[r][c4 + 0] = v.x; tile[r][c4 + 1] = v.y; tile[r][c4 + 2] = v.z; tile[r][c4 + 3] = v.w;
  }
  __syncthreads();
#pragma unroll
  for (int ii = 0; ii < 2; ++ii) {
    int flat = f + ii * 256;
    int cc = flat >> 3, r8 = (flat & 7) << 3;
    short8v vh, vl;
#pragma unroll
    for (int j = 0; j < 8; ++j) {
      float fv = tile[r8 + j][cc];
      short hh = f2bf(fv);
      vh[j] = hh;
      vl[j] = f2bf(fv - bf2f(hh));
    }
    size_t off = (size_t)(cb + cc) * DIM + rb + r8;
    *reinterpret_cast<short8v*>((side ? AvTh : AuTh) + off) = vh;
    *reinterpret_cast<short8v*>((side ? AvTl : AuTl) + off) = vl;
  }
}

// ---------------------------------------------------------------------------
// Gram: G[m][n] = Au_m . Au_n (3-term split-bf16). 64x64 tile -> grid
// (16,16,2) = 512 blocks = 2/CU (occupancy fix: was 128 blocks @128-tile).
__global__ __launch_bounds__(256) void gram_k(const float* __restrict__ U,
                                              const float* __restrict__ V,
                                              const short* __restrict__ AuH,
                                              const short* __restrict__ AuL,
                                              const short* __restrict__ AvH,
                                              const short* __restrict__ AvL,
                                              float* __restrict__ Gu,
                                              float* __restrict__ Gv) {
  __shared__ short Ah[64][36], Al[64][36], Bh[64][36], Bl[64][36];
  const int side = blockIdx.z;
  const float* A = side ? V : U;
  const short* BH = side ? AvH : AuH;
  const short* BL = side ? AvL : AuL;
  float* G = side ? Gv : Gu;
  const int tid = threadIdx.x;
  const int bn = blockIdx.x, bm = blockIdx.y;
  const int wid = tid >> 6, wr = wid >> 1, wc = wid & 1;
  const int lane = tid & 63, l15 = lane & 15, k8 = (lane >> 4) << 3;
  f32x4 acc[2][2] = {};

  for (int kb = 0; kb < DIM; kb += 32) {
    __syncthreads();
#pragma unroll
    for (int ii = 0; ii < 2; ++ii) {
      int flat = tid + ii * 256;          // 0..511
      int r = flat >> 3, kq = (flat & 7) << 2;
      int rg = bm * 64 + r;
      int rs = side ? (1023 - rg) : rg;
      float4 v = *reinterpret_cast<const float4*>(A + (size_t)rs * DIM + kb + kq);
      short4v h, l;
      float fv[4] = {v.x, v.y, v.z, v.w};
#pragma unroll
      for (int j = 0; j < 4; ++j) {
        short hh = f2bf(fv[j]); h[j] = hh; l[j] = f2bf(fv[j] - bf2f(hh));
      }
      *reinterpret_cast<short4v*>(&Ah[r][kq]) = h;
      *reinterpret_cast<short4v*>(&Al[r][kq]) = l;
    }
    {
      int n = tid >> 2, k8s = (tid & 3) << 3;
      size_t off = (size_t)(bn * 64 + n) * DIM + kb + k8s;
      *reinterpret_cast<short8v*>(&Bh[n][k8s]) = *reinterpret_cast<const short8v*>(BH + off);
      *reinterpret_cast<short8v*>(&Bl[n][k8s]) = *reinterpret_cast<const short8v*>(BL + off);
    }
    __syncthreads();
    short8v ah[2], al_[2], bh[2], bl_[2];
#pragma unroll
    for (int m = 0; m < 2; ++m) {
      int r = wr * 32 + m * 16 + l15;
      ah[m] = *reinterpret_cast<const short8v*>(&Ah[r][k8]);
      al_[m] = *reinterpret_cast<const short8v*>(&Al[r][k8]);
    }
#pragma unroll
    for (int n = 0; n < 2; ++n) {
      int r = wc * 32 + n * 16 + l15;
      bh[n] = *reinterpret_cast<const short8v*>(&Bh[r][k8]);
      bl_[n] = *reinterpret_cast<const short8v*>(&Bl[r][k8]);
    }
#pragma unroll
    for (int m = 0; m < 2; ++m)
#pragma unroll
      for (int n = 0; n < 2; ++n) {
        acc[m][n] = __builtin_amdgcn_mfma_f32_16x16x32_bf16(ah[m], bh[n], acc[m][n], 0, 0, 0);
        acc[m][n] = __builtin_amdgcn_mfma_f32_16x16x32_bf16(ah[m], bl_[n], acc[m][n], 0, 0, 0);
        acc[m][n] = __builtin_amdgcn_mfma_f32_16x16x32_bf16(al_[m], bh[n], acc[m][n], 0, 0, 0);
      }
  }
#pragma unroll
  for (int n = 0; n < 2; ++n) {
    int gcol = bn * 64 + wc * 32 + n * 16 + l15;
#pragma unroll
    for (int m = 0; m < 2; ++m) {
      int grow0 = bm * 64 + wr * 32 + m * 16 + ((lane >> 4) << 2);
#pragma unroll
      for (int j = 0; j < 4; ++j)
        G[(size_t)(grow0 + j) * DIM + gcol] = acc[m][n][j];
    }
  }
}

// ---------------------------------------------------------------------------
// 64x64 diagonal T blocks via recursive in-LDS triangular inversion (proven).
__global__ __launch_bounds__(256) void tdiag64_k(const float* __restrict__ Gu,
                                                 const float* __restrict__ Gv,
                                                 const float* __restrict__ tinu,
                                                 const float* __restrict__ tinv,
                                                 float* __restrict__ Tu,
                                                 float* __restrict__ Tv,
                                                 short* __restrict__ TtuH,
                                                 short* __restrict__ TtuL,
                                                 short* __restrict__ TtvH,
                                                 short* __restrict__ TtvL) {
  __shared__ float B[64][65];
  __shared__ float T[64][65];
  __shared__ float Wb[1024];
  int z = blockIdx.x >> 4;
  int d = blockIdx.x & 15;
  const float* G = z ? Gv : Gu;
  const float* tau = z ? tinv : tinu;
  float* Tg = z ? Tv : Tu;
  short* TH = z ? TtvH : TtuH;
  short* TL = z ? TtvL : TtuL;
  int b0 = d * 64;
  int tid = threadIdx.x;

  for (int e = tid; e < 4096; e += 256) {
    int r = e >> 6, c = e & 63;
    float v;
    if (r < c) v = G[(size_t)(b0 + r) * DIM + b0 + c];
    else if (r == c) v = 1.0f / tau[b0 + r];
    else v = 0.f;
    B[r][c] = v;
    T[r][c] = 0.f;
  }
  __syncthreads();

  if (tid < 16) {
    int o = tid * 4;
    float X[4][4];
#pragma unroll
    for (int k = 0; k < 4; ++k) {
      X[k][k] = 1.0f / B[o + k][o + k];
#pragma unroll
      for (int i = 2; i >= 0; --i) {
        if (i < k) {
          float s = 0.f;
#pragma unroll
          for (int j = 0; j < 4; ++j)
            if (j > i && j <= k) s = fmaf(B[o + i][o + j], X[j][k], s);
          X[i][k] = -s / B[o + i][o + i];
        }
      }
    }
#pragma unroll
    for (int k = 0; k < 4; ++k)
#pragma unroll
      for (int i = 0; i < 4; ++i)
        if (i <= k) T[o + i][o + k] = X[i][k];
  }
  __syncthreads();

  for (int s = 4; s <= 32; s <<= 1) {
    int ss = s * s;
    int tot = (32 / s) * ss;
    for (int e = tid; e < tot; e += 256) {
      int p = e / ss;
      int rem = e - p * ss;
      int m = rem / s;
      int j = rem - m * s;
      int o = p * 2 * s;
      float acc = 0.f;
      for (int l = 0; l < s; ++l)
        acc = fmaf(B[o + m][o + s + l], T[o + s + l][o + s + j], acc);
      Wb[e] = acc;
    }
    __syncthreads();
    for (int e = tid; e < tot; e += 256) {
      int p = e / ss;
      int rem = e - p * ss;
      int i = rem / s;
      int j = rem - i * s;
      int o = p * 2 * s;
      float acc = 0.f;
      for (int m = 0; m < s; ++m)
        acc = fmaf(T[o + i][o + m], Wb[p * ss + m * s + j], acc);
      T[o + i][o + s + j] = -acc;
    }
    __syncthreads();
  }

  for (int e = tid; e < 1024; e += 256) {
    int r = e >> 4, c4 = (e & 15) << 2;
    float4 v;
    v.x = T[r][c4]; v.y = T[r][c4 + 1]; v.z = T[r][c4 + 2]; v.w = T[r][c4 + 3];
    *reinterpret_cast<float4*>(Tg + (size_t)(b0 + r) * DIM + b0 + c4) = v;
  }
  for (int e = tid; e < 512; e += 256) {
    int c = e >> 3, r8 = (e & 7) << 3;
    short8v h, l;
#pragma unroll
    for (int j = 0; j < 8; ++j) {
      float fv = T[r8 + j][c];
      short hh = f2bf(fv);
      h[j] = hh;
      l[j] = f2bf(fv - bf2f(hh));
    }
    size_t off = (size_t)(b0 + c) * DIM + b0 + r8;
    *reinterpret_cast<short8v*>(TH + off) = h;
    *reinterpret_cast<short8v*>(TL + off) = l;
  }
}

// ---------------------------------------------------------------------------
// Level s=64 combine, in-LDS; also writes bf16 transposed mirror of X.
__global__ __launch_bounds__(256) void tcomb64_k(const float* __restrict__ Gu,
                                                 const float* __restrict__ Gv,
                                                 float* __restrict__ Tu,
                                                 float* __restrict__ Tv,
                                                 short* __restrict__ TtuH,
                                                 short* __restrict__ TtuL,
                                                 short* __restrict__ TtvH,
                                                 short* __restrict__ TtvL) {
  __shared__ float TA[64][68], SS[64][68], TB[64][68], W[64][68];
  int zz = blockIdx.x;
  int side = zz >> 3, p = zz & 7;
  int a0 = p * 128;
  const float* G = side ? Gv : Gu;
  float* T = side ? Tv : Tu;
  short* TH = side ? TtvH : TtuH;
  short* TL = side ? TtvL : TtuL;
  int tid = threadIdx.x;
#pragma unroll
  for (int ii = 0; ii < 4; ++ii) {
    int flat = tid + ii * 256;
    int r = flat >> 4, c4 = (flat & 15) << 2;
    *reinterpret_cast<float4*>(&TA[r][c4]) =
        *reinterpret_cast<const float4*>(T + (size_t)(a0 + r) * DIM + a0 + c4);
    *reinterpret_cast<float4*>(&SS[r][c4]) =
        *reinterpret_cast<const float4*>(G + (size_t)(a0 + r) * DIM + a0 + 64 + c4);
    *reinterpret_cast<float4*>(&TB[r][c4]) =
        *reinterpret_cast<const float4*>(T + (size_t)(a0 + 64 + r) * DIM + a0 + 64 + c4);
  }
  __syncthreads();
  int tx = tid & 15, ty = tid >> 4;
  float acc[4][4] = {};
  for (int k = 0; k < 64; ++k) {
    float a[4], b[4];
#pragma unroll
    for (int m = 0; m < 4; ++m) a[m] = SS[ty * 4 + m][k];
#pragma unroll
    for (int n = 0; n < 4; ++n) b[n] = TB[k][tx * 4 + n];
#pragma unroll
    for (int m = 0; m < 4; ++m)
#pragma unroll
      for (int n = 0; n < 4; ++n) acc[m][n] = fmaf(a[m], b[n], acc[m][n]);
  }
#pragma unroll
  for (int m = 0; m < 4; ++m)
#pragma unroll
    for (int n = 0; n < 4; ++n) W[ty * 4 + m][tx * 4 + n] = acc[m][n];
  __syncthreads();
  float acc2[4][4] = {};
  for (int k = 0; k < 64; ++k) {
    float a[4], b[4];
#pragma unroll
    for (int m = 0; m < 4; ++m) a[m] = TA[ty * 4 + m][k];
#pragma unroll
    for (int n = 0; n < 4; ++n) b[n] = W[k][tx * 4 + n];
#pragma unroll
    for (int m = 0; m < 4; ++m)
#pragma unroll
      for (int n = 0; n < 4; ++n) acc2[m][n] = fmaf(a[m], b[n], acc2[m][n]);
  }
#pragma unroll
  for (int m = 0; m < 4; ++m)
#pragma unroll
    for (int n = 0; n < 4; ++n)
      T[(size_t)(a0 + ty * 4 + m) * DIM + a0 + 64 + tx * 4 + n] = -acc2[m][n];
#pragma unroll
  for (int n = 0; n < 4; ++n) {
    short4v h, l;
#pragma unroll
    for (int j = 0; j < 4; ++j) {
      float fv = -acc2[j][n];
      short hh = f2bf(fv);
      h[j] = hh;
      l[j] = f2bf(fv - bf2f(hh));
    }
    size_t off = (size_t)(a0 + 64 + tx * 4 + n) * DIM + a0 + ty * 4;
    *reinterpret_cast<short4v*>(TH + off) = h;
    *reinterpret_cast<short4v*>(TL + off) = l;
  }
}

// ---------------------------------------------------------------------------
// Tree levels s>=128. stage1: TmpT = (S_AB @ T_B)^T bf16 (Bt = Tt diag).
// stage2: T off-diag = -T_A @ Tmp (Bt = TmpT); also writes bf16 mirror of X.
__global__ __launch_bounds__(256) void tcombgg_k(const float* __restrict__ Gu,
                                                 const float* __restrict__ Gv,
                                                 float* __restrict__ Tu,
                                                 float* __restrict__ Tv,
                                                 short* __restrict__ TtuH,
                                                 short* __restrict__ TtuL,
                                                 short* __restrict__ TtvH,
                                                 short* __restrict__ TtvL,
                                                 short* __restrict__ TmpTh,
                                                 short* __restrict__ TmpTl,
                                                 int s, int npair, int stage) {
  __shared__ short Ah[128][44], Al[128][44], Bh[128][44], Bl[128][44];
  const int z = blockIdx.z;
  const int side = z / npair, p = z % npair;
  const int a0 = p * 2 * s;
  const float* Ab;
  const short* BH; const short* BL;
  int ldb;
  if (stage == 1) {
    Ab = (side ? Gv : Gu) + (size_t)a0 * DIM + (a0 + s);
    BH = (side ? TtvH : TtuH) + (size_t)(a0 + s) * DIM + (a0 + s);
    BL = (side ? TtvL : TtuL) + (size_t)(a0 + s) * DIM + (a0 + s);
    ldb = DIM;
  } else {
    Ab = (side ? Tv : Tu) + (size_t)a0 * DIM + a0;
    BH = TmpTh + (size_t)z * s * s;
    BL = TmpTl + (size_t)z * s * s;
    ldb = s;
  }
  const int tid = threadIdx.x;
  const int bn = blockIdx.x, bm = blockIdx.y;
  const int wid = tid >> 6, wr = wid >> 1, wc = wid & 1;
  const int lane = tid & 63, l15 = lane & 15, k8 = (lane >> 4) << 3;
  f32x4 acc[4][4] = {};

  for (int kb = 0; kb < s; kb += 32) {
    __syncthreads();
#pragma unroll
    for (int ii = 0; ii < 4; ++ii) {
      int flat = tid + ii * 256;
      int r = flat >> 3, kq = (flat & 7) << 2;
      float4 v = *reinterpret_cast<const float4*>(Ab + (size_t)(bm * 128 + r) * DIM + kb + kq);
      short4v h, l;
      float fv[4] = {v.x, v.y, v.z, v.w};
#pragma unroll
      for (int j = 0; j < 4; ++j) {
        short hh = f2bf(fv[j]); h[j] = hh; l[j] = f2bf(fv[j] - bf2f(hh));
      }
      *reinterpret_cast<short4v*>(&Ah[r][kq]) = h;
      *reinterpret_cast<short4v*>(&Al[r][kq]) = l;
    }
#pragma unroll
    for (int ii = 0; ii < 2; ++ii) {
      int flat = tid + ii * 256;
      int n = flat >> 2, kk8 = (flat & 3) << 3;
      size_t off = (size_t)(bn * 128 + n) * ldb + kb + kk8;
      *reinterpret_cast<short8v*>(&Bh[n][kk8]) = *reinterpret_cast<const short8v*>(BH + off);
      *reinterpret_cast<short8v*>(&Bl[n][kk8]) = *reinterpret_cast<const short8v*>(BL + off);
    }
    __syncthreads();
    short8v ah[4], al_[4], bh[4], bl_[4];
#pragma unroll
    for (int m = 0; m < 4; ++m) {
      int r = wr * 64 + m * 16 + l15;
      ah[m] = *reinterpret_cast<const short8v*>(&Ah[r][k8]);
      al_[m] = *reinterpret_cast<const short8v*>(&Al[r][k8]);
    }
#pragma unroll
    for (int n = 0; n < 4; ++n) {
      int r = wc * 64 + n * 16 + l15;
      bh[n] = *reinterpret_cast<const short8v*>(&Bh[r][k8]);
      bl_[n] = *reinterpret_cast<const short8v*>(&Bl[r][k8]);
    }
#pragma unroll
    for (int m = 0; m < 4; ++m)
#pragma unroll
      for (int n = 0; n < 4; ++n) {
        acc[m][n] = __builtin_amdgcn_mfma_f32_16x16x32_bf16(ah[m], bh[n], acc[m][n], 0, 0, 0);
        acc[m][n] = __builtin_amdgcn_mfma_f32_16x16x32_bf16(ah[m], bl_[n], acc[m][n], 0, 0, 0);
        acc[m][n] = __builtin_amdgcn_mfma_f32_16x16x32_bf16(al_[m], bh[n], acc[m][n], 0, 0, 0);
      }
  }
  if (stage == 1) {
    size_t base = (size_t)z * s * s;
#pragma unroll
    for (int n = 0; n < 4; ++n) {
      int gcol = bn * 128 + wc * 64 + n * 16 + l15;
#pragma unroll
      for (int m = 0; m < 4; ++m) {
        int gk0 = bm * 128 + wr * 64 + m * 16 + ((lane >> 4) << 2);
        short4v h, l;
#pragma unroll
        for (int j = 0; j < 4; ++j) {
          float fv = acc[m][n][j];
          short hh = f2bf(fv);
          h[j] = hh;
          l[j] = f2bf(fv - bf2f(hh));
        }
        *reinterpret_cast<short4v*>(TmpTh + base + (size_t)gcol * s + gk0) = h;
        *reinterpret_cast<short4v*>(TmpTl + base + (size_t)gcol * s + gk0) = l;
      }
    }
  } else {
    float* T = side ? Tv : Tu;
    float* Cb = T + (size_t)a0 * DIM + (a0 + s);
    short* TH = side ? TtvH : TtuH;
    short* TL = side ? TtvL : TtuL;
#pragma unroll
    for (int n = 0; n < 4; ++n) {
      int gcol = bn * 128 + wc * 64 + n * 16 + l15;
#pragma unroll
      for (int m = 0; m < 4; ++m) {
        int grow0 = bm * 128 + wr * 64 + m * 16 + ((lane >> 4) << 2);
        short4v h, l;
#pragma unroll
        for (int j = 0; j < 4; ++j) {
          float fv = -acc[m][n][j];
          Cb[(size_t)(grow0 + j) * DIM + gcol] = fv;
          short hh = f2bf(fv);
          h[j] = hh;
          l[j] = f2bf(fv - bf2f(hh));
        }
        size_t off = (size_t)(a0 + s + gcol) * DIM + a0 + grow0;
        *reinterpret_cast<short4v*>(TH + off) = h;
        *reinterpret_cast<short4v*>(TL + off) = l;
      }
    }
  }
}

// ---------------------------------------------------------------------------
// P = T @ Au ; A = T f32 natural, Bt = AuT/AvT bf16 [c][k]. Out Pt = P^T f32.
// 64x64 tile -> grid (16,16,2) = 512 blocks.
__global__ __launch_bounds__(256) void pgemm_k(const float* __restrict__ Tu,
                                               const float* __restrict__ Tv,
                                               const short* __restrict__ AuTh,
                                               const short* __restrict__ AuTl,
                                               const short* __restrict__ AvTh,
                                               const short* __restrict__ AvTl,
                                               float* __restrict__ Ptu,
                                               float* __restrict__ Ptv) {
  __shared__ short Ah[64][36], Al[64][36], Bh[64][36], Bl[64][36];
  const int side = blockIdx.z;
  const float* A = side ? Tv : Tu;
  const short* BH = side ? AvTh : AuTh;
  const short* BL = side ? AvTl : AuTl;
  float* Out = side ? Ptv : Ptu;
  const int tid = threadIdx.x;
  const int bn = blockIdx.x, bm = blockIdx.y;
  const int wid = tid >> 6, wr = wid >> 1, wc = wid & 1;
  const int lane = tid & 63, l15 = lane & 15, k8 = (lane >> 4) << 3;
  f32x4 acc[2][2] = {};

  for (int kb = 0; kb < DIM; kb += 32) {
    __syncthreads();
#pragma unroll
    for (int ii = 0; ii < 2; ++ii) {
      int flat = tid + ii * 256;
      int r = flat >> 3, kq = (flat & 7) << 2;
      float4 v = *reinterpret_cast<const float4*>(A + (size_t)(bm * 64 + r) * DIM + kb + kq);
      short4v h, l;
      float fv[4] = {v.x, v.y, v.z, v.w};
#pragma unroll
      for (int j = 0; j < 4; ++j) {
        short hh = f2bf(fv[j]); h[j] = hh; l[j] = f2bf(fv[j] - bf2f(hh));
      }
      *reinterpret_cast<short4v*>(&Ah[r][kq]) = h;
      *reinterpret_cast<short4v*>(&Al[r][kq]) = l;
    }
    {
      int n = tid >> 2, k8s = (tid & 3) << 3;
      size_t off = (size_t)(bn * 64 + n) * DIM + kb + k8s;
      *reinterpret_cast<short8v*>(&Bh[n][k8s]) = *reinterpret_cast<const short8v*>(BH + off);
      *reinterpret_cast<short8v*>(&Bl[n][k8s]) = *reinterpret_cast<const short8v*>(BL + off);
    }
    __syncthreads();
    short8v ah[2], al_[2], bh[2], bl_[2];
#pragma unroll
    for (int m = 0; m < 2; ++m) {
      int r = wr * 32 + m * 16 + l15;
      ah[m] = *reinterpret_cast<const short8v*>(&Ah[r][k8]);
      al_[m] = *reinterpret_cast<const short8v*>(&Al[r][k8]);
    }
#pragma unroll
    for (int n = 0; n < 2; ++n) {
      int r = wc * 32 + n * 16 + l15;
      bh[n] = *reinterpret_cast<const short8v*>(&Bh[r][k8]);
      bl_[n] = *reinterpret_cast<const short8v*>(&Bl[r][k8]);
    }
#pragma unroll
    for (int m = 0; m < 2; ++m)
#pragma unroll
      for (int n = 0; n < 2; ++n) {
        acc[m][n] = __builtin_amdgcn_mfma_f32_16x16x32_bf16(ah[m], bh[n], acc[m][n], 0, 0, 0);
        acc[m][n] = __builtin_amdgcn_mfma_f32_16x16x32_bf16(ah[m], bl_[n], acc[m][n], 0, 0, 0);
        acc[m][n] = __builtin_amdgcn_mfma_f32_16x16x32_bf16(al_[m], bh[n], acc[m][n], 0, 0, 0);
      }
  }
#pragma unroll
  for (int n = 0; n < 2; ++n) {
    int gcol = bn * 64 + wc * 32 + n * 16 + l15;
#pragma unroll
    for (int m = 0; m < 2; ++m) {
      int grow0 = bm * 64 + wr * 32 + m * 16 + ((lane >> 4) << 2);
      float4 o;
      o.x = acc[m][n][0]; o.y = acc[m][n][1]; o.z = acc[m][n][2]; o.w = acc[m][n][3];
      *reinterpret_cast<float4*>(Out + (size_t)gcol * DIM + grow0) = o;
    }
  }
}

// ---------------------------------------------------------------------------
// Nt = N^T: A = Pt f32, Bt = AuT/AvT bf16. 64x64 tile -> grid (16,16,2).
// side0: Qu'[gcol][row] = (del - Nt)*sg[row] bf16; side1: Qvt f32 natural.
__global__ __launch_bounds__(256) void ngemm_k(const float* __restrict__ Ptu,
                                               const float* __restrict__ Ptv,
                                               const short* __restrict__ AuTh,
                                               const short* __restrict__ AuTl,
                                               const short* __restrict__ AvTh,
                                               const short* __restrict__ AvTl,
                                               const float* __restrict__ sg,
                                               short* __restrict__ QupH,
                                               short* __restrict__ QupL,
                                               float* __restrict__ Qvt) {
  __shared__ short Ah[64][36], Al[64][36], Bh[64][36], Bl[64][36];
  const int side = blockIdx.z;
  const float* A = side ? Ptv : Ptu;
  const short* BH = side ? AvTh : AuTh;
  const short* BL = side ? AvTl : AuTl;
  const int tid = threadIdx.x;
  const int bn = blockIdx.x, bm = blockIdx.y;
  const int wid = tid >> 6, wr = wid >> 1, wc = wid & 1;
  const int lane = tid & 63, l15 = lane & 15, k8 = (lane >> 4) << 3;
  f32x4 acc[2][2] = {};

  for (int kb = 0; kb < DIM; kb += 32) {
    __syncthreads();
#pragma unroll
    for (int ii = 0; ii < 2; ++ii) {
      int flat = tid + ii * 256;
      int r = flat >> 3, kq = (flat & 7) << 2;
      float4 v = *reinterpret_cast<const float4*>(A + (size_t)(bm * 64 + r) * DIM + kb + kq);
      short4v h, l;
      float fv[4] = {v.x, v.y, v.z, v.w};
#pragma unroll
      for (int j = 0; j < 4; ++j) {
        short hh = f2bf(fv[j]); h[j] = hh; l[j] = f2bf(fv[j] - bf2f(hh));
      }
      *reinterpret_cast<short4v*>(&Ah[r][kq]) = h;
      *reinterpret_cast<short4v*>(&Al[r][kq]) = l;
    }
    {
      int n = tid >> 2, k8s = (tid & 3) << 3;
      size_t off = (size_t)(bn * 64 + n) * DIM + kb + k8s;
      *reinterpret_cast<short8v*>(&Bh[n][k8s]) = *reinterpret_cast<const short8v*>(BH + off);
      *reinterpret_cast<short8v*>(&Bl[n][k8s]) = *reinterpret_cast<const short8v*>(BL + off);
    }
    __syncthreads();
    short8v ah[2], al_[2], bh[2], bl_[2];
#pragma unroll
    for (int m = 0; m < 2; ++m) {
      int r = wr * 32 + m * 16 + l15;
      ah[m] = *reinterpret_cast<const short8v*>(&Ah[r][k8]);
      al_[m] = *reinterpret_cast<const short8v*>(&Al[r][k8]);
    }
#pragma unroll
    for (int n = 0; n < 2; ++n) {
      int r = wc * 32 + n * 16 + l15;
      bh[n] = *reinterpret_cast<const short8v*>(&Bh[r][k8]);
      bl_[n] = *reinterpret_cast<const short8v*>(&Bl[r][k8]);
    }
#pragma unroll
    for (int m = 0; m < 2; ++m)
#pragma unroll
      for (int n = 0; n < 2; ++n) {
        acc[m][n] = __builtin_amdgcn_mfma_f32_16x16x32_bf16(ah[m], bh[n], acc[m][n], 0, 0, 0);
        acc[m][n] = __builtin_amdgcn_mfma_f32_16x16x32_bf16(ah[m], bl_[n], acc[m][n], 0, 0, 0);
        acc[m][n] = __builtin_amdgcn_mfma_f32_16x16x32_bf16(al_[m], bh[n], acc[m][n], 0, 0, 0);
      }
  }
#pragma unroll
  for (int n = 0; n < 2; ++n) {
    int gcol = bn * 64 + wc * 32 + n * 16 + l15;
#pragma unroll
    for (int m = 0; m < 2; ++m) {
      int grow0 = bm * 64 + wr * 32 + m * 16 + ((lane >> 4) << 2);
      if (side == 0) {
        short4v h, l;
#pragma unroll
        for (int j = 0; j < 4; ++j) {
          int row = grow0 + j;
          float del = (row == gcol) ? 1.0f : 0.0f;
          float q = (del - acc[m][n][j]) * sg[row];
          short hh = f2bf(q);
          h[j] = hh;
          l[j] = f2bf(q - bf2f(hh));
        }
        *reinterpret_cast<short4v*>(QupH + (size_t)gcol * DIM + grow0) = h;
        *reinterpret_cast<short4v*>(QupL + (size_t)gcol * DIM + grow0) = l;
      } else {
#pragma unroll
        for (int j = 0; j < 4; ++j) {
          int row = grow0 + j;
          float del = (row == gcol) ? 1.0f : 0.0f;
          Qvt[(size_t)row * DIM + gcol] = del - acc[m][n][j];
        }
      }
    }
  }
}

// ---------------------------------------------------------------------------
// MT = M^T = Qv^T @ Qu'^T : A = Qvt f32, Bt = Qu' bf16. 64x64 tile ->
// grid (16,16) = 256 blocks. Natural bf16 store.
__global__ __launch_bounds__(256) void mgemm2_k(const float* __restrict__ Qvt,
                                                const short* __restrict__ QupH,
                                                const short* __restrict__ QupL,
                                                short* __restrict__ MTh,
                                                short* __restrict__ MTl) {
  __shared__ short Ah[64][36], Al[64][36], Bh[64][36], Bl[64][36];
  const int tid = threadIdx.x;
  const int bn = blockIdx.x, bm = blockIdx.y;
  const int wid = tid >> 6, wr = wid >> 1, wc = wid & 1;
  const int lane = tid & 63, l15 = lane & 15, k8 = (lane >> 4) << 3;
  f32x4 acc[2][2] = {};

  for (int kb = 0; kb < DIM; kb += 32) {
    __syncthreads();
#pragma unroll
    for (int ii = 0; ii < 2; ++ii) {
      int flat = tid + ii * 256;
      int r = flat >> 3, kq = (flat & 7) << 2;
      float4 v = *reinterpret_cast<const float4*>(Qvt + (size_t)(bm * 64 + r) * DIM + kb + kq);
      short4v h, l;
      float fv[4] = {v.x, v.y, v.z, v.w};
#pragma unroll
      for (int j = 0; j < 4; ++j) {
        short hh = f2bf(fv[j]); h[j] = hh; l[j] = f2bf(fv[j] - bf2f(hh));
      }
      *reinterpret_cast<short4v*>(&Ah[r][kq]) = h;
      *reinterpret_cast<short4v*>(&Al[r][kq]) = l;
    }
    {
      int n = tid >> 2, k8s = (tid & 3) << 3;
      size_t off = (size_t)(bn * 64 + n) * DIM + kb + k8s;
      *reinterpret_cast<short8v*>(&Bh[n][k8s]) = *reinterpret_cast<const short8v*>(QupH + off);
      *reinterpret_cast<short8v*>(&Bl[n][k8s]) = *reinterpret_cast<const short8v*>(QupL + off);
    }
    __syncthreads();
    short8v ah[2], al_[2], bh[2], bl_[2];
#pragma unroll
    for (int m = 0; m < 2; ++m) {
      int r = wr * 32 + m * 16 + l15;
      ah[m] = *reinterpret_cast<const short8v*>(&Ah[r][k8]);
      al_[m] = *reinterpret_cast<const short8v*>(&Al[r][k8]);
    }
#pragma unroll
    for (int n = 0; n < 2; ++n) {
      int r = wc * 32 + n * 16 + l15;
      bh[n] = *reinterpret_cast<const short8v*>(&Bh[r][k8]);
      bl_[n] = *reinterpret_cast<const short8v*>(&Bl[r][k8]);
    }
#pragma unroll
    for (int m = 0; m < 2; ++m)
#pragma unroll
      for (int n = 0; n < 2; ++n) {
        acc[m][n] = __builtin_amdgcn_mfma_f32_16x16x32_bf16(ah[m], bh[n], acc[m][n], 0, 0, 0);
        acc[m][n] = __builtin_amdgcn_mfma_f32_16x16x32_bf16(ah[m], bl_[n], acc[m][n], 0, 0, 0);
        acc[m][n] = __builtin_amdgcn_mfma_f32_16x16x32_bf16(al_[m], bh[n], acc[m][n], 0, 0, 0);
      }
  }
#pragma unroll
  for (int n = 0; n < 2; ++n) {
    int gcol = bn * 64 + wc * 32 + n * 16 + l15;
#pragma unroll
    for (int m = 0; m < 2; ++m) {
      int grow0 = bm * 64 + wr * 32 + m * 16 + ((lane >> 4) << 2);
#pragma unroll
      for (int j = 0; j < 4; ++j) {
        float fv = acc[m][n][j];
        short hh = f2bf(fv);
        MTh[(size_t)(grow0 + j) * DIM + gcol] = hh;
        MTl[(size_t)(grow0 + j) * DIM + gcol] = f2bf(fv - bf2f(hh));
      }
    }
  }
}

// ---------------------------------------------------------------------------
// out[4096,1024] = x @ M + bias. Pure bf16-load GEMM (proven R14).
__global__ __launch_bounds__(256) void gemm_mfma_k(const short* __restrict__ xH,
                                                   const short* __restrict__ xL,
                                                   const short* __restrict__ Bthi,
                                                   const short* __restrict__ Btlo,
                                                   const float* __restrict__ bias,
                                                   float* __restrict__ out) {
  __shared__ short Ah[128][36], Al[128][36], Bh[64][36], Bl[64][36];
  const int tid = threadIdx.x;
  const int bn = blockIdx.x;  // 0..15
  const int bm = blockIdx.y;  // 0..31
  const int wid = tid >> 6, wr = wid >> 1, wc = wid & 1;
  const int lane = tid & 63, l15 = lane & 15, k8 = (lane >> 4) << 3;
  f32x4 acc[4][2] = {};

  for (int kb = 0; kb < DIM; kb += 32) {
    __syncthreads();
#pragma unroll
    for (int ii = 0; ii < 2; ++ii) {
      int flat = tid + ii * 256;
      int r = flat >> 2, k8s = (flat & 3) << 3;
      size_t off = (size_t)(bm * 128 + r) * DIM + kb + k8s;
      *reinterpret_cast<short8v*>(&Ah[r][k8s]) = *reinterpret_cast<const short8v*>(xH + off);
      *reinterpret_cast<short8v*>(&Al[r][k8s]) = *reinterpret_cast<const short8v*>(xL + off);
    }
    {
      int n = tid >> 2, k8s = (tid & 3) << 3;
      size_t off = (size_t)(bn * 64 + n) * DIM + kb + k8s;
      *reinterpret_cast<short8v*>(&Bh[n][k8s]) = *reinterpret_cast<const short8v*>(Bthi + off);
      *reinterpret_cast<short8v*>(&Bl[n][k8s]) = *reinterpret_cast<const short8v*>(Btlo + off);
    }
    __syncthreads();

    short8v ah[4], al_[4], bh[2], bl_[2];
#pragma unroll
    for (int m = 0; m < 4; ++m) {
      int r = wr * 64 + m * 16 + l15;
      ah[m] = *reinterpret_cast<const short8v*>(&Ah[r][k8]);
      al_[m] = *reinterpret_cast<const short8v*>(&Al[r][k8]);
    }
#pragma unroll
    for (int n = 0; n < 2; ++n) {
      int r = wc * 32 + n * 16 + l15;
      bh[n] = *reinterpret_cast<const short8v*>(&Bh[r][k8]);
      bl_[n] = *reinterpret_cast<const short8v*>(&Bl[r][k8]);
    }
#pragma unroll
    for (int m = 0; m < 4; ++m)
#pragma unroll
      for (int n = 0; n < 2; ++n) {
        acc[m][n] = __builtin_amdgcn_mfma_f32_16x16x32_bf16(ah[m], bh[n], acc[m][n], 0, 0, 0);
        acc[m][n] = __builtin_amdgcn_mfma_f32_16x16x32_bf16(ah[m], bl_[n], acc[m][n], 0, 0, 0);
        acc[m][n] = __builtin_amdgcn_mfma_f32_16x16x32_bf16(al_[m], bh[n], acc[m][n], 0, 0, 0);
      }
  }

#pragma unroll
  for (int n = 0; n < 2; ++n) {
    int gcol = bn * 64 + wc * 32 + n * 16 + l15;
    float bv = bias[gcol];
#pragma unroll
    for (int m = 0; m < 4; ++m) {
      int grow0 = bm * 128 + wr * 64 + m * 16 + ((lane >> 4) << 2);
#pragma unroll
      for (int j = 0; j < 4; ++j)
        out[(size_t)(grow0 + j) * DIM + gcol] = acc[m][n][j] + bv;
    }
  }
}

// ---------------------------------------------------------------------------
extern "C" void kernel_launch(void* const* d_in, const int* in_sizes, int n_in,
                              void* d_out, int out_size, void* d_ws, size_t ws_size,
                              hipStream_t stream) {
  const float* x    = (const float*)d_in[0];
  const float* U    = (const float*)d_in[1];
  const float* V    = (const float*)d_in[2];
  const float* p    = (const float*)d_in[3];
  const float* bias = (const float*)d_in[4];
  float* out = (float*)d_out;

  float* F = (float*)d_ws;
  short* AuH  = (short*)F;
  short* AuL  = AuH + 1048576;
  short* AvH  = AuL + 1048576;
  short* AvL  = AvH + 1048576;
  short* QupH = AuH;                  // overlay after gram
  short* QupL = AuL;
  float* Qvt  = F + 1048576;          // overlays AvH/AvL
  float* Gu   = F + 2097152;
  float* Gv   = F + 3145728;
  float* Ptu  = Gu;                   // overlay after tree
  float* Ptv  = Gv;
  short* xH   = (short*)(F + 2097152);  // overlays Ptu/Ptv after ngemm
  float* Tu   = F + 4194304;
  float* Tv   = F + 5242880;
  short* MTh  = (short*)Tu;           // overlay after pgemm
  short* MTl  = MTh + 1048576;
  short* TtuH = (short*)(F + 6291456);
  short* TtuL = TtuH + 1048576;
  short* TtvH = TtuL + 1048576;
  short* TtvL = TtvH + 1048576;
  short* xL   = (short*)(F + 6291456);  // overlays Tt after tree
  short* AuTh = (short*)(F + 8388608);
  short* AuTl = AuTh + 1048576;
  short* AvTh = AuTl + 1048576;
  short* AvTl = AvTh + 1048576;
  short* TmpTh = (short*)(F + 10485760);
  short* TmpTl = TmpTh + 524288;
  float* tinu = F + 11010048;
  float* tinv = tinu + DIM;
  float* sg   = tinv + DIM;

  prep_k<<<512, 256, 0, stream>>>(U, V, p, tinu, tinv, sg);
  asplit_k<<<1024, 256, 0, stream>>>(U, V, AuH, AuL, AvH, AvL);
  tsplUV_k<<<dim3(16, 16, 2), 256, 0, stream>>>(U, V, AuTh, AuTl, AvTh, AvTl);
  gram_k<<<dim3(16, 16, 2), 256, 0, stream>>>(U, V, AuH, AuL, AvH, AvL, Gu, Gv);
  hipMemsetAsync(Tu, 0, (size_t)4194304 * sizeof(float), stream);  // Tu|Tv|Tt
  tdiag64_k<<<32, 256, 0, stream>>>(Gu, Gv, tinu, tinv, Tu, Tv,
                                    TtuH, TtuL, TtvH, TtvL);
  tcomb64_k<<<16, 256, 0, stream>>>(Gu, Gv, Tu, Tv, TtuH, TtuL, TtvH, TtvL);
  tcombgg_k<<<dim3(1, 1, 8), 256, 0, stream>>>(Gu, Gv, Tu, Tv, TtuH, TtuL, TtvH, TtvL, TmpTh, TmpTl, 128, 4, 1);
  tcombgg_k<<<dim3(1, 1, 8), 256, 0, stream>>>(Gu, Gv, Tu, Tv, TtuH, TtuL, TtvH, TtvL, TmpTh, TmpTl, 128, 4, 2);
  tcombgg_k<<<dim3(2, 2, 4), 256, 0, stream>>>(Gu, Gv, Tu, Tv, TtuH, TtuL, TtvH, TtvL, TmpTh, TmpTl, 256, 2, 1);
  tcombgg_k<<<dim3(2, 2, 4), 256, 0, stream>>>(Gu, Gv, Tu, Tv, TtuH, TtuL, TtvH, TtvL, TmpTh, TmpTl, 256, 2, 2);
  tcombgg_k<<<dim3(4, 4, 2), 256, 0, stream>>>(Gu, Gv, Tu, Tv, TtuH, TtuL, TtvH, TtvL, TmpTh, TmpTl, 512, 1, 1);
  tcombgg_k<<<dim3(4, 4, 2), 256, 0, stream>>>(Gu, Gv, Tu, Tv, TtuH, TtuL, TtvH, TtvL, TmpTh, TmpTl, 512, 1, 2);
  pgemm_k<<<dim3(16, 16, 2), 256, 0, stream>>>(Tu, Tv, AuTh, AuTl, AvTh, AvTl, Ptu, Ptv);
  ngemm_k<<<dim3(16, 16, 2), 256, 0, stream>>>(Ptu, Ptv, AuTh, AuTl, AvTh, AvTl, sg, QupH, QupL, Qvt);
  xsplit_k<<<2048, 256, 0, stream>>>(x, xH, xL);
  mgemm2_k<<<dim3(16, 16), 256, 0, stream>>>(Qvt, QupH, QupL, MTh, MTl);
  gemm_mfma_k<<<dim3(16, 32), 256, 0, stream>>>(xH, xL, MTh, MTl, bias, out);
}

// Round 16
// 319.583 us; speedup vs baseline: 2.3330x; 1.0191x over previous
//
#include <hip/hip_runtime.h>

#define DIM 1024
#define BATCH 4096

typedef __attribute__((ext_vector_type(8))) short short8v;
typedef __attribute__((ext_vector_type(4))) short short4v;
typedef __attribute__((ext_vector_type(4))) float f32x4;

// ---------------------------------------------------------------------------
__device__ __forceinline__ float dpp_reduce_bcast(float x) {
  int v = __builtin_bit_cast(int, x);
#define DPP_STEP(ctrl)                                                        \
  {                                                                           \
    int s = __builtin_amdgcn_update_dpp(0, v, ctrl, 0xf, 0xf, true);          \
    v = __builtin_bit_cast(                                                   \
        int, __builtin_bit_cast(float, v) + __builtin_bit_cast(float, s));    \
  }
  DPP_STEP(0x111) DPP_STEP(0x112) DPP_STEP(0x114) DPP_STEP(0x118)
  DPP_STEP(0x142) DPP_STEP(0x143)
#undef DPP_STEP
  return __builtin_bit_cast(float, __builtin_amdgcn_readlane(v, 63));
}

__device__ __forceinline__ short f2bf(float f) {
  unsigned u = __builtin_bit_cast(unsigned, f);
  u += 0x7FFFu + ((u >> 16) & 1u);
  return (short)(u >> 16);
}
__device__ __forceinline__ float bf2f(short h) {
  unsigned u = ((unsigned)(unsigned short)h) << 16;
  return __builtin_bit_cast(float, u);
}

// ---------------------------------------------------------------------------
// tau[m] = 2/||row m||^2 (U: row m; V: row 1023-m). Fused: sg sigmoid map.
__global__ __launch_bounds__(256) void prep_k(const float* __restrict__ U,
                                              const float* __restrict__ V,
                                              const float* __restrict__ p,
                                              float* __restrict__ tinu,
                                              float* __restrict__ tinv,
                                              float* __restrict__ sg) {
  int gi = blockIdx.x * 256 + threadIdx.x;
  if (gi < DIM) sg[gi] = 0.1f + 0.9f / (1.0f + __expf(-p[gi]));
  int gw = gi >> 6;
  int lane = threadIdx.x & 63;
  if (gw >= 2048) return;
  const float* src = (gw < 1024) ? (U + (size_t)gw * DIM)
                                 : (V + (size_t)(1023 - (gw - 1024)) * DIM);
  float s = 0.f;
#pragma unroll
  for (int q = 0; q < 4; ++q) {
    float4 v = *reinterpret_cast<const float4*>(src + q * 256 + lane * 4);
    s += v.x * v.x + v.y * v.y + v.z * v.z + v.w * v.w;
  }
  float tot = dpp_reduce_bcast(s);
  if (lane == 0) {
    float val = 2.0f / tot;
    if (gw < 1024) tinu[gw] = val; else tinv[gw - 1024] = val;
  }
}

// ---------------------------------------------------------------------------
// Natural-layout bf16 hi/lo splits of Au = U and Av = rows-of-V-reversed.
__global__ __launch_bounds__(256) void asplit_k(const float* __restrict__ U,
                                                const float* __restrict__ V,
                                                short* __restrict__ AuH,
                                                short* __restrict__ AuL,
                                                short* __restrict__ AvH,
                                                short* __restrict__ AvL) {
  int e = (blockIdx.x * 256 + threadIdx.x) * 8;
  int side = e >> 20;
  int idx = e & 1048575;
  int r = idx >> 10, c = idx & 1023;
  const float* src = side ? (V + (size_t)(1023 - r) * DIM + c)
                          : (U + (size_t)r * DIM + c);
  float4 a = *reinterpret_cast<const float4*>(src);
  float4 b = *reinterpret_cast<const float4*>(src + 4);
  float fv[8] = {a.x, a.y, a.z, a.w, b.x, b.y, b.z, b.w};
  short8v h, l;
#pragma unroll
  for (int j = 0; j < 8; ++j) {
    short hh = f2bf(fv[j]);
    h[j] = hh;
    l[j] = f2bf(fv[j] - bf2f(hh));
  }
  *reinterpret_cast<short8v*>((side ? AvH : AuH) + idx) = h;
  *reinterpret_cast<short8v*>((side ? AvL : AuL) + idx) = l;
}

// ---------------------------------------------------------------------------
// bf16 hi/lo split of x (natural layout).
__global__ __launch_bounds__(256) void xsplit_k(const float* __restrict__ x,
                                                short* __restrict__ xH,
                                                short* __restrict__ xL) {
  int idx = (blockIdx.x * 256 + threadIdx.x) * 8;
  float4 a = *reinterpret_cast<const float4*>(x + idx);
  float4 b = *reinterpret_cast<const float4*>(x + idx + 4);
  float fv[8] = {a.x, a.y, a.z, a.w, b.x, b.y, b.z, b.w};
  short8v h, l;
#pragma unroll
  for (int j = 0; j < 8; ++j) {
    short hh = f2bf(fv[j]);
    h[j] = hh;
    l[j] = f2bf(fv[j] - bf2f(hh));
  }
  *reinterpret_cast<short8v*>(xH + idx) = h;
  *reinterpret_cast<short8v*>(xL + idx) = l;
}

// ---------------------------------------------------------------------------
// Transpose-split of U / V-flipped: AuT[c][k] = split(U[k][c]),
// AvT[c][k] = split(V[1023-k][c]).
__global__ __launch_bounds__(256) void tsplUV_k(const float* __restrict__ U,
                                                const float* __restrict__ V,
                                                short* __restrict__ AuTh,
                                                short* __restrict__ AuTl,
                                                short* __restrict__ AvTh,
                                                short* __restrict__ AvTl) {
  __shared__ float tile[64][68];
  const int side = blockIdx.z;
  const int rb = blockIdx.y * 64, cb = blockIdx.x * 64;
  const int f = threadIdx.x;
  const float* S = side ? V : U;
#pragma unroll
  for (int ii = 0; ii < 4; ++ii) {
    int flat = f + ii * 256;
    int r = flat >> 4, c4 = (flat & 15) << 2;
    int rs = rb + r;
    if (side) rs = 1023 - rs;
    float4 v = *reinterpret_cast<const float4*>(S + (size_t)rs * DIM + cb + c4);
    tile[r][c4 + 0] = v.x; tile[r][c4 + 1] = v.y; tile[r][c4 + 2] = v.z; tile[r][c4 + 3] = v.w;
  }
  __syncthreads();
#pragma unroll
  for (int ii = 0; ii < 2; ++ii) {
    int flat = f + ii * 256;
    int cc = flat >> 3, r8 = (flat & 7) << 3;
    short8v vh, vl;
#pragma unroll
    for (int j = 0; j < 8; ++j) {
      float fv = tile[r8 + j][cc];
      short hh = f2bf(fv);
      vh[j] = hh;
      vl[j] = f2bf(fv - bf2f(hh));
    }
    size_t off = (size_t)(cb + cc) * DIM + rb + r8;
    *reinterpret_cast<short8v*>((side ? AvTh : AuTh) + off) = vh;
    *reinterpret_cast<short8v*>((side ? AvTl : AuTl) + off) = vl;
  }
}

// ---------------------------------------------------------------------------
// Gram: G[m][n] = Au_m . Au_n (3-term split-bf16). TRIANGULAR: only upper
// blocks (bm<=bn) are computed (lower never read downstream), and K starts
// at the first nonzero: side0 kb0=bn*64 (U triu), side1 kb0=(15-bm)*64
// (V rows reversed). Skipped terms are exact zeros -> bitwise identical.
__global__ __launch_bounds__(256) void gram_k(const float* __restrict__ U,
                                              const float* __restrict__ V,
                                              const short* __restrict__ AuH,
                                              const short* __restrict__ AuL,
                                              const short* __restrict__ AvH,
                                              const short* __restrict__ AvL,
                                              float* __restrict__ Gu,
                                              float* __restrict__ Gv) {
  __shared__ short Ah[64][36], Al[64][36], Bh[64][36], Bl[64][36];
  const int side = blockIdx.z;
  // triangular block mapping: bid in [0,136) -> (bm,bn), bm<=bn
  int bm = 0, rem = blockIdx.x;
  while (rem >= 16 - bm) { rem -= 16 - bm; ++bm; }
  const int bn = bm + rem;
  const int kb0 = (side ? (15 - bm) : bn) * 64;
  const float* A = side ? V : U;
  const short* BH = side ? AvH : AuH;
  const short* BL = side ? AvL : AuL;
  float* G = side ? Gv : Gu;
  const int tid = threadIdx.x;
  const int wid = tid >> 6, wr = wid >> 1, wc = wid & 1;
  const int lane = tid & 63, l15 = lane & 15, k8 = (lane >> 4) << 3;
  f32x4 acc[2][2] = {};

  for (int kb = kb0; kb < DIM; kb += 32) {
    __syncthreads();
#pragma unroll
    for (int ii = 0; ii < 2; ++ii) {
      int flat = tid + ii * 256;
      int r = flat >> 3, kq = (flat & 7) << 2;
      int rg = bm * 64 + r;
      int rs = side ? (1023 - rg) : rg;
      float4 v = *reinterpret_cast<const float4*>(A + (size_t)rs * DIM + kb + kq);
      short4v h, l;
      float fv[4] = {v.x, v.y, v.z, v.w};
#pragma unroll
      for (int j = 0; j < 4; ++j) {
        short hh = f2bf(fv[j]); h[j] = hh; l[j] = f2bf(fv[j] - bf2f(hh));
      }
      *reinterpret_cast<short4v*>(&Ah[r][kq]) = h;
      *reinterpret_cast<short4v*>(&Al[r][kq]) = l;
    }
    {
      int n = tid >> 2, k8s = (tid & 3) << 3;
      size_t off = (size_t)(bn * 64 + n) * DIM + kb + k8s;
      *reinterpret_cast<short8v*>(&Bh[n][k8s]) = *reinterpret_cast<const short8v*>(BH + off);
      *reinterpret_cast<short8v*>(&Bl[n][k8s]) = *reinterpret_cast<const short8v*>(BL + off);
    }
    __syncthreads();
    short8v ah[2], al_[2], bh[2], bl_[2];
#pragma unroll
    for (int m = 0; m < 2; ++m) {
      int r = wr * 32 + m * 16 + l15;
      ah[m] = *reinterpret_cast<const short8v*>(&Ah[r][k8]);
      al_[m] = *reinterpret_cast<const short8v*>(&Al[r][k8]);
    }
#pragma unroll
    for (int n = 0; n < 2; ++n) {
      int r = wc * 32 + n * 16 + l15;
      bh[n] = *reinterpret_cast<const short8v*>(&Bh[r][k8]);
      bl_[n] = *reinterpret_cast<const short8v*>(&Bl[r][k8]);
    }
#pragma unroll
    for (int m = 0; m < 2; ++m)
#pragma unroll
      for (int n = 0; n < 2; ++n) {
        acc[m][n] = __builtin_amdgcn_mfma_f32_16x16x32_bf16(ah[m], bh[n], acc[m][n], 0, 0, 0);
        acc[m][n] = __builtin_amdgcn_mfma_f32_16x16x32_bf16(ah[m], bl_[n], acc[m][n], 0, 0, 0);
        acc[m][n] = __builtin_amdgcn_mfma_f32_16x16x32_bf16(al_[m], bh[n], acc[m][n], 0, 0, 0);
      }
  }
#pragma unroll
  for (int n = 0; n < 2; ++n) {
    int gcol = bn * 64 + wc * 32 + n * 16 + l15;
#pragma unroll
    for (int m = 0; m < 2; ++m) {
      int grow0 = bm * 64 + wr * 32 + m * 16 + ((lane >> 4) << 2);
#pragma unroll
      for (int j = 0; j < 4; ++j)
        G[(size_t)(grow0 + j) * DIM + gcol] = acc[m][n][j];
    }
  }
}

// ---------------------------------------------------------------------------
// 64x64 diagonal T blocks via recursive in-LDS triangular inversion (proven).
__global__ __launch_bounds__(256) void tdiag64_k(const float* __restrict__ Gu,
                                                 const float* __restrict__ Gv,
                                                 const float* __restrict__ tinu,
                                                 const float* __restrict__ tinv,
                                                 float* __restrict__ Tu,
                                                 float* __restrict__ Tv,
                                                 short* __restrict__ TtuH,
                                                 short* __restrict__ TtuL,
                                                 short* __restrict__ TtvH,
                                                 short* __restrict__ TtvL) {
  __shared__ float B[64][65];
  __shared__ float T[64][65];
  __shared__ float Wb[1024];
  int z = blockIdx.x >> 4;
  int d = blockIdx.x & 15;
  const float* G = z ? Gv : Gu;
  const float* tau = z ? tinv : tinu;
  float* Tg = z ? Tv : Tu;
  short* TH = z ? TtvH : TtuH;
  short* TL = z ? TtvL : TtuL;
  int b0 = d * 64;
  int tid = threadIdx.x;

  for (int e = tid; e < 4096; e += 256) {
    int r = e >> 6, c = e & 63;
    float v;
    if (r < c) v = G[(size_t)(b0 + r) * DIM + b0 + c];
    else if (r == c) v = 1.0f / tau[b0 + r];
    else v = 0.f;
    B[r][c] = v;
    T[r][c] = 0.f;
  }
  __syncthreads();

  if (tid < 16) {
    int o = tid * 4;
    float X[4][4];
#pragma unroll
    for (int k = 0; k < 4; ++k) {
      X[k][k] = 1.0f / B[o + k][o + k];
#pragma unroll
      for (int i = 2; i >= 0; --i) {
        if (i < k) {
          float s = 0.f;
#pragma unroll
          for (int j = 0; j < 4; ++j)
            if (j > i && j <= k) s = fmaf(B[o + i][o + j], X[j][k], s);
          X[i][k] = -s / B[o + i][o + i];
        }
      }
    }
#pragma unroll
    for (int k = 0; k < 4; ++k)
#pragma unroll
      for (int i = 0; i < 4; ++i)
        if (i <= k) T[o + i][o + k] = X[i][k];
  }
  __syncthreads();

  for (int s = 4; s <= 32; s <<= 1) {
    int ss = s * s;
    int tot = (32 / s) * ss;
    for (int e = tid; e < tot; e += 256) {
      int p = e / ss;
      int rem = e - p * ss;
      int m = rem / s;
      int j = rem - m * s;
      int o = p * 2 * s;
      float acc = 0.f;
      for (int l = 0; l < s; ++l)
        acc = fmaf(B[o + m][o + s + l], T[o + s + l][o + s + j], acc);
      Wb[e] = acc;
    }
    __syncthreads();
    for (int e = tid; e < tot; e += 256) {
      int p = e / ss;
      int rem = e - p * ss;
      int i = rem / s;
      int j = rem - i * s;
      int o = p * 2 * s;
      float acc = 0.f;
      for (int m = 0; m < s; ++m)
        acc = fmaf(T[o + i][o + m], Wb[p * ss + m * s + j], acc);
      T[o + i][o + s + j] = -acc;
    }
    __syncthreads();
  }

  for (int e = tid; e < 1024; e += 256) {
    int r = e >> 4, c4 = (e & 15) << 2;
    float4 v;
    v.x = T[r][c4]; v.y = T[r][c4 + 1]; v.z = T[r][c4 + 2]; v.w = T[r][c4 + 3];
    *reinterpret_cast<float4*>(Tg + (size_t)(b0 + r) * DIM + b0 + c4) = v;
  }
  for (int e = tid; e < 512; e += 256) {
    int c = e >> 3, r8 = (e & 7) << 3;
    short8v h, l;
#pragma unroll
    for (int j = 0; j < 8; ++j) {
      float fv = T[r8 + j][c];
      short hh = f2bf(fv);
      h[j] = hh;
      l[j] = f2bf(fv - bf2f(hh));
    }
    size_t off = (size_t)(b0 + c) * DIM + b0 + r8;
    *reinterpret_cast<short8v*>(TH + off) = h;
    *reinterpret_cast<short8v*>(TL + off) = l;
  }
}

// ---------------------------------------------------------------------------
// Level s=64 combine, in-LDS; also writes bf16 transposed mirror of X.
__global__ __launch_bounds__(256) void tcomb64_k(const float* __restrict__ Gu,
                                                 const float* __restrict__ Gv,
                                                 float* __restrict__ Tu,
                                                 float* __restrict__ Tv,
                                                 short* __restrict__ TtuH,
                                                 short* __restrict__ TtuL,
                                                 short* __restrict__ TtvH,
                                                 short* __restrict__ TtvL) {
  __shared__ float TA[64][68], SS[64][68], TB[64][68], W[64][68];
  int zz = blockIdx.x;
  int side = zz >> 3, p = zz & 7;
  int a0 = p * 128;
  const float* G = side ? Gv : Gu;
  float* T = side ? Tv : Tu;
  short* TH = side ? TtvH : TtuH;
  short* TL = side ? TtvL : TtuL;
  int tid = threadIdx.x;
#pragma unroll
  for (int ii = 0; ii < 4; ++ii) {
    int flat = tid + ii * 256;
    int r = flat >> 4, c4 = (flat & 15) << 2;
    *reinterpret_cast<float4*>(&TA[r][c4]) =
        *reinterpret_cast<const float4*>(T + (size_t)(a0 + r) * DIM + a0 + c4);
    *reinterpret_cast<float4*>(&SS[r][c4]) =
        *reinterpret_cast<const float4*>(G + (size_t)(a0 + r) * DIM + a0 + 64 + c4);
    *reinterpret_cast<float4*>(&TB[r][c4]) =
        *reinterpret_cast<const float4*>(T + (size_t)(a0 + 64 + r) * DIM + a0 + 64 + c4);
  }
  __syncthreads();
  int tx = tid & 15, ty = tid >> 4;
  float acc[4][4] = {};
  for (int k = 0; k < 64; ++k) {
    float a[4], b[4];
#pragma unroll
    for (int m = 0; m < 4; ++m) a[m] = SS[ty * 4 + m][k];
#pragma unroll
    for (int n = 0; n < 4; ++n) b[n] = TB[k][tx * 4 + n];
#pragma unroll
    for (int m = 0; m < 4; ++m)
#pragma unroll
      for (int n = 0; n < 4; ++n) acc[m][n] = fmaf(a[m], b[n], acc[m][n]);
  }
#pragma unroll
  for (int m = 0; m < 4; ++m)
#pragma unroll
    for (int n = 0; n < 4; ++n) W[ty * 4 + m][tx * 4 + n] = acc[m][n];
  __syncthreads();
  float acc2[4][4] = {};
  for (int k = 0; k < 64; ++k) {
    float a[4], b[4];
#pragma unroll
    for (int m = 0; m < 4; ++m) a[m] = TA[ty * 4 + m][k];
#pragma unroll
    for (int n = 0; n < 4; ++n) b[n] = W[k][tx * 4 + n];
#pragma unroll
    for (int m = 0; m < 4; ++m)
#pragma unroll
      for (int n = 0; n < 4; ++n) acc2[m][n] = fmaf(a[m], b[n], acc2[m][n]);
  }
#pragma unroll
  for (int m = 0; m < 4; ++m)
#pragma unroll
    for (int n = 0; n < 4; ++n)
      T[(size_t)(a0 + ty * 4 + m) * DIM + a0 + 64 + tx * 4 + n] = -acc2[m][n];
#pragma unroll
  for (int n = 0; n < 4; ++n) {
    short4v h, l;
#pragma unroll
    for (int j = 0; j < 4; ++j) {
      float fv = -acc2[j][n];
      short hh = f2bf(fv);
      h[j] = hh;
      l[j] = f2bf(fv - bf2f(hh));
    }
    size_t off = (size_t)(a0 + 64 + tx * 4 + n) * DIM + a0 + ty * 4;
    *reinterpret_cast<short4v*>(TH + off) = h;
    *reinterpret_cast<short4v*>(TL + off) = l;
  }
}

// ---------------------------------------------------------------------------
// Tree levels s>=128 (unchanged from R15).
__global__ __launch_bounds__(256) void tcombgg_k(const float* __restrict__ Gu,
                                                 const float* __restrict__ Gv,
                                                 float* __restrict__ Tu,
                                                 float* __restrict__ Tv,
                                                 short* __restrict__ TtuH,
                                                 short* __restrict__ TtuL,
                                                 short* __restrict__ TtvH,
                                                 short* __restrict__ TtvL,
                                                 short* __restrict__ TmpTh,
                                                 short* __restrict__ TmpTl,
                                                 int s, int npair, int stage) {
  __shared__ short Ah[128][44], Al[128][44], Bh[128][44], Bl[128][44];
  const int z = blockIdx.z;
  const int side = z / npair, p = z % npair;
  const int a0 = p * 2 * s;
  const float* Ab;
  const short* BH; const short* BL;
  int ldb;
  if (stage == 1) {
    Ab = (side ? Gv : Gu) + (size_t)a0 * DIM + (a0 + s);
    BH = (side ? TtvH : TtuH) + (size_t)(a0 + s) * DIM + (a0 + s);
    BL = (side ? TtvL : TtuL) + (size_t)(a0 + s) * DIM + (a0 + s);
    ldb = DIM;
  } else {
    Ab = (side ? Tv : Tu) + (size_t)a0 * DIM + a0;
    BH = TmpTh + (size_t)z * s * s;
    BL = TmpTl + (size_t)z * s * s;
    ldb = s;
  }
  const int tid = threadIdx.x;
  const int bn = blockIdx.x, bm = blockIdx.y;
  const int wid = tid >> 6, wr = wid >> 1, wc = wid & 1;
  const int lane = tid & 63, l15 = lane & 15, k8 = (lane >> 4) << 3;
  f32x4 acc[4][4] = {};

  for (int kb = 0; kb < s; kb += 32) {
    __syncthreads();
#pragma unroll
    for (int ii = 0; ii < 4; ++ii) {
      int flat = tid + ii * 256;
      int r = flat >> 3, kq = (flat & 7) << 2;
      float4 v = *reinterpret_cast<const float4*>(Ab + (size_t)(bm * 128 + r) * DIM + kb + kq);
      short4v h, l;
      float fv[4] = {v.x, v.y, v.z, v.w};
#pragma unroll
      for (int j = 0; j < 4; ++j) {
        short hh = f2bf(fv[j]); h[j] = hh; l[j] = f2bf(fv[j] - bf2f(hh));
      }
      *reinterpret_cast<short4v*>(&Ah[r][kq]) = h;
      *reinterpret_cast<short4v*>(&Al[r][kq]) = l;
    }
#pragma unroll
    for (int ii = 0; ii < 2; ++ii) {
      int flat = tid + ii * 256;
      int n = flat >> 2, kk8 = (flat & 3) << 3;
      size_t off = (size_t)(bn * 128 + n) * ldb + kb + kk8;
      *reinterpret_cast<short8v*>(&Bh[n][kk8]) = *reinterpret_cast<const short8v*>(BH + off);
      *reinterpret_cast<short8v*>(&Bl[n][kk8]) = *reinterpret_cast<const short8v*>(BL + off);
    }
    __syncthreads();
    short8v ah[4], al_[4], bh[4], bl_[4];
#pragma unroll
    for (int m = 0; m < 4; ++m) {
      int r = wr * 64 + m * 16 + l15;
      ah[m] = *reinterpret_cast<const short8v*>(&Ah[r][k8]);
      al_[m] = *reinterpret_cast<const short8v*>(&Al[r][k8]);
    }
#pragma unroll
    for (int n = 0; n < 4; ++n) {
      int r = wc * 64 + n * 16 + l15;
      bh[n] = *reinterpret_cast<const short8v*>(&Bh[r][k8]);
      bl_[n] = *reinterpret_cast<const short8v*>(&Bl[r][k8]);
    }
#pragma unroll
    for (int m = 0; m < 4; ++m)
#pragma unroll
      for (int n = 0; n < 4; ++n) {
        acc[m][n] = __builtin_amdgcn_mfma_f32_16x16x32_bf16(ah[m], bh[n], acc[m][n], 0, 0, 0);
        acc[m][n] = __builtin_amdgcn_mfma_f32_16x16x32_bf16(ah[m], bl_[n], acc[m][n], 0, 0, 0);
        acc[m][n] = __builtin_amdgcn_mfma_f32_16x16x32_bf16(al_[m], bh[n], acc[m][n], 0, 0, 0);
      }
  }
  if (stage == 1) {
    size_t base = (size_t)z * s * s;
#pragma unroll
    for (int n = 0; n < 4; ++n) {
      int gcol = bn * 128 + wc * 64 + n * 16 + l15;
#pragma unroll
      for (int m = 0; m < 4; ++m) {
        int gk0 = bm * 128 + wr * 64 + m * 16 + ((lane >> 4) << 2);
        short4v h, l;
#pragma unroll
        for (int j = 0; j < 4; ++j) {
          float fv = acc[m][n][j];
          short hh = f2bf(fv);
          h[j] = hh;
          l[j] = f2bf(fv - bf2f(hh));
        }
        *reinterpret_cast<short4v*>(TmpTh + base + (size_t)gcol * s + gk0) = h;
        *reinterpret_cast<short4v*>(TmpTl + base + (size_t)gcol * s + gk0) = l;
      }
    }
  } else {
    float* T = side ? Tv : Tu;
    float* Cb = T + (size_t)a0 * DIM + (a0 + s);
    short* TH = side ? TtvH : TtuH;
    short* TL = side ? TtvL : TtuL;
#pragma unroll
    for (int n = 0; n < 4; ++n) {
      int gcol = bn * 128 + wc * 64 + n * 16 + l15;
#pragma unroll
      for (int m = 0; m < 4; ++m) {
        int grow0 = bm * 128 + wr * 64 + m * 16 + ((lane >> 4) << 2);
        short4v h, l;
#pragma unroll
        for (int j = 0; j < 4; ++j) {
          float fv = -acc[m][n][j];
          Cb[(size_t)(grow0 + j) * DIM + gcol] = fv;
          short hh = f2bf(fv);
          h[j] = hh;
          l[j] = f2bf(fv - bf2f(hh));
        }
        size_t off = (size_t)(a0 + s + gcol) * DIM + a0 + grow0;
        *reinterpret_cast<short4v*>(TH + off) = h;
        *reinterpret_cast<short4v*>(TL + off) = l;
      }
    }
  }
}

// ---------------------------------------------------------------------------
// P = T @ Au ; A = T f32 natural, Bt = AuT/AvT bf16 [c][k]. Out Pt = P^T f32.
// TRIANGULAR K-trim: side0 kb in [bm*64,(bn+1)*64), tiles bn<bm all-zero and
// never read -> early exit; side1 kb in [max(bm,15-bn)*64, 1024).
__global__ __launch_bounds__(256) void pgemm_k(const float* __restrict__ Tu,
                                               const float* __restrict__ Tv,
                                               const short* __restrict__ AuTh,
                                               const short* __restrict__ AuTl,
                                               const short* __restrict__ AvTh,
                                               const short* __restrict__ AvTl,
                                               float* __restrict__ Ptu,
                                               float* __restrict__ Ptv) {
  __shared__ short Ah[64][36], Al[64][36], Bh[64][36], Bl[64][36];
  const int side = blockIdx.z;
  const int bn = blockIdx.x, bm = blockIdx.y;
  int kb0, kb1;
  if (side == 0) {
    if (bn < bm) return;               // P[m][c]=0 for c<m; never read
    kb0 = bm * 64; kb1 = (bn + 1) * 64;
  } else {
    kb0 = (bm > 15 - bn ? bm : 15 - bn) * 64; kb1 = DIM;
  }
  const float* A = side ? Tv : Tu;
  const short* BH = side ? AvTh : AuTh;
  const short* BL = side ? AvTl : AuTl;
  float* Out = side ? Ptv : Ptu;
  const int tid = threadIdx.x;
  const int wid = tid >> 6, wr = wid >> 1, wc = wid & 1;
  const int lane = tid & 63, l15 = lane & 15, k8 = (lane >> 4) << 3;
  f32x4 acc[2][2] = {};

  for (int kb = kb0; kb < kb1; kb += 32) {
    __syncthreads();
#pragma unroll
    for (int ii = 0; ii < 2; ++ii) {
      int flat = tid + ii * 256;
      int r = flat >> 3, kq = (flat & 7) << 2;
      float4 v = *reinterpret_cast<const float4*>(A + (size_t)(bm * 64 + r) * DIM + kb + kq);
      short4v h, l;
      float fv[4] = {v.x, v.y, v.z, v.w};
#pragma unroll
      for (int j = 0; j < 4; ++j) {
        short hh = f2bf(fv[j]); h[j] = hh; l[j] = f2bf(fv[j] - bf2f(hh));
      }
      *reinterpret_cast<short4v*>(&Ah[r][kq]) = h;
      *reinterpret_cast<short4v*>(&Al[r][kq]) = l;
    }
    {
      int n = tid >> 2, k8s = (tid & 3) << 3;
      size_t off = (size_t)(bn * 64 + n) * DIM + kb + k8s;
      *reinterpret_cast<short8v*>(&Bh[n][k8s]) = *reinterpret_cast<const short8v*>(BH + off);
      *reinterpret_cast<short8v*>(&Bl[n][k8s]) = *reinterpret_cast<const short8v*>(BL + off);
    }
    __syncthreads();
    short8v ah[2], al_[2], bh[2], bl_[2];
#pragma unroll
    for (int m = 0; m < 2; ++m) {
      int r = wr * 32 + m * 16 + l15;
      ah[m] = *reinterpret_cast<const short8v*>(&Ah[r][k8]);
      al_[m] = *reinterpret_cast<const short8v*>(&Al[r][k8]);
    }
#pragma unroll
    for (int n = 0; n < 2; ++n) {
      int r = wc * 32 + n * 16 + l15;
      bh[n] = *reinterpret_cast<const short8v*>(&Bh[r][k8]);
      bl_[n] = *reinterpret_cast<const short8v*>(&Bl[r][k8]);
    }
#pragma unroll
    for (int m = 0; m < 2; ++m)
#pragma unroll
      for (int n = 0; n < 2; ++n) {
        acc[m][n] = __builtin_amdgcn_mfma_f32_16x16x32_bf16(ah[m], bh[n], acc[m][n], 0, 0, 0);
        acc[m][n] = __builtin_amdgcn_mfma_f32_16x16x32_bf16(ah[m], bl_[n], acc[m][n], 0, 0, 0);
        acc[m][n] = __builtin_amdgcn_mfma_f32_16x16x32_bf16(al_[m], bh[n], acc[m][n], 0, 0, 0);
      }
  }
#pragma unroll
  for (int n = 0; n < 2; ++n) {
    int gcol = bn * 64 + wc * 32 + n * 16 + l15;
#pragma unroll
    for (int m = 0; m < 2; ++m) {
      int grow0 = bm * 64 + wr * 32 + m * 16 + ((lane >> 4) << 2);
      float4 o;
      o.x = acc[m][n][0]; o.y = acc[m][n][1]; o.z = acc[m][n][2]; o.w = acc[m][n][3];
      *reinterpret_cast<float4*>(Out + (size_t)gcol * DIM + grow0) = o;
    }
  }
}

// ---------------------------------------------------------------------------
// Nt = Pt @ Au: A = Pt f32, Bt = AuT/AvT bf16. TRIANGULAR K-trim:
// side0 kb < (min(bm,bn)+1)*64 (Pt k<=m, Au k<=n); side1 kb >= (15-bn)*64.
// side0 out: Qu'[gcol][row] = (del - Nt)*sg[row] bf16; side1 Qvt f32.
__global__ __launch_bounds__(256) void ngemm_k(const float* __restrict__ Ptu,
                                               const float* __restrict__ Ptv,
                                               const short* __restrict__ AuTh,
                                               const short* __restrict__ AuTl,
                                               const short* __restrict__ AvTh,
                                               const short* __restrict__ AvTl,
                                               const float* __restrict__ sg,
                                               short* __restrict__ QupH,
                                               short* __restrict__ QupL,
                                               float* __restrict__ Qvt) {
  __shared__ short Ah[64][36], Al[64][36], Bh[64][36], Bl[64][36];
  const int side = blockIdx.z;
  const int bn = blockIdx.x, bm = blockIdx.y;
  int kb0, kb1;
  if (side == 0) {
    kb0 = 0;
    kb1 = ((bm < bn ? bm : bn) + 1) * 64;
  } else {
    kb0 = (15 - bn) * 64; kb1 = DIM;
  }
  const float* A = side ? Ptv : Ptu;
  const short* BH = side ? AvTh : AuTh;
  const short* BL = side ? AvTl : AuTl;
  const int tid = threadIdx.x;
  const int wid = tid >> 6, wr = wid >> 1, wc = wid & 1;
  const int lane = tid & 63, l15 = lane & 15, k8 = (lane >> 4) << 3;
  f32x4 acc[2][2] = {};

  for (int kb = kb0; kb < kb1; kb += 32) {
    __syncthreads();
#pragma unroll
    for (int ii = 0; ii < 2; ++ii) {
      int flat = tid + ii * 256;
      int r = flat >> 3, kq = (flat & 7) << 2;
      float4 v = *reinterpret_cast<const float4*>(A + (size_t)(bm * 64 + r) * DIM + kb + kq);
      short4v h, l;
      float fv[4] = {v.x, v.y, v.z, v.w};
#pragma unroll
      for (int j = 0; j < 4; ++j) {
        short hh = f2bf(fv[j]); h[j] = hh; l[j] = f2bf(fv[j] - bf2f(hh));
      }
      *reinterpret_cast<short4v*>(&Ah[r][kq]) = h;
      *reinterpret_cast<short4v*>(&Al[r][kq]) = l;
    }
    {
      int n = tid >> 2, k8s = (tid & 3) << 3;
      size_t off = (size_t)(bn * 64 + n) * DIM + kb + k8s;
      *reinterpret_cast<short8v*>(&Bh[n][k8s]) = *reinterpret_cast<const short8v*>(BH + off);
      *reinterpret_cast<short8v*>(&Bl[n][k8s]) = *reinterpret_cast<const short8v*>(BL + off);
    }
    __syncthreads();
    short8v ah[2], al_[2], bh[2], bl_[2];
#pragma unroll
    for (int m = 0; m < 2; ++m) {
      int r = wr * 32 + m * 16 + l15;
      ah[m] = *reinterpret_cast<const short8v*>(&Ah[r][k8]);
      al_[m] = *reinterpret_cast<const short8v*>(&Al[r][k8]);
    }
#pragma unroll
    for (int n = 0; n < 2; ++n) {
      int r = wc * 32 + n * 16 + l15;
      bh[n] = *reinterpret_cast<const short8v*>(&Bh[r][k8]);
      bl_[n] = *reinterpret_cast<const short8v*>(&Bl[r][k8]);
    }
#pragma unroll
    for (int m = 0; m < 2; ++m)
#pragma unroll
      for (int n = 0; n < 2; ++n) {
        acc[m][n] = __builtin_amdgcn_mfma_f32_16x16x32_bf16(ah[m], bh[n], acc[m][n], 0, 0, 0);
        acc[m][n] = __builtin_amdgcn_mfma_f32_16x16x32_bf16(ah[m], bl_[n], acc[m][n], 0, 0, 0);
        acc[m][n] = __builtin_amdgcn_mfma_f32_16x16x32_bf16(al_[m], bh[n], acc[m][n], 0, 0, 0);
      }
  }
#pragma unroll
  for (int n = 0; n < 2; ++n) {
    int gcol = bn * 64 + wc * 32 + n * 16 + l15;
#pragma unroll
    for (int m = 0; m < 2; ++m) {
      int grow0 = bm * 64 + wr * 32 + m * 16 + ((lane >> 4) << 2);
      if (side == 0) {
        short4v h, l;
#pragma unroll
        for (int j = 0; j < 4; ++j) {
          int row = grow0 + j;
          float del = (row == gcol) ? 1.0f : 0.0f;
          float q = (del - acc[m][n][j]) * sg[row];
          short hh = f2bf(q);
          h[j] = hh;
          l[j] = f2bf(q - bf2f(hh));
        }
        *reinterpret_cast<short4v*>(QupH + (size_t)gcol * DIM + grow0) = h;
        *reinterpret_cast<short4v*>(QupL + (size_t)gcol * DIM + grow0) = l;
      } else {
#pragma unroll
        for (int j = 0; j < 4; ++j) {
          int row = grow0 + j;
          float del = (row == gcol) ? 1.0f : 0.0f;
          Qvt[(size_t)row * DIM + gcol] = del - acc[m][n][j];
        }
      }
    }
  }
}

// ---------------------------------------------------------------------------
// MT = M^T = Qv^T @ Qu'^T : A = Qvt f32, Bt = Qu' bf16 (unchanged).
__global__ __launch_bounds__(256) void mgemm2_k(const float* __restrict__ Qvt,
                                                const short* __restrict__ QupH,
                                                const short* __restrict__ QupL,
                                                short* __restrict__ MTh,
                                                short* __restrict__ MTl) {
  __shared__ short Ah[64][36], Al[64][36], Bh[64][36], Bl[64][36];
  const int tid = threadIdx.x;
  const int bn = blockIdx.x, bm = blockIdx.y;
  const int wid = tid >> 6, wr = wid >> 1, wc = wid & 1;
  const int lane = tid & 63, l15 = lane & 15, k8 = (lane >> 4) << 3;
  f32x4 acc[2][2] = {};

  for (int kb = 0; kb < DIM; kb += 32) {
    __syncthreads();
#pragma unroll
    for (int ii = 0; ii < 2; ++ii) {
      int flat = tid + ii * 256;
      int r = flat >> 3, kq = (flat & 7) << 2;
      float4 v = *reinterpret_cast<const float4*>(Qvt + (size_t)(bm * 64 + r) * DIM + kb + kq);
      short4v h, l;
      float fv[4] = {v.x, v.y, v.z, v.w};
#pragma unroll
      for (int j = 0; j < 4; ++j) {
        short hh = f2bf(fv[j]); h[j] = hh; l[j] = f2bf(fv[j] - bf2f(hh));
      }
      *reinterpret_cast<short4v*>(&Ah[r][kq]) = h;
      *reinterpret_cast<short4v*>(&Al[r][kq]) = l;
    }
    {
      int n = tid >> 2, k8s = (tid & 3) << 3;
      size_t off = (size_t)(bn * 64 + n) * DIM + kb + k8s;
      *reinterpret_cast<short8v*>(&Bh[n][k8s]) = *reinterpret_cast<const short8v*>(QupH + off);
      *reinterpret_cast<short8v*>(&Bl[n][k8s]) = *reinterpret_cast<const short8v*>(QupL + off);
    }
    __syncthreads();
    short8v ah[2], al_[2], bh[2], bl_[2];
#pragma unroll
    for (int m = 0; m < 2; ++m) {
      int r = wr * 32 + m * 16 + l15;
      ah[m] = *reinterpret_cast<const short8v*>(&Ah[r][k8]);
      al_[m] = *reinterpret_cast<const short8v*>(&Al[r][k8]);
    }
#pragma unroll
    for (int n = 0; n < 2; ++n) {
      int r = wc * 32 + n * 16 + l15;
      bh[n] = *reinterpret_cast<const short8v*>(&Bh[r][k8]);
      bl_[n] = *reinterpret_cast<const short8v*>(&Bl[r][k8]);
    }
#pragma unroll
    for (int m = 0; m < 2; ++m)
#pragma unroll
      for (int n = 0; n < 2; ++n) {
        acc[m][n] = __builtin_amdgcn_mfma_f32_16x16x32_bf16(ah[m], bh[n], acc[m][n], 0, 0, 0);
        acc[m][n] = __builtin_amdgcn_mfma_f32_16x16x32_bf16(ah[m], bl_[n], acc[m][n], 0, 0, 0);
        acc[m][n] = __builtin_amdgcn_mfma_f32_16x16x32_bf16(al_[m], bh[n], acc[m][n], 0, 0, 0);
      }
  }
#pragma unroll
  for (int n = 0; n < 2; ++n) {
    int gcol = bn * 64 + wc * 32 + n * 16 + l15;
#pragma unroll
    for (int m = 0; m < 2; ++m) {
      int grow0 = bm * 64 + wr * 32 + m * 16 + ((lane >> 4) << 2);
#pragma unroll
      for (int j = 0; j < 4; ++j) {
        float fv = acc[m][n][j];
        short hh = f2bf(fv);
        MTh[(size_t)(grow0 + j) * DIM + gcol] = hh;
        MTl[(size_t)(grow0 + j) * DIM + gcol] = f2bf(fv - bf2f(hh));
      }
    }
  }
}

// ---------------------------------------------------------------------------
// out[4096,1024] = x @ M + bias. 64x64 tile -> 1024 blocks = 4/CU, with
// bijective XCD-chunk swizzle (each XCD gets 128 contiguous tiles: its
// A-working-set ~2MB + B 4MB mostly L2-resident).
__global__ __launch_bounds__(256) void gemm_mfma_k(const short* __restrict__ xH,
                                                   const short* __restrict__ xL,
                                                   const short* __restrict__ Bthi,
                                                   const short* __restrict__ Btlo,
                                                   const float* __restrict__ bias,
                                                   float* __restrict__ out) {
  __shared__ short Ah[64][36], Al[64][36], Bh[64][36], Bl[64][36];
  const int tid = threadIdx.x;
  int lin = (blockIdx.x & 7) * 128 + (blockIdx.x >> 3);  // XCD chunk swizzle
  const int bm = lin >> 4;   // 0..63
  const int bn = lin & 15;   // 0..15
  const int wid = tid >> 6, wr = wid >> 1, wc = wid & 1;
  const int lane = tid & 63, l15 = lane & 15, k8 = (lane >> 4) << 3;
  f32x4 acc[2][2] = {};

  for (int kb = 0; kb < DIM; kb += 32) {
    __syncthreads();
    {
      int r = tid >> 2, k8s = (tid & 3) << 3;
      size_t off = (size_t)(bm * 64 + r) * DIM + kb + k8s;
      *reinterpret_cast<short8v*>(&Ah[r][k8s]) = *reinterpret_cast<const short8v*>(xH + off);
      *reinterpret_cast<short8v*>(&Al[r][k8s]) = *reinterpret_cast<const short8v*>(xL + off);
    }
    {
      int n = tid >> 2, k8s = (tid & 3) << 3;
      size_t off = (size_t)(bn * 64 + n) * DIM + kb + k8s;
      *reinterpret_cast<short8v*>(&Bh[n][k8s]) = *reinterpret_cast<const short8v*>(Bthi + off);
      *reinterpret_cast<short8v*>(&Bl[n][k8s]) = *reinterpret_cast<const short8v*>(Btlo + off);
    }
    __syncthreads();

    short8v ah[2], al_[2], bh[2], bl_[2];
#pragma unroll
    for (int m = 0; m < 2; ++m) {
      int r = wr * 32 + m * 16 + l15;
      ah[m] = *reinterpret_cast<const short8v*>(&Ah[r][k8]);
      al_[m] = *reinterpret_cast<const short8v*>(&Al[r][k8]);
    }
#pragma unroll
    for (int n = 0; n < 2; ++n) {
      int r = wc * 32 + n * 16 + l15;
      bh[n] = *reinterpret_cast<const short8v*>(&Bh[r][k8]);
      bl_[n] = *reinterpret_cast<const short8v*>(&Bl[r][k8]);
    }
#pragma unroll
    for (int m = 0; m < 2; ++m)
#pragma unroll
      for (int n = 0; n < 2; ++n) {
        acc[m][n] = __builtin_amdgcn_mfma_f32_16x16x32_bf16(ah[m], bh[n], acc[m][n], 0, 0, 0);
        acc[m][n] = __builtin_amdgcn_mfma_f32_16x16x32_bf16(ah[m], bl_[n], acc[m][n], 0, 0, 0);
        acc[m][n] = __builtin_amdgcn_mfma_f32_16x16x32_bf16(al_[m], bh[n], acc[m][n], 0, 0, 0);
      }
  }

#pragma unroll
  for (int n = 0; n < 2; ++n) {
    int gcol = bn * 64 + wc * 32 + n * 16 + l15;
    float bv = bias[gcol];
#pragma unroll
    for (int m = 0; m < 2; ++m) {
      int grow0 = bm * 64 + wr * 32 + m * 16 + ((lane >> 4) << 2);
#pragma unroll
      for (int j = 0; j < 4; ++j)
        out[(size_t)(grow0 + j) * DIM + gcol] = acc[m][n][j] + bv;
    }
  }
}

// ---------------------------------------------------------------------------
extern "C" void kernel_launch(void* const* d_in, const int* in_sizes, int n_in,
                              void* d_out, int out_size, void* d_ws, size_t ws_size,
                              hipStream_t stream) {
  const float* x    = (const float*)d_in[0];
  const float* U    = (const float*)d_in[1];
  const float* V    = (const float*)d_in[2];
  const float* p    = (const float*)d_in[3];
  const float* bias = (const float*)d_in[4];
  float* out = (float*)d_out;

  float* F = (float*)d_ws;
  short* AuH  = (short*)F;
  short* AuL  = AuH + 1048576;
  short* AvH  = AuL + 1048576;
  short* AvL  = AvH + 1048576;
  short* QupH = AuH;                  // overlay after gram
  short* QupL = AuL;
  float* Qvt  = F + 1048576;          // overlays AvH/AvL
  float* Gu   = F + 2097152;
  float* Gv   = F + 3145728;
  float* Ptu  = Gu;                   // overlay after tree
  float* Ptv  = Gv;
  short* xH   = (short*)(F + 2097152);  // overlays Ptu/Ptv after ngemm
  float* Tu   = F + 4194304;
  float* Tv   = F + 5242880;
  short* MTh  = (short*)Tu;           // overlay after pgemm
  short* MTl  = MTh + 1048576;
  short* TtuH = (short*)(F + 6291456);
  short* TtuL = TtuH + 1048576;
  short* TtvH = TtuL + 1048576;
  short* TtvL = TtvH + 1048576;
  short* xL   = (short*)(F + 6291456);  // overlays Tt after tree
  short* AuTh = (short*)(F + 8388608);
  short* AuTl = AuTh + 1048576;
  short* AvTh = AuTl + 1048576;
  short* AvTl = AvTh + 1048576;
  short* TmpTh = (short*)(F + 10485760);
  short* TmpTl = TmpTh + 524288;
  float* tinu = F + 11010048;
  float* tinv = tinu + DIM;
  float* sg   = tinv + DIM;

  prep_k<<<512, 256, 0, stream>>>(U, V, p, tinu, tinv, sg);
  asplit_k<<<1024, 256, 0, stream>>>(U, V, AuH, AuL, AvH, AvL);
  tsplUV_k<<<dim3(16, 16, 2), 256, 0, stream>>>(U, V, AuTh, AuTl, AvTh, AvTl);
  gram_k<<<dim3(136, 1, 2), 256, 0, stream>>>(U, V, AuH, AuL, AvH, AvL, Gu, Gv);
  hipMemsetAsync(Tu, 0, (size_t)4194304 * sizeof(float), stream);  // Tu|Tv|Tt
  tdiag64_k<<<32, 256, 0, stream>>>(Gu, Gv, tinu, tinv, Tu, Tv,
                                    TtuH, TtuL, TtvH, TtvL);
  tcomb64_k<<<16, 256, 0, stream>>>(Gu, Gv, Tu, Tv, TtuH, TtuL, TtvH, TtvL);
  tcombgg_k<<<dim3(1, 1, 8), 256, 0, stream>>>(Gu, Gv, Tu, Tv, TtuH, TtuL, TtvH, TtvL, TmpTh, TmpTl, 128, 4, 1);
  tcombgg_k<<<dim3(1, 1, 8), 256, 0, stream>>>(Gu, Gv, Tu, Tv, TtuH, TtuL, TtvH, TtvL, TmpTh, TmpTl, 128, 4, 2);
  tcombgg_k<<<dim3(2, 2, 4), 256, 0, stream>>>(Gu, Gv, Tu, Tv, TtuH, TtuL, TtvH, TtvL, TmpTh, TmpTl, 256, 2, 1);
  tcombgg_k<<<dim3(2, 2, 4), 256, 0, stream>>>(Gu, Gv, Tu, Tv, TtuH, TtuL, TtvH, TtvL, TmpTh, TmpTl, 256, 2, 2);
  tcombgg_k<<<dim3(4, 4, 2), 256, 0, stream>>>(Gu, Gv, Tu, Tv, TtuH, TtuL, TtvH, TtvL, TmpTh, TmpTl, 512, 1, 1);
  tcombgg_k<<<dim3(4, 4, 2), 256, 0, stream>>>(Gu, Gv, Tu, Tv, TtuH, TtuL, TtvH, TtvL, TmpTh, TmpTl, 512, 1, 2);
  pgemm_k<<<dim3(16, 16, 2), 256, 0, stream>>>(Tu, Tv, AuTh, AuTl, AvTh, AvTl, Ptu, Ptv);
  ngemm_k<<<dim3(16, 16, 2), 256, 0, stream>>>(Ptu, Ptv, AuTh, AuTl, AvTh, AvTl, sg, QupH, QupL, Qvt);
  xsplit_k<<<2048, 256, 0, stream>>>(x, xH, xL);
  mgemm2_k<<<dim3(16, 16), 256, 0, stream>>>(Qvt, QupH, QupL, MTh, MTl);
  gemm_mfma_k<<<1024, 256, 0, stream>>>(xH, xL, MTh, MTl, bias, out);
}